// Round 3
// baseline (5125.433 us; speedup 1.0000x reference)
//
#include <hip/hip_runtime.h>
#include <cstdint>
#include <cmath>

#define MASKV -9.0e20f

// ---------------- Threefry-2x32 (JAX-compatible) ----------------
__host__ __device__ inline void tf2x32(uint32_t k0, uint32_t k1, uint32_t& x0, uint32_t& x1){
  uint32_t ks2 = k0 ^ k1 ^ 0x1BD11BDAu;
  x0 += k0; x1 += k1;
#define TFR(r) { x0 += x1; x1 = (x1<<(r))|(x1>>(32-(r))); x1 ^= x0; }
  TFR(13) TFR(15) TFR(26) TFR(6)
  x0 += k1;  x1 += ks2 + 1u;
  TFR(17) TFR(29) TFR(16) TFR(24)
  x0 += ks2; x1 += k0 + 2u;
  TFR(13) TFR(15) TFR(26) TFR(6)
  x0 += k0;  x1 += k1 + 3u;
  TFR(17) TFR(29) TFR(16) TFR(24)
  x0 += k1;  x1 += ks2 + 4u;
  TFR(13) TFR(15) TFR(26) TFR(6)
  x0 += ks2; x1 += k0 + 5u;
#undef TFR
}

__device__ inline uint32_t rbits32(uint32_t k0, uint32_t k1, uint32_t idx){
  uint32_t x0 = 0u, x1 = idx;
  tf2x32(k0, k1, x0, x1);
  return x0 ^ x1;
}

__device__ inline float u01_from_bits(uint32_t bits){
  union { uint32_t u; float f; } c;
  c.u = (bits >> 9) | 0x3f800000u;
  return c.f - 1.0f;
}

__device__ inline float erfinv_f(float x){
  float w = -log1pf(-x*x);
  float p;
  if (w < 5.0f){
    w -= 2.5f;
    p = 2.81022636e-08f;
    p = fmaf(p, w, 3.43273939e-07f);
    p = fmaf(p, w, -3.5233877e-06f);
    p = fmaf(p, w, -4.39150654e-06f);
    p = fmaf(p, w, 0.00021858087f);
    p = fmaf(p, w, -0.00125372503f);
    p = fmaf(p, w, -0.00417768164f);
    p = fmaf(p, w, 0.246640727f);
    p = fmaf(p, w, 1.50140941f);
  } else {
    w = sqrtf(w) - 3.0f;
    p = -0.000200214257f;
    p = fmaf(p, w, 0.000100950558f);
    p = fmaf(p, w, 0.00134934322f);
    p = fmaf(p, w, -0.00367342844f);
    p = fmaf(p, w, 0.00573950773f);
    p = fmaf(p, w, -0.0076224613f);
    p = fmaf(p, w, 0.00943887047f);
    p = fmaf(p, w, 1.00167406f);
    p = fmaf(p, w, 2.83297682f);
  }
  return p * x;
}

__device__ inline float jax_normal(uint32_t k0, uint32_t k1, uint32_t idx){
  float f = u01_from_bits(rbits32(k0, k1, idx));
  float v = fmaf(f, 2.0f, -0.99999994f);
  v = fmaxf(v, -0.99999994f);
  return 1.41421356f * erfinv_f(v);
}

__device__ inline float jax_gumbel(uint32_t k0, uint32_t k1, uint32_t idx){
  float f = u01_from_bits(rbits32(k0, k1, idx));
  f = f + 1.17549435e-38f;
  f = fmaxf(f, 1.17549435e-38f);
  return -logf(-logf(f));
}

// ---------------- small tiled SGEMM (64x64 tile, 4x4 microtile) ----------------
template<int ACT>
__global__ __launch_bounds__(256) void gemm_k(
    const float* __restrict__ A, int lda,
    const long* __restrict__ atab, int anblk,
    const float* __restrict__ W, const float* __restrict__ bias,
    float* __restrict__ C, int K, int N,
    long c_base, int c_rdiv, long c_ostride, long c_istride)
{
  __shared__ float As[16][64];
  __shared__ float Ws[16][64];
  int tid = threadIdx.x;
  int c0 = blockIdx.x * 64;
  int r0 = blockIdx.y * 64;
  int lr = tid >> 2;
  int lk = (tid & 3) << 2;
  int wk = tid >> 4;
  int wc = (tid & 15) << 2;
  int tx = tid & 15;
  int ty = tid >> 4;
  long aoff0 = 0, aoff1 = 0;
  if (atab){
    const long* t = atab + (long)(r0 + lr) * anblk;
    aoff0 = t[0];
    if (anblk == 2) aoff1 = t[1];
  } else {
    aoff0 = (long)(r0 + lr) * lda;
  }
  float acc[4][4];
#pragma unroll
  for (int i = 0; i < 4; i++)
#pragma unroll
    for (int j = 0; j < 4; j++) acc[i][j] = 0.f;

  for (int k0 = 0; k0 < K; k0 += 16){
    int ka = k0 + lk;
    long ab = (atab && anblk == 2 && ka >= 512) ? (aoff1 + (ka - 512)) : (aoff0 + ka);
    float4 av = *(const float4*)(A + ab);
    As[lk + 0][lr] = av.x;
    As[lk + 1][lr] = av.y;
    As[lk + 2][lr] = av.z;
    As[lk + 3][lr] = av.w;
    float4 wv = *(const float4*)(W + (long)(k0 + wk) * N + (c0 + wc));
    *(float4*)&Ws[wk][wc] = wv;
    __syncthreads();
#pragma unroll
    for (int kk = 0; kk < 16; kk++){
      float4 a4 = *(const float4*)&As[kk][ty << 2];
      float4 w4 = *(const float4*)&Ws[kk][tx << 2];
      float aa[4] = {a4.x, a4.y, a4.z, a4.w};
      float ww[4] = {w4.x, w4.y, w4.z, w4.w};
#pragma unroll
      for (int i = 0; i < 4; i++)
#pragma unroll
        for (int j = 0; j < 4; j++)
          acc[i][j] = fmaf(aa[i], ww[j], acc[i][j]);
    }
    __syncthreads();
  }
  float4 bv = *(const float4*)(bias + c0 + (tx << 2));
  float bb[4] = {bv.x, bv.y, bv.z, bv.w};
#pragma unroll
  for (int i = 0; i < 4; i++){
    int r = r0 + (ty << 2) + i;
    long off = c_base + (long)(r / c_rdiv) * c_ostride + (long)(r % c_rdiv) * c_istride
               + c0 + (tx << 2);
    float4 v;
    float o0 = acc[i][0] + bb[0], o1 = acc[i][1] + bb[1];
    float o2 = acc[i][2] + bb[2], o3 = acc[i][3] + bb[3];
    if (ACT){ o0 = fmaxf(o0, 0.f); o1 = fmaxf(o1, 0.f); o2 = fmaxf(o2, 0.f); o3 = fmaxf(o3, 0.f); }
    v.x = o0; v.y = o1; v.z = o2; v.w = o3;
    *(float4*)(C + off) = v;
  }
}

// ---------------- 256x128-tile fused policy GEMM (initial step, 30720 rows) ----------------
// 512 threads / 8 waves, 8x8 microtile -> LDS floats/FMA = 0.25 (vs 0.375 of 4x8) AND
// ~4 waves/SIMD. Per-output k-order, column sets, shuffle tree identical to prior
// versions -> bitwise-identical logits.
__global__ __launch_bounds__(512, 4) void gemm128f_k(
    const float* __restrict__ Y,
    const long* __restrict__ atab,
    const float* __restrict__ b1,
    const float* __restrict__ W2, const float* __restrict__ b2,
    const float* __restrict__ w3,
    const int* __restrict__ scat, float* __restrict__ logits)
{
  __shared__ float As[16][260];
  __shared__ float Ws[16][132];
  int tid = threadIdx.x;
  int c0 = blockIdx.x * 128;
  int r0 = blockIdx.y * 256;
  int tx = tid & 15, ty = tid >> 4;   // ty in [0,32): 8 rows each
  int rA = tid >> 1;                  // [0,256): staged A-row
  int kh = (tid & 1) << 3;            // 0 or 8
  long a0r = atab[(long)(r0 + rA) * 2];
  long a1r = atab[(long)(r0 + rA) * 2 + 1];
  int wk = tid >> 5;                  // [0,16)
  int wc = (tid & 31) << 2;           // [0,128)
  float acc[8][8];
#pragma unroll
  for (int i = 0; i < 8; i++)
#pragma unroll
    for (int j = 0; j < 8; j++) acc[i][j] = 0.f;

  for (int k0 = 0; k0 < 512; k0 += 16){
    float4 p0 = *(const float4*)(Y + a0r + k0 + kh);
    float4 p1 = *(const float4*)(Y + a0r + k0 + kh + 4);
    float4 q0 = *(const float4*)(Y + a1r + k0 + kh);
    float4 q1 = *(const float4*)(Y + a1r + k0 + kh + 4);
    float4 bv0 = *(const float4*)(b1 + k0 + kh);
    float4 bv1 = *(const float4*)(b1 + k0 + kh + 4);
    As[kh + 0][rA] = fmaxf(p0.x + q0.x + bv0.x, 0.f);
    As[kh + 1][rA] = fmaxf(p0.y + q0.y + bv0.y, 0.f);
    As[kh + 2][rA] = fmaxf(p0.z + q0.z + bv0.z, 0.f);
    As[kh + 3][rA] = fmaxf(p0.w + q0.w + bv0.w, 0.f);
    As[kh + 4][rA] = fmaxf(p1.x + q1.x + bv1.x, 0.f);
    As[kh + 5][rA] = fmaxf(p1.y + q1.y + bv1.y, 0.f);
    As[kh + 6][rA] = fmaxf(p1.z + q1.z + bv1.z, 0.f);
    As[kh + 7][rA] = fmaxf(p1.w + q1.w + bv1.w, 0.f);
    *(float4*)&Ws[wk][wc] = *(const float4*)(W2 + (long)(k0 + wk) * 512 + (c0 + wc));
    __syncthreads();
#pragma unroll
    for (int kk = 0; kk < 16; kk++){
      float a8[8], w8[8];
      *(float4*)&a8[0] = *(const float4*)&As[kk][ty << 3];
      *(float4*)&a8[4] = *(const float4*)&As[kk][(ty << 3) + 4];
      *(float4*)&w8[0] = *(const float4*)&Ws[kk][tx << 2];
      *(float4*)&w8[4] = *(const float4*)&Ws[kk][(tx << 2) + 64];
#pragma unroll
      for (int i = 0; i < 8; i++)
#pragma unroll
        for (int j = 0; j < 8; j++)
          acc[i][j] = fmaf(a8[i], w8[j], acc[i][j]);
    }
    __syncthreads();
  }
  float bb[8], w3v[8];
  *(float4*)&bb[0]  = *(const float4*)(b2 + c0 + (tx << 2));
  *(float4*)&bb[4]  = *(const float4*)(b2 + c0 + (tx << 2) + 64);
  *(float4*)&w3v[0] = *(const float4*)(w3 + c0 + (tx << 2));
  *(float4*)&w3v[4] = *(const float4*)(w3 + c0 + (tx << 2) + 64);
#pragma unroll
  for (int i = 0; i < 8; i++){
    float p = 0.f;
#pragma unroll
    for (int j = 0; j < 8; j++)
      p = fmaf(fmaxf(acc[i][j] + bb[j], 0.f), w3v[j], p);
    for (int m = 1; m < 16; m <<= 1) p += __shfl_xor(p, m);
    if (tx == 0){
      int rr = (ty << 3) + i;
      atomicAdd(logits + scat[r0 + rr], p);
    }
  }
}

// ---------------- 64-tile fused policy GEMM (in-loop, rows <= 3584) ----------------
__global__ __launch_bounds__(256) void gemm64f_k(
    const float* __restrict__ Y,
    const long* __restrict__ atab,
    const float* __restrict__ b1,
    const float* __restrict__ W2, const float* __restrict__ b2,
    const float* __restrict__ w3,
    const int* __restrict__ scat, float* __restrict__ logits)
{
  __shared__ float As[16][64];
  __shared__ float Ws[16][64];
  int tid = threadIdx.x;
  int c0 = blockIdx.x * 64;
  int r0 = blockIdx.y * 64;
  int lr = tid >> 2;
  int lk = (tid & 3) << 2;
  int wk = tid >> 4;
  int wc = (tid & 15) << 2;
  int tx = tid & 15;
  int ty = tid >> 4;
  long a0 = atab[(long)(r0 + lr) * 2];
  long a1 = atab[(long)(r0 + lr) * 2 + 1];
  float acc[4][4];
#pragma unroll
  for (int i = 0; i < 4; i++)
#pragma unroll
    for (int j = 0; j < 4; j++) acc[i][j] = 0.f;

  for (int k0 = 0; k0 < 512; k0 += 16){
    int ka = k0 + lk;
    float4 p = *(const float4*)(Y + a0 + ka);
    float4 q = *(const float4*)(Y + a1 + ka);
    float4 bb = *(const float4*)(b1 + ka);
    As[lk + 0][lr] = fmaxf(p.x + q.x + bb.x, 0.f);
    As[lk + 1][lr] = fmaxf(p.y + q.y + bb.y, 0.f);
    As[lk + 2][lr] = fmaxf(p.z + q.z + bb.z, 0.f);
    As[lk + 3][lr] = fmaxf(p.w + q.w + bb.w, 0.f);
    *(float4*)&Ws[wk][wc] = *(const float4*)(W2 + (long)(k0 + wk) * 512 + (c0 + wc));
    __syncthreads();
#pragma unroll
    for (int kk = 0; kk < 16; kk++){
      float4 a4 = *(const float4*)&As[kk][ty << 2];
      float4 w4 = *(const float4*)&Ws[kk][tx << 2];
      float aa[4] = {a4.x, a4.y, a4.z, a4.w};
      float ww[4] = {w4.x, w4.y, w4.z, w4.w};
#pragma unroll
      for (int i = 0; i < 4; i++)
#pragma unroll
        for (int j = 0; j < 4; j++)
          acc[i][j] = fmaf(aa[i], ww[j], acc[i][j]);
    }
    __syncthreads();
  }
  float bb4[4], w34[4];
  *(float4*)&bb4[0] = *(const float4*)(b2 + c0 + (tx << 2));
  *(float4*)&w34[0] = *(const float4*)(w3 + c0 + (tx << 2));
#pragma unroll
  for (int i = 0; i < 4; i++){
    float p = 0.f;
#pragma unroll
    for (int j = 0; j < 4; j++)
      p = fmaf(fmaxf(acc[i][j] + bb4[j], 0.f), w34[j], p);
    for (int m = 1; m < 16; m <<= 1) p += __shfl_xor(p, m);
    if (tx == 0){
      int r = r0 + (ty << 2) + i;
      atomicAdd(logits + scat[r], p);
    }
  }
}

// N=2 final layer with scatter table: one wave per row
__global__ __launch_bounds__(256) void rowdot2_k(
    const float* __restrict__ A, int lda,
    const float* __restrict__ W, const float* __restrict__ bias,
    int K, float* __restrict__ out, const int* __restrict__ scat)
{
  int wid = threadIdx.x >> 6, lane = threadIdx.x & 63;
  int r = blockIdx.x * 4 + wid;
  const float* a = A + (long)r * lda;
  float s0 = 0.f, s1 = 0.f;
  for (int k = lane; k < K; k += 64){
    float x = a[k];
    s0 = fmaf(x, W[k * 2], s0);
    s1 = fmaf(x, W[k * 2 + 1], s1);
  }
  for (int off = 32; off > 0; off >>= 1){
    s0 += __shfl_down(s0, off);
    s1 += __shfl_down(s1, off);
  }
  if (lane == 0){
    long o = scat[r];
    out[o] = s0 + bias[0];
    out[o + 1] = s1 + bias[1];
  }
}

// ---------------- batched matvec: 4 batch rows x 256 cols per block ----------------
// W traffic per dispatch: 32 blocks-per-colgroup x K x 256 x 4B (128x less per-element
// re-read than one-batch-per-block). Each W element loaded once per block, FMA'd into
// 4 accumulators. k-split accumulator chains (a0: k, k+4, ...) identical to the prior
// per-batch kernels -> bitwise-identical outputs.
// grid (N/256, 32), 256 threads. Wave wid stages batch b0+wid into LDS.
// tab != nullptr: pair-gather mode (K=1024, two 512 segments); else strided rows.
template<int ACT>
__global__ __launch_bounds__(256) void bmv4_k(
    const float* __restrict__ src, long sbase, long sstride,
    const long* __restrict__ tab,
    const float* __restrict__ W, const float* __restrict__ bias,
    int K, int N, float* __restrict__ dst, long dbase, long dstride)
{
  __shared__ float s[4][1024];
  int tid = threadIdx.x;
  int lane = tid & 63, wid = tid >> 6;
  int b0 = blockIdx.y * 4;
  int c = blockIdx.x * 256 + tid;
  if (tab){
    long t0 = tab[(long)(b0 + wid) * 2];
    long t1 = tab[(long)(b0 + wid) * 2 + 1];
    if (lane < 32){
      int k0 = lane << 4;
      *(float4*)&s[wid][k0]      = *(const float4*)(src + t0 + k0);
      *(float4*)&s[wid][k0 + 4]  = *(const float4*)(src + t0 + k0 + 4);
      *(float4*)&s[wid][k0 + 8]  = *(const float4*)(src + t0 + k0 + 8);
      *(float4*)&s[wid][k0 + 12] = *(const float4*)(src + t0 + k0 + 12);
    } else {
      int k0 = (lane - 32) << 4;
      *(float4*)&s[wid][512 + k0]      = *(const float4*)(src + t1 + k0);
      *(float4*)&s[wid][512 + k0 + 4]  = *(const float4*)(src + t1 + k0 + 4);
      *(float4*)&s[wid][512 + k0 + 8]  = *(const float4*)(src + t1 + k0 + 8);
      *(float4*)&s[wid][512 + k0 + 12] = *(const float4*)(src + t1 + k0 + 12);
    }
  } else {
    const float* sr = src + sbase + (long)(b0 + wid) * sstride;
    int k0 = lane << 3;
    *(float4*)&s[wid][k0]     = *(const float4*)(sr + k0);
    *(float4*)&s[wid][k0 + 4] = *(const float4*)(sr + k0 + 4);
  }
  __syncthreads();
  float acc[4][4];
#pragma unroll
  for (int bi = 0; bi < 4; bi++)
#pragma unroll
    for (int j = 0; j < 4; j++) acc[bi][j] = 0.f;

#pragma unroll 4
  for (int k = 0; k < K; k += 4){
    float wv0 = W[(long)k * N + c];
    float wv1 = W[(long)(k + 1) * N + c];
    float wv2 = W[(long)(k + 2) * N + c];
    float wv3 = W[(long)(k + 3) * N + c];
#pragma unroll
    for (int bi = 0; bi < 4; bi++){
      float4 sv = *(const float4*)&s[bi][k];
      acc[bi][0] = fmaf(sv.x, wv0, acc[bi][0]);
      acc[bi][1] = fmaf(sv.y, wv1, acc[bi][1]);
      acc[bi][2] = fmaf(sv.z, wv2, acc[bi][2]);
      acc[bi][3] = fmaf(sv.w, wv3, acc[bi][3]);
    }
  }
  float bc = bias[c];
#pragma unroll
  for (int bi = 0; bi < 4; bi++){
    float v = ((acc[bi][0] + acc[bi][1]) + (acc[bi][2] + acc[bi][3])) + bc;
    if (ACT) v = fmaxf(v, 0.f);
    dst[dbase + (long)(b0 + bi) * dstride + c] = v;
  }
}

// enc layer3 as batched matvec: z stored to z_all, z+noise to u token row. grid (2, 32)
__global__ __launch_bounds__(256) void lay3z4_k(
    const float* __restrict__ src,
    const float* __restrict__ W, const float* __restrict__ bias,
    float* __restrict__ z_all, float* __restrict__ u,
    int it, uint32_t k0, uint32_t k1)
{
  __shared__ float s[4][512];
  int tid = threadIdx.x;
  int lane = tid & 63, wid = tid >> 6;
  int b0 = blockIdx.y * 4;
  int c = blockIdx.x * 256 + tid;
  {
    const float* sr = src + (long)(b0 + wid) * 512;
    int kk = lane << 3;
    *(float4*)&s[wid][kk]     = *(const float4*)(sr + kk);
    *(float4*)&s[wid][kk + 4] = *(const float4*)(sr + kk + 4);
  }
  __syncthreads();
  float acc[4][4];
#pragma unroll
  for (int bi = 0; bi < 4; bi++)
#pragma unroll
    for (int j = 0; j < 4; j++) acc[bi][j] = 0.f;

#pragma unroll 4
  for (int k = 0; k < 512; k += 4){
    float wv0 = W[(long)k * 512 + c];
    float wv1 = W[(long)(k + 1) * 512 + c];
    float wv2 = W[(long)(k + 2) * 512 + c];
    float wv3 = W[(long)(k + 3) * 512 + c];
#pragma unroll
    for (int bi = 0; bi < 4; bi++){
      float4 sv = *(const float4*)&s[bi][k];
      acc[bi][0] = fmaf(sv.x, wv0, acc[bi][0]);
      acc[bi][1] = fmaf(sv.y, wv1, acc[bi][1]);
      acc[bi][2] = fmaf(sv.z, wv2, acc[bi][2]);
      acc[bi][3] = fmaf(sv.w, wv3, acc[bi][3]);
    }
  }
  float bc = bias[c];
#pragma unroll
  for (int bi = 0; bi < 4; bi++){
    int b = b0 + bi;
    float v = ((acc[bi][0] + acc[bi][1]) + (acc[bi][2] + acc[bi][3])) + bc;
    z_all[(long)it * 65536 + (long)b * 512 + c] = v;
    float nv = jax_normal(k0, k1, (uint32_t)(b * 512 + c));
    u[((long)(b * 31 + 16 + it)) * 512 + c] = v + 0.01f * nv;
  }
}

// reverse layer3 + scatter into dmat, batched. grid (4, 32)
__global__ __launch_bounds__(256) void rev34_k(
    const float* __restrict__ src,
    const float* __restrict__ W, const float* __restrict__ bias,
    float* __restrict__ dmat, const int* __restrict__ actions, int it)
{
  __shared__ float s[4][512];
  int tid = threadIdx.x;
  int lane = tid & 63, wid = tid >> 6;
  int b0 = blockIdx.y * 4;
  int p = blockIdx.x * 256 + tid;
  {
    const float* sr = src + (long)(b0 + wid) * 512;
    int kk = lane << 3;
    *(float4*)&s[wid][kk]     = *(const float4*)(sr + kk);
    *(float4*)&s[wid][kk + 4] = *(const float4*)(sr + kk + 4);
  }
  __syncthreads();
  float acc[4][4];
#pragma unroll
  for (int bi = 0; bi < 4; bi++)
#pragma unroll
    for (int j = 0; j < 4; j++) acc[bi][j] = 0.f;

#pragma unroll 4
  for (int k = 0; k < 512; k += 4){
    float wv0 = W[(long)k * 1024 + p];
    float wv1 = W[(long)(k + 1) * 1024 + p];
    float wv2 = W[(long)(k + 2) * 1024 + p];
    float wv3 = W[(long)(k + 3) * 1024 + p];
#pragma unroll
    for (int bi = 0; bi < 4; bi++){
      float4 sv = *(const float4*)&s[bi][k];
      acc[bi][0] = fmaf(sv.x, wv0, acc[bi][0]);
      acc[bi][1] = fmaf(sv.y, wv1, acc[bi][1]);
      acc[bi][2] = fmaf(sv.z, wv2, acc[bi][2]);
      acc[bi][3] = fmaf(sv.w, wv3, acc[bi][3]);
    }
  }
  float bc = bias[p];
  int fit = 14 - it;
  int ee = p & 511;
#pragma unroll
  for (int bi = 0; bi < 4; bi++){
    int b = b0 + bi;
    float v = ((acc[bi][0] + acc[bi][1]) + (acc[bi][2] + acc[bi][3])) + bc;
    int s0 = actions[(b * 15 + fit) * 2];
    int s1 = actions[(b * 15 + fit) * 2 + 1];
    int node = (p < 512) ? s0 : s1;
    dmat[((long)(b * 31 + node)) * 512 + ee] = v;
  }
}

// batched osl over all steps: grid 1920 (r = it*128 + b)
__global__ __launch_bounds__(256) void oslb_k(
    const float* __restrict__ pred, const float* __restrict__ u,
    const int* __restrict__ actions, float* __restrict__ sl, float* __restrict__ rew)
{
  int r = blockIdx.x, tid = threadIdx.x;
  int it = r >> 7, b = r & 127;
  int s0 = actions[(b * 15 + it) * 2];
  int s1 = actions[(b * 15 + it) * 2 + 1];
  const float* t0 = u + ((long)(b * 31 + s0)) * 512;
  const float* t1 = u + ((long)(b * 31 + s1)) * 512;
  const float* p = pred + (long)r * 1024;
  float s = 0.f;
  for (int k = tid; k < 512; k += 256){
    float d0 = p[k] - t0[k];       s = fmaf(d0, d0, s);
    float d1 = p[k + 512] - t1[k]; s = fmaf(d1, d1, s);
  }
  __shared__ float red[256];
  red[tid] = s; __syncthreads();
  for (int st = 128; st > 0; st >>= 1){ if (tid < st) red[tid] += red[tid + st]; __syncthreads(); }
  if (tid == 0){
    float osl = red[0] / 1024.0f;
    atomicAdd(sl + b, osl);
    rew[b * 15 + it] = -osl;
  }
}

// ---------------- init (no dmat zeroing: every cell of d is provably overwritten) ----------------
__global__ __launch_bounds__(256) void init_k(float* __restrict__ lbl,
    float* __restrict__ logits, float* __restrict__ sl, float* __restrict__ ent,
    int* __restrict__ active, float* __restrict__ zb,
    float* __restrict__ W1cat, const float* __restrict__ pol_w1, const float* __restrict__ pol_b3,
    long* __restrict__ tab_init, int* __restrict__ scat_init, long* __restrict__ tab_tok16,
    long* __restrict__ tab_mgd, int* __restrict__ scat_clf, long clf_off)
{
  long i = (long)blockIdx.x * 256 + threadIdx.x;
  if (i < 524288L){
    int k = (int)(i >> 10), n = (int)(i & 1023);
    W1cat[i] = (n < 512) ? pol_w1[(long)k * 512 + n] : pol_w1[(long)(k + 512) * 512 + (n - 512)];
  }
  if (i < 115200L){
    int rem = (int)(i % 900);
    int rr = rem / 30, cc = rem % 30;
    logits[i] = (rr < 16 && cc < 16 && rr != cc) ? pol_b3[0] : MASKV;
  }
  if (i < 30720L){
    int r = (int)i;
    int pk = r >> 7, b = r & 127;
    int ii2 = pk / 15, jr = pk % 15;
    int jj2 = jr + (jr >= ii2 ? 1 : 0);
    tab_init[r * 2]     = ((long)(b * 31 + ii2)) * 1024;
    tab_init[r * 2 + 1] = ((long)(b * 31 + jj2)) * 1024 + 512;
    scat_init[r] = b * 900 + ii2 * 30 + jj2;
  }
  if (i < 3968L){
    lbl[i] = ((i % 31) < 15) ? 1.0f : 0.0f;
    int r = (int)i;
    if (r < 1920){
      scat_clf[r] = (int)(clf_off + (long)(r & 127) * 62 + (r >> 7) * 2);
    } else {
      int rr = r - 1920;
      scat_clf[r] = (int)(clf_off + (long)(rr >> 4) * 62 + 60 - ((rr & 15) << 1));
    }
  }
  if (i < 2048L){
    active[i] = (int)(i & 15);
    tab_tok16[i] = ((long)((i >> 4) * 31 + (i & 15))) * 512;
  }
  if (i < 1920L){
    int it = (int)(i >> 7), b = (int)(i & 127);
    tab_mgd[i] = ((long)(b * 31 + 30 - it)) * 512;
  }
  if (i < 1024L)  zb[i] = 0.f;
  if (i < 128L){ sl[i] = 0.f; ent[i] = 0.f; }
}

__global__ __launch_bounds__(256) void noise_u_k(float* __restrict__ u, uint32_t k0, uint32_t k1){
  uint32_t e = blockIdx.x * 256u + threadIdx.x; // < 1048576
  uint32_t b = e >> 13, rem = e & 8191u, n = rem >> 9, ee = rem & 511u;
  float nr = jax_normal(k0, k1, e);
  long off = ((long)(b * 31u + n)) * 512 + ee;
  u[off] += 0.01f * nr;
}

__global__ __launch_bounds__(256) void build_d_k(float* __restrict__ dmat, const float* __restrict__ u){
  int e = blockIdx.x * 256 + threadIdx.x; // 65536
  int b = e >> 9, ee = e & 511;
  long off = ((long)(b * 31 + 30)) * 512 + ee;
  dmat[off] = u[off];
}

// softmax stats + entropy + gumbel-argmax + mask + active update + next tables + b3 preset
// wave-shuffle reductions (1 barrier each) + fused sum/entropy sweep:
//   sum p*log p = T/S - log S with T = sum e*(l-m), S = sum e
__global__ __launch_bounds__(256) void sample_k(float* __restrict__ logits, int* __restrict__ active,
    int* __restrict__ actions, float* __restrict__ lp, float* __restrict__ ent,
    int it, int A, uint32_t k0, uint32_t k1, float log_opt,
    long* __restrict__ tab_loop, int* __restrict__ scat_loop, long* __restrict__ tab_pair,
    const float* __restrict__ pol_b3)
{
  int b = blockIdx.x, tid = threadIdx.x;
  int lane = tid & 63, wid = tid >> 6;
  float* Lg = logits + (long)b * 900;
  __shared__ float rmax[4], rS[4], rT[4], rG[4];
  __shared__ int rGi[4];
  __shared__ int ss0, ss1;

  // pass 1: max
  float v = -3.4e38f;
  for (int j = tid; j < 900; j += 256) v = fmaxf(v, Lg[j]);
#pragma unroll
  for (int m = 32; m; m >>= 1) v = fmaxf(v, __shfl_xor(v, m));
  if (lane == 0) rmax[wid] = v;
  __syncthreads();
  float mx = fmaxf(fmaxf(rmax[0], rmax[1]), fmaxf(rmax[2], rmax[3]));

  // pass 2: S = sum exp(l-m); T = sum e*(l-m) over unmasked
  float s = 0.f, t = 0.f;
  for (int j = tid; j < 900; j += 256){
    float l = Lg[j];
    float d = l - mx;
    float e = expf(d);
    s += e;
    if (l > MASKV) t = fmaf(e, d, t);
  }
#pragma unroll
  for (int m = 32; m; m >>= 1){ s += __shfl_xor(s, m); t += __shfl_xor(t, m); }
  if (lane == 0){ rS[wid] = s; rT[wid] = t; }

  // pass 3: gumbel argmax (earliest index wins on ties)
  float bv = -3.4e38f; int bi = 0;
  for (int j = tid; j < 900; j += 256){
    float g = jax_gumbel(k0, k1, (uint32_t)(b * 900 + j));
    float val = Lg[j] + g;
    if (val > bv){ bv = val; bi = j; }
  }
#pragma unroll
  for (int m = 32; m; m >>= 1){
    float ov = __shfl_xor(bv, m); int oi = __shfl_xor(bi, m);
    if (ov > bv || (ov == bv && oi < bi)){ bv = ov; bi = oi; }
  }
  if (lane == 0){ rG[wid] = bv; rGi[wid] = bi; }
  __syncthreads();

  if (tid == 0){
    float S = (rS[0] + rS[1]) + (rS[2] + rS[3]);
    float T = (rT[0] + rT[1]) + (rT[2] + rT[3]);
    ent[b] += -(T / S - logf(S)) / log_opt;
    float gb = rG[0]; int gi = rGi[0];
    for (int w = 1; w < 4; w++){
      if (rG[w] > gb || (rG[w] == gb && rGi[w] < gi)){ gb = rG[w]; gi = rGi[w]; }
    }
    int sf = gi;
    int s0 = sf / 30, s1 = sf % 30;
    ss0 = s0; ss1 = s1;
    actions[(b * 15 + it) * 2] = s0;
    actions[(b * 15 + it) * 2 + 1] = s1;
    lp[b * 15 + it] = Lg[sf] - mx - logf(S);
    tab_pair[b * 2]     = ((long)(b * 31 + s0)) * 512;
    tab_pair[b * 2 + 1] = ((long)(b * 31 + s1)) * 512;
  }
  __syncthreads();
  int s0 = ss0, s1 = ss1;
  if (tid < 30){
    Lg[s0 * 30 + tid] = MASKV;
    Lg[s1 * 30 + tid] = MASKV;
    Lg[tid * 30 + s0] = MASKV;
    Lg[tid * 30 + s1] = MASKV;
  }
  if (tid == 0){
    float b3v = pol_b3[0];
    int buf[16]; int c = 0;
    for (int k = 0; k < A; k++){
      int a = active[b * 16 + k];
      if (a != s0 && a != s1) buf[c++] = a;
    }
    int nt2 = 16 + it;
    buf[c++] = nt2;
    for (int k = 0; k < c; k++) active[b * 16 + k] = buf[k];
    int na2 = c - 1;
    for (int j = 0; j < na2; j++){
      int q = buf[j];
      int r1 = j * 128 + b;
      tab_loop[r1 * 2]     = ((long)(b * 31 + nt2)) * 1024;
      tab_loop[r1 * 2 + 1] = ((long)(b * 31 + q)) * 1024 + 512;
      int sc1 = b * 900 + nt2 * 30 + q;
      scat_loop[r1] = sc1;
      logits[sc1] = b3v;
      int r2 = (na2 + j) * 128 + b;
      tab_loop[r2 * 2]     = ((long)(b * 31 + q)) * 1024;
      tab_loop[r2 * 2 + 1] = ((long)(b * 31 + nt2)) * 1024 + 512;
      int sc2 = b * 900 + q * 30 + nt2;
      scat_loop[r2] = sc2;
      logits[sc2] = b3v;
    }
  }
}

__global__ __launch_bounds__(256) void finalize_k(const float* __restrict__ rew,
    const float* __restrict__ lp, const float* __restrict__ sl, const float* __restrict__ ent,
    float* __restrict__ out_sl, float* __restrict__ out_ent, float* __restrict__ out_reinf)
{
  __shared__ float red[256];
  int tid = threadIdx.x;
  float s = 0.f;
  for (int i = tid; i < 1920; i += 256) s += rew[i];
  red[tid] = s; __syncthreads();
  for (int st = 128; st > 0; st >>= 1){ if (tid < st) red[tid] += red[tid + st]; __syncthreads(); }
  float mean = red[0] / 1920.0f; __syncthreads();
  float v = 0.f;
  for (int i = tid; i < 1920; i += 256){ float x = rew[i] - mean; v = fmaf(x, x, v); }
  red[tid] = v; __syncthreads();
  for (int st = 128; st > 0; st >>= 1){ if (tid < st) red[tid] += red[tid + st]; __syncthreads(); }
  float denom = sqrtf(red[0] / 1919.0f) + 1e-20f;
  if (tid < 128){
    out_sl[tid] = sl[tid] / 15.0f;
    out_ent[tid] = ent[tid] / 15.0f;
    float r = 0.f;
    for (int k = 0; k < 15; k++){
      float rn = (rew[tid * 15 + k] - mean) / denom;
      r = fmaf(lp[tid * 15 + k], rn, r);
    }
    out_reinf[tid] = r;
  }
}

// ---------------- host ----------------
extern "C" void kernel_launch(void* const* d_in, const int* in_sizes, int n_in,
                              void* d_out, int out_size, void* d_ws, size_t ws_size,
                              hipStream_t stream)
{
  const float* x        = (const float*)d_in[0];
  const float* lift_w   = (const float*)d_in[1];
  const float* lift_b   = (const float*)d_in[2];
  const float* unlift_w = (const float*)d_in[3];
  const float* unlift_b = (const float*)d_in[4];
  const float* enc_w1   = (const float*)d_in[5];
  const float* enc_b1   = (const float*)d_in[6];
  const float* enc_w2   = (const float*)d_in[7];
  const float* enc_b2   = (const float*)d_in[8];
  const float* enc_w3   = (const float*)d_in[9];
  const float* enc_b3   = (const float*)d_in[10];
  const float* dec_w1   = (const float*)d_in[11];
  const float* dec_b1   = (const float*)d_in[12];
  const float* dec_w2   = (const float*)d_in[13];
  const float* dec_b2   = (const float*)d_in[14];
  const float* dec_w3   = (const float*)d_in[15];
  const float* dec_b3   = (const float*)d_in[16];
  const float* clf_w1   = (const float*)d_in[17];
  const float* clf_b1   = (const float*)d_in[18];
  const float* clf_w2   = (const float*)d_in[19];
  const float* clf_b2   = (const float*)d_in[20];
  const float* clf_w3   = (const float*)d_in[21];
  const float* clf_b3   = (const float*)d_in[22];
  const float* pol_w1   = (const float*)d_in[23];
  const float* pol_b1   = (const float*)d_in[24];
  const float* pol_w2   = (const float*)d_in[25];
  const float* pol_b2   = (const float*)d_in[26];
  const float* pol_w3   = (const float*)d_in[27];
  const float* pol_b3   = (const float*)d_in[28];

  float* out = (float*)d_out;
  const long U_OFF     = 2097152;
  const long D_OFF     = 4128768;
  const long SL_OFF    = 6160384;
  const long ENT_OFF   = 6160512;
  const long CLF_OFF   = 6160640;
  const long LBL_OFF   = 6168576;
  const long REINF_OFF = 6172544;
  float* recon = out;
  float* u     = out + U_OFF;
  float* dmat  = out + D_OFF;

  char* wsb = (char*)d_ws;
  size_t wo = 0;
  auto alloc = [&](size_t bytes) -> void* {
    void* p = (void*)(wsb + wo);
    wo = (wo + bytes + 255) & ~(size_t)255;
    return p;
  };
  float* logits    = (float*)alloc(115200 * 4);
  float* Y         = (float*)alloc((size_t)3968 * 1024 * 4); // dead after fwd -> overlays:
  float* h1clf     = Y;                  // tail clf hidden1 (3968x512)
  float* pbuf      = Y + 2031616;        // dec output 1920x1024, then clf h2
  float* h2clf     = Y + 2031616;
  float* W1cat     = (float*)alloc((size_t)524288 * 4);
  float* zb        = (float*)alloc(1024 * 4);
  float* h1        = (float*)alloc((size_t)2048 * 512 * 4);
  float* h2        = (float*)alloc((size_t)2048 * 512 * 4);
  float* z_all     = (float*)alloc((size_t)15 * 65536 * 4);
  float* sl        = (float*)alloc(128 * 4);
  float* ent       = (float*)alloc(128 * 4);
  float* lp        = (float*)alloc(1920 * 4);
  float* rew       = (float*)alloc(1920 * 4);
  int*   active    = (int*)alloc(2048 * 4);
  int*   actions   = (int*)alloc(3840 * 4);
  long*  tab_init  = (long*)alloc((size_t)30720 * 2 * 8);
  int*   scat_init = (int*)alloc(30720 * 4);
  long*  tab_loop  = (long*)alloc((size_t)3584 * 2 * 8);
  int*   scat_loop = (int*)alloc(3584 * 4);
  long*  tab_pair  = (long*)alloc(256 * 8);
  long*  tab_mgd   = (long*)alloc(1920 * 8);   // contiguous with tab_tok16 -> 3968-row clf table
  long*  tab_tok16 = (long*)alloc(2048 * 8);
  int*   scat_clf  = (int*)alloc(3968 * 4);
  long*  tab_clf   = tab_mgd;
  (void)ws_size; (void)in_sizes; (void)n_in; (void)out_size;

  uint32_t k7a, k7b, ck0[15], ck1[15], mk0[15], mk1[15];
  { uint32_t a = 0, b = 7; tf2x32(0u, 42u, a, b); k7a = a; k7b = b; }
  for (int it = 0; it < 15; it++){
    { uint32_t a = 0, b = (uint32_t)(100 + it); tf2x32(0u, 42u, a, b); ck0[it] = a; ck1[it] = b; }
    { uint32_t a = 0, b = (uint32_t)(1000 + it); tf2x32(0u, 42u, a, b); mk0[it] = a; mk1[it] = b; }
  }

  auto gemm = [&](int act, const float* A, int lda, const long* atab, int anblk,
                  const float* W, const float* bs, float* C, int rows, int K, int Nn,
                  long cb, int crd, long cos, long cis){
    dim3 g(Nn / 64, rows / 64);
    if (act) gemm_k<1><<<g, 256, 0, stream>>>(A, lda, atab, anblk, W, bs, C, K, Nn, cb, crd, cos, cis);
    else     gemm_k<0><<<g, 256, 0, stream>>>(A, lda, atab, anblk, W, bs, C, K, Nn, cb, crd, cos, cis);
  };

  // ---- init ----
  init_k<<<2048, 256, 0, stream>>>(out + LBL_OFF, logits, sl, ent, active, zb,
                                   W1cat, pol_w1, pol_b3, tab_init, scat_init, tab_tok16,
                                   tab_mgd, scat_clf, CLF_OFF);

  // ---- lift + noise ----
  gemm(0, x, 1024, nullptr, 0, lift_w, lift_b, u, 2048, 1024, 512, 0, 16, 15872, 512);
  noise_u_k<<<4096, 256, 0, stream>>>(u, k7a, k7b);

  // ---- Y init for tokens 0..15 ----
  gemm(0, u, 0, tab_tok16, 1, W1cat, zb, Y, 2048, 512, 1024, 0, 16, 31744, 1024);

  // ---- initial policy logits (256x128 tiles, 512 threads) ----
  { dim3 g(4, 120);
    gemm128f_k<<<g, 512, 0, stream>>>(Y, tab_init, pol_b1, pol_w2, pol_b2, pol_w3,
                                      scat_init, logits); }

  // ---- forward merge loop ----
  for (int it = 0; it < 15; it++){
    int A = 16 - it;
    if (it > 0){
      int rows = 256 * (15 - it);
      dim3 g(8, rows / 64);
      gemm64f_k<<<g, 256, 0, stream>>>(Y, tab_loop, pol_b1, pol_w2, pol_b2, pol_w3,
                                       scat_loop, logits);
    }
    float log_opt = (float)log((double)(A * (A - 1)));
    sample_k<<<128, 256, 0, stream>>>(logits, active, actions, lp, ent, it, A,
                                      ck0[it], ck1[it], log_opt,
                                      tab_loop, scat_loop, tab_pair, pol_b3);
    { dim3 g(2, 32);
      bmv4_k<1><<<g, 256, 0, stream>>>(u, 0, 0, tab_pair, enc_w1, enc_b1,
                                       1024, 512, h1, 0, 512); }
    { dim3 g(2, 32);
      bmv4_k<1><<<g, 256, 0, stream>>>(h1, 0, 512, nullptr, enc_w2, enc_b2,
                                       512, 512, h2, 0, 512); }
    { dim3 g(2, 32);
      lay3z4_k<<<g, 256, 0, stream>>>(h2, enc_w3, enc_b3, z_all, u, it, mk0[it], mk1[it]); }
    if (it < 14){
      dim3 g(4, 32);
      bmv4_k<0><<<g, 256, 0, stream>>>(u, (long)(16 + it) * 512, 15872, nullptr, W1cat, zb,
                                       512, 1024, Y, (long)(16 + it) * 1024, 31744);
    }
  }

  // ---- deferred batched dec over all 15 steps (1920 rows), then osl ----
  gemm(1, z_all, 512, nullptr, 0, dec_w1, dec_b1, h1, 1920, 512, 512, 0, 1, 512, 0);
  gemm(1, h1, 512, nullptr, 0, dec_w2, dec_b2, h2, 1920, 512, 512, 0, 1, 512, 0);
  gemm(0, h2, 512, nullptr, 0, dec_w3, dec_b3, pbuf, 1920, 512, 1024, 0, 1, 1024, 0);
  oslb_k<<<1920, 256, 0, stream>>>(pbuf, u, actions, sl, rew);

  // ---- d init (only token 30 active) ----
  build_d_k<<<256, 256, 0, stream>>>(dmat, u);

  // ---- reverse unmerge loop: 3 batched layers per step ----
  for (int it = 0; it < 15; it++){
    int tok = 30 - it;
    { dim3 g(2, 32);
      bmv4_k<1><<<g, 256, 0, stream>>>(dmat, (long)tok * 512, 15872, nullptr, dec_w1, dec_b1,
                                       512, 512, h1, 0, 512); }
    { dim3 g(2, 32);
      bmv4_k<1><<<g, 256, 0, stream>>>(h1, 0, 512, nullptr, dec_w2, dec_b2,
                                       512, 512, h2, 0, 512); }
    { dim3 g(4, 32);
      rev34_k<<<g, 256, 0, stream>>>(h2, dec_w3, dec_b3, dmat, actions, it); }
  }

  // ---- combined clf over mgd rows (1920) + final d[:, :16] rows (2048) ----
  gemm(1, dmat, 0, tab_clf, 1, clf_w1, clf_b1, h1clf, 3968, 512, 512, 0, 1, 512, 0);
  gemm(1, h1clf, 512, nullptr, 0, clf_w2, clf_b2, h2clf, 3968, 512, 512, 0, 1, 512, 0);
  rowdot2_k<<<992, 256, 0, stream>>>(h2clf, 512, clf_w3, clf_b3, 512, out, scat_clf);

  // ---- recon = d[:, :16] @ unlift_w + unlift_b ----
  gemm(0, dmat, 0, tab_tok16, 1, unlift_w, unlift_b, recon, 2048, 512, 1024,
       0, 16, 16384, 1024);

  // ---- reward normalization, reinf, per-batch losses ----
  finalize_k<<<1, 256, 0, stream>>>(rew, lp, sl, ent,
                                    out + SL_OFF, out + ENT_OFF, out + REINF_OFF);
}

// Round 4
// 4236.330 us; speedup vs baseline: 1.2099x; 1.2099x over previous
//
#include <hip/hip_runtime.h>
#include <cstdint>
#include <cmath>

#define MASKV -9.0e20f

// ---------------- Threefry-2x32 (JAX-compatible) ----------------
__host__ __device__ inline void tf2x32(uint32_t k0, uint32_t k1, uint32_t& x0, uint32_t& x1){
  uint32_t ks2 = k0 ^ k1 ^ 0x1BD11BDAu;
  x0 += k0; x1 += k1;
#define TFR(r) { x0 += x1; x1 = (x1<<(r))|(x1>>(32-(r))); x1 ^= x0; }
  TFR(13) TFR(15) TFR(26) TFR(6)
  x0 += k1;  x1 += ks2 + 1u;
  TFR(17) TFR(29) TFR(16) TFR(24)
  x0 += ks2; x1 += k0 + 2u;
  TFR(13) TFR(15) TFR(26) TFR(6)
  x0 += k0;  x1 += k1 + 3u;
  TFR(17) TFR(29) TFR(16) TFR(24)
  x0 += k1;  x1 += ks2 + 4u;
  TFR(13) TFR(15) TFR(26) TFR(6)
  x0 += ks2; x1 += k0 + 5u;
#undef TFR
}

__device__ inline uint32_t rbits32(uint32_t k0, uint32_t k1, uint32_t idx){
  uint32_t x0 = 0u, x1 = idx;
  tf2x32(k0, k1, x0, x1);
  return x0 ^ x1;
}

__device__ inline float u01_from_bits(uint32_t bits){
  union { uint32_t u; float f; } c;
  c.u = (bits >> 9) | 0x3f800000u;
  return c.f - 1.0f;
}

__device__ inline float erfinv_f(float x){
  float w = -log1pf(-x*x);
  float p;
  if (w < 5.0f){
    w -= 2.5f;
    p = 2.81022636e-08f;
    p = fmaf(p, w, 3.43273939e-07f);
    p = fmaf(p, w, -3.5233877e-06f);
    p = fmaf(p, w, -4.39150654e-06f);
    p = fmaf(p, w, 0.00021858087f);
    p = fmaf(p, w, -0.00125372503f);
    p = fmaf(p, w, -0.00417768164f);
    p = fmaf(p, w, 0.246640727f);
    p = fmaf(p, w, 1.50140941f);
  } else {
    w = sqrtf(w) - 3.0f;
    p = -0.000200214257f;
    p = fmaf(p, w, 0.000100950558f);
    p = fmaf(p, w, 0.00134934322f);
    p = fmaf(p, w, -0.00367342844f);
    p = fmaf(p, w, 0.00573950773f);
    p = fmaf(p, w, -0.0076224613f);
    p = fmaf(p, w, 0.00943887047f);
    p = fmaf(p, w, 1.00167406f);
    p = fmaf(p, w, 2.83297682f);
  }
  return p * x;
}

__device__ inline float jax_normal(uint32_t k0, uint32_t k1, uint32_t idx){
  float f = u01_from_bits(rbits32(k0, k1, idx));
  float v = fmaf(f, 2.0f, -0.99999994f);
  v = fmaxf(v, -0.99999994f);
  return 1.41421356f * erfinv_f(v);
}

__device__ inline float jax_gumbel(uint32_t k0, uint32_t k1, uint32_t idx){
  float f = u01_from_bits(rbits32(k0, k1, idx));
  f = f + 1.17549435e-38f;
  f = fmaxf(f, 1.17549435e-38f);
  return -logf(-logf(f));
}

// ---------------- small tiled SGEMM (64x64 tile, 4x4 microtile) ----------------
template<int ACT>
__global__ __launch_bounds__(256) void gemm_k(
    const float* __restrict__ A, int lda,
    const long* __restrict__ atab, int anblk,
    const float* __restrict__ W, const float* __restrict__ bias,
    float* __restrict__ C, int K, int N,
    long c_base, int c_rdiv, long c_ostride, long c_istride)
{
  __shared__ float As[16][64];
  __shared__ float Ws[16][64];
  int tid = threadIdx.x;
  int c0 = blockIdx.x * 64;
  int r0 = blockIdx.y * 64;
  int lr = tid >> 2;
  int lk = (tid & 3) << 2;
  int wk = tid >> 4;
  int wc = (tid & 15) << 2;
  int tx = tid & 15;
  int ty = tid >> 4;
  long aoff0 = 0, aoff1 = 0;
  if (atab){
    const long* t = atab + (long)(r0 + lr) * anblk;
    aoff0 = t[0];
    if (anblk == 2) aoff1 = t[1];
  } else {
    aoff0 = (long)(r0 + lr) * lda;
  }
  float acc[4][4];
#pragma unroll
  for (int i = 0; i < 4; i++)
#pragma unroll
    for (int j = 0; j < 4; j++) acc[i][j] = 0.f;

  for (int k0 = 0; k0 < K; k0 += 16){
    int ka = k0 + lk;
    long ab = (atab && anblk == 2 && ka >= 512) ? (aoff1 + (ka - 512)) : (aoff0 + ka);
    float4 av = *(const float4*)(A + ab);
    As[lk + 0][lr] = av.x;
    As[lk + 1][lr] = av.y;
    As[lk + 2][lr] = av.z;
    As[lk + 3][lr] = av.w;
    float4 wv = *(const float4*)(W + (long)(k0 + wk) * N + (c0 + wc));
    *(float4*)&Ws[wk][wc] = wv;
    __syncthreads();
#pragma unroll
    for (int kk = 0; kk < 16; kk++){
      float4 a4 = *(const float4*)&As[kk][ty << 2];
      float4 w4 = *(const float4*)&Ws[kk][tx << 2];
      float aa[4] = {a4.x, a4.y, a4.z, a4.w};
      float ww[4] = {w4.x, w4.y, w4.z, w4.w};
#pragma unroll
      for (int i = 0; i < 4; i++)
#pragma unroll
        for (int j = 0; j < 4; j++)
          acc[i][j] = fmaf(aa[i], ww[j], acc[i][j]);
    }
    __syncthreads();
  }
  float4 bv = *(const float4*)(bias + c0 + (tx << 2));
  float bb[4] = {bv.x, bv.y, bv.z, bv.w};
#pragma unroll
  for (int i = 0; i < 4; i++){
    int r = r0 + (ty << 2) + i;
    long off = c_base + (long)(r / c_rdiv) * c_ostride + (long)(r % c_rdiv) * c_istride
               + c0 + (tx << 2);
    float4 v;
    float o0 = acc[i][0] + bb[0], o1 = acc[i][1] + bb[1];
    float o2 = acc[i][2] + bb[2], o3 = acc[i][3] + bb[3];
    if (ACT){ o0 = fmaxf(o0, 0.f); o1 = fmaxf(o1, 0.f); o2 = fmaxf(o2, 0.f); o3 = fmaxf(o3, 0.f); }
    v.x = o0; v.y = o1; v.z = o2; v.w = o3;
    *(float4*)(C + off) = v;
  }
}

// ---------------- 256x128-tile fused policy GEMM (initial step, 30720 rows) ----------------
// At the LDS-read roofline for this structure (ds_read_b128 ~85 B/cyc caps VALU ~62%).
__global__ __launch_bounds__(512, 4) void gemm128f_k(
    const float* __restrict__ Y,
    const long* __restrict__ atab,
    const float* __restrict__ b1,
    const float* __restrict__ W2, const float* __restrict__ b2,
    const float* __restrict__ w3,
    const int* __restrict__ scat, float* __restrict__ logits)
{
  __shared__ float As[16][260];
  __shared__ float Ws[16][132];
  int tid = threadIdx.x;
  int c0 = blockIdx.x * 128;
  int r0 = blockIdx.y * 256;
  int tx = tid & 15, ty = tid >> 4;   // ty in [0,32): 8 rows each
  int rA = tid >> 1;                  // [0,256): staged A-row
  int kh = (tid & 1) << 3;            // 0 or 8
  long a0r = atab[(long)(r0 + rA) * 2];
  long a1r = atab[(long)(r0 + rA) * 2 + 1];
  int wk = tid >> 5;                  // [0,16)
  int wc = (tid & 31) << 2;           // [0,128)
  float acc[8][8];
#pragma unroll
  for (int i = 0; i < 8; i++)
#pragma unroll
    for (int j = 0; j < 8; j++) acc[i][j] = 0.f;

  for (int k0 = 0; k0 < 512; k0 += 16){
    float4 p0 = *(const float4*)(Y + a0r + k0 + kh);
    float4 p1 = *(const float4*)(Y + a0r + k0 + kh + 4);
    float4 q0 = *(const float4*)(Y + a1r + k0 + kh);
    float4 q1 = *(const float4*)(Y + a1r + k0 + kh + 4);
    float4 bv0 = *(const float4*)(b1 + k0 + kh);
    float4 bv1 = *(const float4*)(b1 + k0 + kh + 4);
    As[kh + 0][rA] = fmaxf(p0.x + q0.x + bv0.x, 0.f);
    As[kh + 1][rA] = fmaxf(p0.y + q0.y + bv0.y, 0.f);
    As[kh + 2][rA] = fmaxf(p0.z + q0.z + bv0.z, 0.f);
    As[kh + 3][rA] = fmaxf(p0.w + q0.w + bv0.w, 0.f);
    As[kh + 4][rA] = fmaxf(p1.x + q1.x + bv1.x, 0.f);
    As[kh + 5][rA] = fmaxf(p1.y + q1.y + bv1.y, 0.f);
    As[kh + 6][rA] = fmaxf(p1.z + q1.z + bv1.z, 0.f);
    As[kh + 7][rA] = fmaxf(p1.w + q1.w + bv1.w, 0.f);
    *(float4*)&Ws[wk][wc] = *(const float4*)(W2 + (long)(k0 + wk) * 512 + (c0 + wc));
    __syncthreads();
#pragma unroll
    for (int kk = 0; kk < 16; kk++){
      float a8[8], w8[8];
      *(float4*)&a8[0] = *(const float4*)&As[kk][ty << 3];
      *(float4*)&a8[4] = *(const float4*)&As[kk][(ty << 3) + 4];
      *(float4*)&w8[0] = *(const float4*)&Ws[kk][tx << 2];
      *(float4*)&w8[4] = *(const float4*)&Ws[kk][(tx << 2) + 64];
#pragma unroll
      for (int i = 0; i < 8; i++)
#pragma unroll
        for (int j = 0; j < 8; j++)
          acc[i][j] = fmaf(a8[i], w8[j], acc[i][j]);
    }
    __syncthreads();
  }
  float bb[8], w3v[8];
  *(float4*)&bb[0]  = *(const float4*)(b2 + c0 + (tx << 2));
  *(float4*)&bb[4]  = *(const float4*)(b2 + c0 + (tx << 2) + 64);
  *(float4*)&w3v[0] = *(const float4*)(w3 + c0 + (tx << 2));
  *(float4*)&w3v[4] = *(const float4*)(w3 + c0 + (tx << 2) + 64);
#pragma unroll
  for (int i = 0; i < 8; i++){
    float p = 0.f;
#pragma unroll
    for (int j = 0; j < 8; j++)
      p = fmaf(fmaxf(acc[i][j] + bb[j], 0.f), w3v[j], p);
    for (int m = 1; m < 16; m <<= 1) p += __shfl_xor(p, m);
    if (tx == 0){
      int rr = (ty << 3) + i;
      atomicAdd(logits + scat[r0 + rr], p);
    }
  }
}

// ---------------- 64-tile fused policy GEMM (in-loop, rows <= 3584) ----------------
__global__ __launch_bounds__(256) void gemm64f_k(
    const float* __restrict__ Y,
    const long* __restrict__ atab,
    const float* __restrict__ b1,
    const float* __restrict__ W2, const float* __restrict__ b2,
    const float* __restrict__ w3,
    const int* __restrict__ scat, float* __restrict__ logits)
{
  __shared__ float As[16][64];
  __shared__ float Ws[16][64];
  int tid = threadIdx.x;
  int c0 = blockIdx.x * 64;
  int r0 = blockIdx.y * 64;
  int lr = tid >> 2;
  int lk = (tid & 3) << 2;
  int wk = tid >> 4;
  int wc = (tid & 15) << 2;
  int tx = tid & 15;
  int ty = tid >> 4;
  long a0 = atab[(long)(r0 + lr) * 2];
  long a1 = atab[(long)(r0 + lr) * 2 + 1];
  float acc[4][4];
#pragma unroll
  for (int i = 0; i < 4; i++)
#pragma unroll
    for (int j = 0; j < 4; j++) acc[i][j] = 0.f;

  for (int k0 = 0; k0 < 512; k0 += 16){
    int ka = k0 + lk;
    float4 p = *(const float4*)(Y + a0 + ka);
    float4 q = *(const float4*)(Y + a1 + ka);
    float4 bb = *(const float4*)(b1 + ka);
    As[lk + 0][lr] = fmaxf(p.x + q.x + bb.x, 0.f);
    As[lk + 1][lr] = fmaxf(p.y + q.y + bb.y, 0.f);
    As[lk + 2][lr] = fmaxf(p.z + q.z + bb.z, 0.f);
    As[lk + 3][lr] = fmaxf(p.w + q.w + bb.w, 0.f);
    *(float4*)&Ws[wk][wc] = *(const float4*)(W2 + (long)(k0 + wk) * 512 + (c0 + wc));
    __syncthreads();
#pragma unroll
    for (int kk = 0; kk < 16; kk++){
      float4 a4 = *(const float4*)&As[kk][ty << 2];
      float4 w4 = *(const float4*)&Ws[kk][tx << 2];
      float aa[4] = {a4.x, a4.y, a4.z, a4.w};
      float ww[4] = {w4.x, w4.y, w4.z, w4.w};
#pragma unroll
      for (int i = 0; i < 4; i++)
#pragma unroll
        for (int j = 0; j < 4; j++)
          acc[i][j] = fmaf(aa[i], ww[j], acc[i][j]);
    }
    __syncthreads();
  }
  float bb4[4], w34[4];
  *(float4*)&bb4[0] = *(const float4*)(b2 + c0 + (tx << 2));
  *(float4*)&w34[0] = *(const float4*)(w3 + c0 + (tx << 2));
#pragma unroll
  for (int i = 0; i < 4; i++){
    float p = 0.f;
#pragma unroll
    for (int j = 0; j < 4; j++)
      p = fmaf(fmaxf(acc[i][j] + bb4[j], 0.f), w34[j], p);
    for (int m = 1; m < 16; m <<= 1) p += __shfl_xor(p, m);
    if (tx == 0){
      int r = r0 + (ty << 2) + i;
      atomicAdd(logits + scat[r], p);
    }
  }
}

// N=2 final layer with scatter table: one wave per row
__global__ __launch_bounds__(256) void rowdot2_k(
    const float* __restrict__ A, int lda,
    const float* __restrict__ W, const float* __restrict__ bias,
    int K, float* __restrict__ out, const int* __restrict__ scat)
{
  int wid = threadIdx.x >> 6, lane = threadIdx.x & 63;
  int r = blockIdx.x * 4 + wid;
  const float* a = A + (long)r * lda;
  float s0 = 0.f, s1 = 0.f;
  for (int k = lane; k < K; k += 64){
    float x = a[k];
    s0 = fmaf(x, W[k * 2], s0);
    s1 = fmaf(x, W[k * 2 + 1], s1);
  }
  for (int off = 32; off > 0; off >>= 1){
    s0 += __shfl_down(s0, off);
    s1 += __shfl_down(s1, off);
  }
  if (lane == 0){
    long o = scat[r];
    out[o] = s0 + bias[0];
    out[o + 1] = s1 + bias[1];
  }
}

// ---------------- fused forward step: enc1 -> enc2 -> enc3(+noise,+u) -> yrow ----------------
// 2 batches per block (64 blocks x 512 threads). Block-local barriers between layers.
// All per-output accumulator chains (4-way k-split, ((a0+a1)+(a2+a3))+bias) are verbatim
// from the per-layer kernels -> bitwise-identical outputs. W elements loaded once per
// block, reused for both batches (halves L2 weight traffic vs per-batch kernels).
__global__ __launch_bounds__(512) void fwdstep_k(
    float* __restrict__ u, const long* __restrict__ tab_pair,
    const float* __restrict__ w1e, const float* __restrict__ b1e,
    const float* __restrict__ w2e, const float* __restrict__ b2e,
    const float* __restrict__ w3e, const float* __restrict__ b3e,
    const float* __restrict__ W1cat,
    float* __restrict__ z_all, float* __restrict__ Y,
    int it, uint32_t k0r, uint32_t k1r)
{
  __shared__ float s[2][1024];
  __shared__ float h1s[2][512];
  __shared__ float h2s[2][512];
  int tid = threadIdx.x;
  int b0 = blockIdx.x * 2;

  // stage both pair vectors (2 x 1024 floats), one float4 per thread
  {
    int f = tid << 2;
    int bi = f >> 10;
    int off = f & 1023;
    int seg = off >> 9;
    int ko = off & 511;
    long t = tab_pair[(long)(b0 + bi) * 2 + seg];
    *(float4*)&s[bi][off] = *(const float4*)(u + t + ko);
  }
  __syncthreads();

  int c = tid;
  // ---- layer 1: K=1024, relu ----
  {
    float a0[2] = {0.f, 0.f}, a1[2] = {0.f, 0.f}, a2[2] = {0.f, 0.f}, a3[2] = {0.f, 0.f};
#pragma unroll 8
    for (int k = 0; k < 1024; k += 4){
      float wv0 = w1e[(long)k * 512 + c];
      float wv1 = w1e[(long)(k + 1) * 512 + c];
      float wv2 = w1e[(long)(k + 2) * 512 + c];
      float wv3 = w1e[(long)(k + 3) * 512 + c];
#pragma unroll
      for (int bi = 0; bi < 2; bi++){
        a0[bi] = fmaf(s[bi][k],     wv0, a0[bi]);
        a1[bi] = fmaf(s[bi][k + 1], wv1, a1[bi]);
        a2[bi] = fmaf(s[bi][k + 2], wv2, a2[bi]);
        a3[bi] = fmaf(s[bi][k + 3], wv3, a3[bi]);
      }
    }
    float bc = b1e[c];
    h1s[0][c] = fmaxf(((a0[0] + a1[0]) + (a2[0] + a3[0])) + bc, 0.f);
    h1s[1][c] = fmaxf(((a0[1] + a1[1]) + (a2[1] + a3[1])) + bc, 0.f);
  }
  __syncthreads();

  // ---- layer 2: K=512, relu ----
  {
    float a0[2] = {0.f, 0.f}, a1[2] = {0.f, 0.f}, a2[2] = {0.f, 0.f}, a3[2] = {0.f, 0.f};
#pragma unroll 8
    for (int k = 0; k < 512; k += 4){
      float wv0 = w2e[(long)k * 512 + c];
      float wv1 = w2e[(long)(k + 1) * 512 + c];
      float wv2 = w2e[(long)(k + 2) * 512 + c];
      float wv3 = w2e[(long)(k + 3) * 512 + c];
#pragma unroll
      for (int bi = 0; bi < 2; bi++){
        a0[bi] = fmaf(h1s[bi][k],     wv0, a0[bi]);
        a1[bi] = fmaf(h1s[bi][k + 1], wv1, a1[bi]);
        a2[bi] = fmaf(h1s[bi][k + 2], wv2, a2[bi]);
        a3[bi] = fmaf(h1s[bi][k + 3], wv3, a3[bi]);
      }
    }
    float bc = b2e[c];
    h2s[0][c] = fmaxf(((a0[0] + a1[0]) + (a2[0] + a3[0])) + bc, 0.f);
    h2s[1][c] = fmaxf(((a0[1] + a1[1]) + (a2[1] + a3[1])) + bc, 0.f);
  }
  __syncthreads();

  // ---- layer 3: K=512, no relu; z_all store; u row = z + noise; stage u row in s ----
  {
    float a0[2] = {0.f, 0.f}, a1[2] = {0.f, 0.f}, a2[2] = {0.f, 0.f}, a3[2] = {0.f, 0.f};
#pragma unroll 8
    for (int k = 0; k < 512; k += 4){
      float wv0 = w3e[(long)k * 512 + c];
      float wv1 = w3e[(long)(k + 1) * 512 + c];
      float wv2 = w3e[(long)(k + 2) * 512 + c];
      float wv3 = w3e[(long)(k + 3) * 512 + c];
#pragma unroll
      for (int bi = 0; bi < 2; bi++){
        a0[bi] = fmaf(h2s[bi][k],     wv0, a0[bi]);
        a1[bi] = fmaf(h2s[bi][k + 1], wv1, a1[bi]);
        a2[bi] = fmaf(h2s[bi][k + 2], wv2, a2[bi]);
        a3[bi] = fmaf(h2s[bi][k + 3], wv3, a3[bi]);
      }
    }
    float bc = b3e[c];
#pragma unroll
    for (int bi = 0; bi < 2; bi++){
      int b = b0 + bi;
      float v = ((a0[bi] + a1[bi]) + (a2[bi] + a3[bi])) + bc;
      z_all[(long)it * 65536 + (long)b * 512 + c] = v;
      float nv = jax_normal(k0r, k1r, (uint32_t)(b * 512 + c));
      float uv = v + 0.01f * nv;
      u[((long)(b * 31 + 16 + it)) * 512 + c] = uv;
      s[bi][c] = uv;   // stage for yrow (s[*][512:] stale/unused now)
    }
  }
  if (it >= 14) return;
  __syncthreads();

  // ---- yrow: Y[tok] = u_row @ W1cat (K=512, N=1024, no bias); 2 cols/thread ----
  {
    float a0[2][2] = {{0.f,0.f},{0.f,0.f}}, a1[2][2] = {{0.f,0.f},{0.f,0.f}};
    float a2[2][2] = {{0.f,0.f},{0.f,0.f}}, a3[2][2] = {{0.f,0.f},{0.f,0.f}};
    int p0 = tid, p1 = tid + 512;
#pragma unroll 4
    for (int k = 0; k < 512; k += 4){
      float w00 = W1cat[(long)k * 1024 + p0];
      float w01 = W1cat[(long)(k + 1) * 1024 + p0];
      float w02 = W1cat[(long)(k + 2) * 1024 + p0];
      float w03 = W1cat[(long)(k + 3) * 1024 + p0];
      float w10 = W1cat[(long)k * 1024 + p1];
      float w11 = W1cat[(long)(k + 1) * 1024 + p1];
      float w12 = W1cat[(long)(k + 2) * 1024 + p1];
      float w13 = W1cat[(long)(k + 3) * 1024 + p1];
#pragma unroll
      for (int bi = 0; bi < 2; bi++){
        float s0v = s[bi][k], s1v = s[bi][k + 1], s2v = s[bi][k + 2], s3v = s[bi][k + 3];
        a0[bi][0] = fmaf(s0v, w00, a0[bi][0]);
        a1[bi][0] = fmaf(s1v, w01, a1[bi][0]);
        a2[bi][0] = fmaf(s2v, w02, a2[bi][0]);
        a3[bi][0] = fmaf(s3v, w03, a3[bi][0]);
        a0[bi][1] = fmaf(s0v, w10, a0[bi][1]);
        a1[bi][1] = fmaf(s1v, w11, a1[bi][1]);
        a2[bi][1] = fmaf(s2v, w12, a2[bi][1]);
        a3[bi][1] = fmaf(s3v, w13, a3[bi][1]);
      }
    }
#pragma unroll
    for (int bi = 0; bi < 2; bi++){
      int b = b0 + bi;
      long yb = ((long)(b * 31 + 16 + it)) * 1024;
      Y[yb + p0] = (a0[bi][0] + a1[bi][0]) + (a2[bi][0] + a3[bi][0]);
      Y[yb + p1] = (a0[bi][1] + a1[bi][1]) + (a2[bi][1] + a3[bi][1]);
    }
  }
}

// ---------------- fused reverse step: dec1 -> dec2 -> dec3 + scatter into dmat ----------------
// 2 batches per block (64 blocks x 512 threads). Source row staged before any write.
__global__ __launch_bounds__(512) void revstep_k(
    float* __restrict__ dmat,
    const float* __restrict__ w1d, const float* __restrict__ b1d,
    const float* __restrict__ w2d, const float* __restrict__ b2d,
    const float* __restrict__ w3d, const float* __restrict__ b3d,
    const int* __restrict__ actions, int it)
{
  __shared__ float s[2][512];
  __shared__ float h1s[2][512];
  __shared__ float h2s[2][512];
  int tid = threadIdx.x;
  int b0 = blockIdx.x * 2;
  int tok = 30 - it;

  s[0][tid] = dmat[(long)b0 * 15872 + (long)tok * 512 + tid];
  s[1][tid] = dmat[(long)(b0 + 1) * 15872 + (long)tok * 512 + tid];
  __syncthreads();

  int c = tid;
  // ---- dec layer 1: relu ----
  {
    float a0[2] = {0.f, 0.f}, a1[2] = {0.f, 0.f}, a2[2] = {0.f, 0.f}, a3[2] = {0.f, 0.f};
#pragma unroll 8
    for (int k = 0; k < 512; k += 4){
      float wv0 = w1d[(long)k * 512 + c];
      float wv1 = w1d[(long)(k + 1) * 512 + c];
      float wv2 = w1d[(long)(k + 2) * 512 + c];
      float wv3 = w1d[(long)(k + 3) * 512 + c];
#pragma unroll
      for (int bi = 0; bi < 2; bi++){
        a0[bi] = fmaf(s[bi][k],     wv0, a0[bi]);
        a1[bi] = fmaf(s[bi][k + 1], wv1, a1[bi]);
        a2[bi] = fmaf(s[bi][k + 2], wv2, a2[bi]);
        a3[bi] = fmaf(s[bi][k + 3], wv3, a3[bi]);
      }
    }
    float bc = b1d[c];
    h1s[0][c] = fmaxf(((a0[0] + a1[0]) + (a2[0] + a3[0])) + bc, 0.f);
    h1s[1][c] = fmaxf(((a0[1] + a1[1]) + (a2[1] + a3[1])) + bc, 0.f);
  }
  __syncthreads();

  // ---- dec layer 2: relu ----
  {
    float a0[2] = {0.f, 0.f}, a1[2] = {0.f, 0.f}, a2[2] = {0.f, 0.f}, a3[2] = {0.f, 0.f};
#pragma unroll 8
    for (int k = 0; k < 512; k += 4){
      float wv0 = w2d[(long)k * 512 + c];
      float wv1 = w2d[(long)(k + 1) * 512 + c];
      float wv2 = w2d[(long)(k + 2) * 512 + c];
      float wv3 = w2d[(long)(k + 3) * 512 + c];
#pragma unroll
      for (int bi = 0; bi < 2; bi++){
        a0[bi] = fmaf(h1s[bi][k],     wv0, a0[bi]);
        a1[bi] = fmaf(h1s[bi][k + 1], wv1, a1[bi]);
        a2[bi] = fmaf(h1s[bi][k + 2], wv2, a2[bi]);
        a3[bi] = fmaf(h1s[bi][k + 3], wv3, a3[bi]);
      }
    }
    float bc = b2d[c];
    h2s[0][c] = fmaxf(((a0[0] + a1[0]) + (a2[0] + a3[0])) + bc, 0.f);
    h2s[1][c] = fmaxf(((a0[1] + a1[1]) + (a2[1] + a3[1])) + bc, 0.f);
  }
  __syncthreads();

  // ---- dec layer 3 (N=1024) + scatter: 2 cols/thread ----
  {
    float a0[2][2] = {{0.f,0.f},{0.f,0.f}}, a1[2][2] = {{0.f,0.f},{0.f,0.f}};
    float a2[2][2] = {{0.f,0.f},{0.f,0.f}}, a3[2][2] = {{0.f,0.f},{0.f,0.f}};
    int p0 = tid, p1 = tid + 512;
#pragma unroll 4
    for (int k = 0; k < 512; k += 4){
      float w00 = w3d[(long)k * 1024 + p0];
      float w01 = w3d[(long)(k + 1) * 1024 + p0];
      float w02 = w3d[(long)(k + 2) * 1024 + p0];
      float w03 = w3d[(long)(k + 3) * 1024 + p0];
      float w10 = w3d[(long)k * 1024 + p1];
      float w11 = w3d[(long)(k + 1) * 1024 + p1];
      float w12 = w3d[(long)(k + 2) * 1024 + p1];
      float w13 = w3d[(long)(k + 3) * 1024 + p1];
#pragma unroll
      for (int bi = 0; bi < 2; bi++){
        float s0v = h2s[bi][k], s1v = h2s[bi][k + 1], s2v = h2s[bi][k + 2], s3v = h2s[bi][k + 3];
        a0[bi][0] = fmaf(s0v, w00, a0[bi][0]);
        a1[bi][0] = fmaf(s1v, w01, a1[bi][0]);
        a2[bi][0] = fmaf(s2v, w02, a2[bi][0]);
        a3[bi][0] = fmaf(s3v, w03, a3[bi][0]);
        a0[bi][1] = fmaf(s0v, w10, a0[bi][1]);
        a1[bi][1] = fmaf(s1v, w11, a1[bi][1]);
        a2[bi][1] = fmaf(s2v, w12, a2[bi][1]);
        a3[bi][1] = fmaf(s3v, w13, a3[bi][1]);
      }
    }
    int fit = 14 - it;
#pragma unroll
    for (int bi = 0; bi < 2; bi++){
      int b = b0 + bi;
      int sa = actions[(b * 15 + fit) * 2];
      int sb = actions[(b * 15 + fit) * 2 + 1];
      float v0 = ((a0[bi][0] + a1[bi][0]) + (a2[bi][0] + a3[bi][0])) + b3d[p0];
      float v1 = ((a0[bi][1] + a1[bi][1]) + (a2[bi][1] + a3[bi][1])) + b3d[p1];
      dmat[((long)(b * 31 + sa)) * 512 + p0] = v0;          // p0 < 512
      dmat[((long)(b * 31 + sb)) * 512 + (p1 & 511)] = v1;  // p1 >= 512
    }
  }
}

// batched osl over all steps: grid 1920 (r = it*128 + b)
__global__ __launch_bounds__(256) void oslb_k(
    const float* __restrict__ pred, const float* __restrict__ u,
    const int* __restrict__ actions, float* __restrict__ sl, float* __restrict__ rew)
{
  int r = blockIdx.x, tid = threadIdx.x;
  int it = r >> 7, b = r & 127;
  int s0 = actions[(b * 15 + it) * 2];
  int s1 = actions[(b * 15 + it) * 2 + 1];
  const float* t0 = u + ((long)(b * 31 + s0)) * 512;
  const float* t1 = u + ((long)(b * 31 + s1)) * 512;
  const float* p = pred + (long)r * 1024;
  float s = 0.f;
  for (int k = tid; k < 512; k += 256){
    float d0 = p[k] - t0[k];       s = fmaf(d0, d0, s);
    float d1 = p[k + 512] - t1[k]; s = fmaf(d1, d1, s);
  }
  __shared__ float red[256];
  red[tid] = s; __syncthreads();
  for (int st = 128; st > 0; st >>= 1){ if (tid < st) red[tid] += red[tid + st]; __syncthreads(); }
  if (tid == 0){
    float osl = red[0] / 1024.0f;
    atomicAdd(sl + b, osl);
    rew[b * 15 + it] = -osl;
  }
}

// ---------------- init (no dmat zeroing: every cell of d is provably overwritten) ----------------
__global__ __launch_bounds__(256) void init_k(float* __restrict__ lbl,
    float* __restrict__ logits, float* __restrict__ sl, float* __restrict__ ent,
    int* __restrict__ active, float* __restrict__ zb,
    float* __restrict__ W1cat, const float* __restrict__ pol_w1, const float* __restrict__ pol_b3,
    long* __restrict__ tab_init, int* __restrict__ scat_init, long* __restrict__ tab_tok16,
    long* __restrict__ tab_mgd, int* __restrict__ scat_clf, long clf_off)
{
  long i = (long)blockIdx.x * 256 + threadIdx.x;
  if (i < 524288L){
    int k = (int)(i >> 10), n = (int)(i & 1023);
    W1cat[i] = (n < 512) ? pol_w1[(long)k * 512 + n] : pol_w1[(long)(k + 512) * 512 + (n - 512)];
  }
  if (i < 115200L){
    int rem = (int)(i % 900);
    int rr = rem / 30, cc = rem % 30;
    logits[i] = (rr < 16 && cc < 16 && rr != cc) ? pol_b3[0] : MASKV;
  }
  if (i < 30720L){
    int r = (int)i;
    int pk = r >> 7, b = r & 127;
    int ii2 = pk / 15, jr = pk % 15;
    int jj2 = jr + (jr >= ii2 ? 1 : 0);
    tab_init[r * 2]     = ((long)(b * 31 + ii2)) * 1024;
    tab_init[r * 2 + 1] = ((long)(b * 31 + jj2)) * 1024 + 512;
    scat_init[r] = b * 900 + ii2 * 30 + jj2;
  }
  if (i < 3968L){
    lbl[i] = ((i % 31) < 15) ? 1.0f : 0.0f;
    int r = (int)i;
    if (r < 1920){
      scat_clf[r] = (int)(clf_off + (long)(r & 127) * 62 + (r >> 7) * 2);
    } else {
      int rr = r - 1920;
      scat_clf[r] = (int)(clf_off + (long)(rr >> 4) * 62 + 60 - ((rr & 15) << 1));
    }
  }
  if (i < 2048L){
    active[i] = (int)(i & 15);
    tab_tok16[i] = ((long)((i >> 4) * 31 + (i & 15))) * 512;
  }
  if (i < 1920L){
    int it = (int)(i >> 7), b = (int)(i & 127);
    tab_mgd[i] = ((long)(b * 31 + 30 - it)) * 512;
  }
  if (i < 1024L)  zb[i] = 0.f;
  if (i < 128L){ sl[i] = 0.f; ent[i] = 0.f; }
}

__global__ __launch_bounds__(256) void noise_u_k(float* __restrict__ u, uint32_t k0, uint32_t k1){
  uint32_t e = blockIdx.x * 256u + threadIdx.x; // < 1048576
  uint32_t b = e >> 13, rem = e & 8191u, n = rem >> 9, ee = rem & 511u;
  float nr = jax_normal(k0, k1, e);
  long off = ((long)(b * 31u + n)) * 512 + ee;
  u[off] += 0.01f * nr;
}

__global__ __launch_bounds__(256) void build_d_k(float* __restrict__ dmat, const float* __restrict__ u){
  int e = blockIdx.x * 256 + threadIdx.x; // 65536
  int b = e >> 9, ee = e & 511;
  long off = ((long)(b * 31 + 30)) * 512 + ee;
  dmat[off] = u[off];
}

// softmax stats + entropy + gumbel-argmax + mask + active update + next tables + b3 preset
__global__ __launch_bounds__(256) void sample_k(float* __restrict__ logits, int* __restrict__ active,
    int* __restrict__ actions, float* __restrict__ lp, float* __restrict__ ent,
    int it, int A, uint32_t k0, uint32_t k1, float log_opt,
    long* __restrict__ tab_loop, int* __restrict__ scat_loop, long* __restrict__ tab_pair,
    const float* __restrict__ pol_b3)
{
  int b = blockIdx.x, tid = threadIdx.x;
  int lane = tid & 63, wid = tid >> 6;
  float* Lg = logits + (long)b * 900;
  __shared__ float rmax[4], rS[4], rT[4], rG[4];
  __shared__ int rGi[4];
  __shared__ int ss0, ss1;

  // pass 1: max
  float v = -3.4e38f;
  for (int j = tid; j < 900; j += 256) v = fmaxf(v, Lg[j]);
#pragma unroll
  for (int m = 32; m; m >>= 1) v = fmaxf(v, __shfl_xor(v, m));
  if (lane == 0) rmax[wid] = v;
  __syncthreads();
  float mx = fmaxf(fmaxf(rmax[0], rmax[1]), fmaxf(rmax[2], rmax[3]));

  // pass 2: S = sum exp(l-m); T = sum e*(l-m) over unmasked
  float s = 0.f, t = 0.f;
  for (int j = tid; j < 900; j += 256){
    float l = Lg[j];
    float d = l - mx;
    float e = expf(d);
    s += e;
    if (l > MASKV) t = fmaf(e, d, t);
  }
#pragma unroll
  for (int m = 32; m; m >>= 1){ s += __shfl_xor(s, m); t += __shfl_xor(t, m); }
  if (lane == 0){ rS[wid] = s; rT[wid] = t; }

  // pass 3: gumbel argmax (earliest index wins on ties)
  float bv = -3.4e38f; int bi = 0;
  for (int j = tid; j < 900; j += 256){
    float g = jax_gumbel(k0, k1, (uint32_t)(b * 900 + j));
    float val = Lg[j] + g;
    if (val > bv){ bv = val; bi = j; }
  }
#pragma unroll
  for (int m = 32; m; m >>= 1){
    float ov = __shfl_xor(bv, m); int oi = __shfl_xor(bi, m);
    if (ov > bv || (ov == bv && oi < bi)){ bv = ov; bi = oi; }
  }
  if (lane == 0){ rG[wid] = bv; rGi[wid] = bi; }
  __syncthreads();

  if (tid == 0){
    float S = (rS[0] + rS[1]) + (rS[2] + rS[3]);
    float T = (rT[0] + rT[1]) + (rT[2] + rT[3]);
    ent[b] += -(T / S - logf(S)) / log_opt;
    float gb = rG[0]; int gi = rGi[0];
    for (int w = 1; w < 4; w++){
      if (rG[w] > gb || (rG[w] == gb && rGi[w] < gi)){ gb = rG[w]; gi = rGi[w]; }
    }
    int sf = gi;
    int s0 = sf / 30, s1 = sf % 30;
    ss0 = s0; ss1 = s1;
    actions[(b * 15 + it) * 2] = s0;
    actions[(b * 15 + it) * 2 + 1] = s1;
    lp[b * 15 + it] = Lg[sf] - mx - logf(S);
    tab_pair[b * 2]     = ((long)(b * 31 + s0)) * 512;
    tab_pair[b * 2 + 1] = ((long)(b * 31 + s1)) * 512;
  }
  __syncthreads();
  int s0 = ss0, s1 = ss1;
  if (tid < 30){
    Lg[s0 * 30 + tid] = MASKV;
    Lg[s1 * 30 + tid] = MASKV;
    Lg[tid * 30 + s0] = MASKV;
    Lg[tid * 30 + s1] = MASKV;
  }
  if (tid == 0){
    float b3v = pol_b3[0];
    int buf[16]; int c = 0;
    for (int k = 0; k < A; k++){
      int a = active[b * 16 + k];
      if (a != s0 && a != s1) buf[c++] = a;
    }
    int nt2 = 16 + it;
    buf[c++] = nt2;
    for (int k = 0; k < c; k++) active[b * 16 + k] = buf[k];
    int na2 = c - 1;
    for (int j = 0; j < na2; j++){
      int q = buf[j];
      int r1 = j * 128 + b;
      tab_loop[r1 * 2]     = ((long)(b * 31 + nt2)) * 1024;
      tab_loop[r1 * 2 + 1] = ((long)(b * 31 + q)) * 1024 + 512;
      int sc1 = b * 900 + nt2 * 30 + q;
      scat_loop[r1] = sc1;
      logits[sc1] = b3v;
      int r2 = (na2 + j) * 128 + b;
      tab_loop[r2 * 2]     = ((long)(b * 31 + q)) * 1024;
      tab_loop[r2 * 2 + 1] = ((long)(b * 31 + nt2)) * 1024 + 512;
      int sc2 = b * 900 + q * 30 + nt2;
      scat_loop[r2] = sc2;
      logits[sc2] = b3v;
    }
  }
}

__global__ __launch_bounds__(256) void finalize_k(const float* __restrict__ rew,
    const float* __restrict__ lp, const float* __restrict__ sl, const float* __restrict__ ent,
    float* __restrict__ out_sl, float* __restrict__ out_ent, float* __restrict__ out_reinf)
{
  __shared__ float red[256];
  int tid = threadIdx.x;
  float s = 0.f;
  for (int i = tid; i < 1920; i += 256) s += rew[i];
  red[tid] = s; __syncthreads();
  for (int st = 128; st > 0; st >>= 1){ if (tid < st) red[tid] += red[tid + st]; __syncthreads(); }
  float mean = red[0] / 1920.0f; __syncthreads();
  float v = 0.f;
  for (int i = tid; i < 1920; i += 256){ float x = rew[i] - mean; v = fmaf(x, x, v); }
  red[tid] = v; __syncthreads();
  for (int st = 128; st > 0; st >>= 1){ if (tid < st) red[tid] += red[tid + st]; __syncthreads(); }
  float denom = sqrtf(red[0] / 1919.0f) + 1e-20f;
  if (tid < 128){
    out_sl[tid] = sl[tid] / 15.0f;
    out_ent[tid] = ent[tid] / 15.0f;
    float r = 0.f;
    for (int k = 0; k < 15; k++){
      float rn = (rew[tid * 15 + k] - mean) / denom;
      r = fmaf(lp[tid * 15 + k], rn, r);
    }
    out_reinf[tid] = r;
  }
}

// ---------------- host ----------------
extern "C" void kernel_launch(void* const* d_in, const int* in_sizes, int n_in,
                              void* d_out, int out_size, void* d_ws, size_t ws_size,
                              hipStream_t stream)
{
  const float* x        = (const float*)d_in[0];
  const float* lift_w   = (const float*)d_in[1];
  const float* lift_b   = (const float*)d_in[2];
  const float* unlift_w = (const float*)d_in[3];
  const float* unlift_b = (const float*)d_in[4];
  const float* enc_w1   = (const float*)d_in[5];
  const float* enc_b1   = (const float*)d_in[6];
  const float* enc_w2   = (const float*)d_in[7];
  const float* enc_b2   = (const float*)d_in[8];
  const float* enc_w3   = (const float*)d_in[9];
  const float* enc_b3   = (const float*)d_in[10];
  const float* dec_w1   = (const float*)d_in[11];
  const float* dec_b1   = (const float*)d_in[12];
  const float* dec_w2   = (const float*)d_in[13];
  const float* dec_b2   = (const float*)d_in[14];
  const float* dec_w3   = (const float*)d_in[15];
  const float* dec_b3   = (const float*)d_in[16];
  const float* clf_w1   = (const float*)d_in[17];
  const float* clf_b1   = (const float*)d_in[18];
  const float* clf_w2   = (const float*)d_in[19];
  const float* clf_b2   = (const float*)d_in[20];
  const float* clf_w3   = (const float*)d_in[21];
  const float* clf_b3   = (const float*)d_in[22];
  const float* pol_w1   = (const float*)d_in[23];
  const float* pol_b1   = (const float*)d_in[24];
  const float* pol_w2   = (const float*)d_in[25];
  const float* pol_b2   = (const float*)d_in[26];
  const float* pol_w3   = (const float*)d_in[27];
  const float* pol_b3   = (const float*)d_in[28];

  float* out = (float*)d_out;
  const long U_OFF     = 2097152;
  const long D_OFF     = 4128768;
  const long SL_OFF    = 6160384;
  const long ENT_OFF   = 6160512;
  const long CLF_OFF   = 6160640;
  const long LBL_OFF   = 6168576;
  const long REINF_OFF = 6172544;
  float* recon = out;
  float* u     = out + U_OFF;
  float* dmat  = out + D_OFF;

  char* wsb = (char*)d_ws;
  size_t wo = 0;
  auto alloc = [&](size_t bytes) -> void* {
    void* p = (void*)(wsb + wo);
    wo = (wo + bytes + 255) & ~(size_t)255;
    return p;
  };
  float* logits    = (float*)alloc(115200 * 4);
  float* Y         = (float*)alloc((size_t)3968 * 1024 * 4); // dead after fwd -> overlays:
  float* h1clf     = Y;                  // tail clf hidden1 (3968x512)
  float* pbuf      = Y + 2031616;        // dec output 1920x1024, then clf h2
  float* h2clf     = Y + 2031616;
  float* W1cat     = (float*)alloc((size_t)524288 * 4);
  float* zb        = (float*)alloc(1024 * 4);
  float* h1        = (float*)alloc((size_t)2048 * 512 * 4);
  float* h2        = (float*)alloc((size_t)2048 * 512 * 4);
  float* z_all     = (float*)alloc((size_t)15 * 65536 * 4);
  float* sl        = (float*)alloc(128 * 4);
  float* ent       = (float*)alloc(128 * 4);
  float* lp        = (float*)alloc(1920 * 4);
  float* rew       = (float*)alloc(1920 * 4);
  int*   active    = (int*)alloc(2048 * 4);
  int*   actions   = (int*)alloc(3840 * 4);
  long*  tab_init  = (long*)alloc((size_t)30720 * 2 * 8);
  int*   scat_init = (int*)alloc(30720 * 4);
  long*  tab_loop  = (long*)alloc((size_t)3584 * 2 * 8);
  int*   scat_loop = (int*)alloc(3584 * 4);
  long*  tab_pair  = (long*)alloc(256 * 8);
  long*  tab_mgd   = (long*)alloc(1920 * 8);   // contiguous with tab_tok16 -> 3968-row clf table
  long*  tab_tok16 = (long*)alloc(2048 * 8);
  int*   scat_clf  = (int*)alloc(3968 * 4);
  long*  tab_clf   = tab_mgd;
  (void)ws_size; (void)in_sizes; (void)n_in; (void)out_size;

  uint32_t k7a, k7b, ck0[15], ck1[15], mk0[15], mk1[15];
  { uint32_t a = 0, b = 7; tf2x32(0u, 42u, a, b); k7a = a; k7b = b; }
  for (int it = 0; it < 15; it++){
    { uint32_t a = 0, b = (uint32_t)(100 + it); tf2x32(0u, 42u, a, b); ck0[it] = a; ck1[it] = b; }
    { uint32_t a = 0, b = (uint32_t)(1000 + it); tf2x32(0u, 42u, a, b); mk0[it] = a; mk1[it] = b; }
  }

  auto gemm = [&](int act, const float* A, int lda, const long* atab, int anblk,
                  const float* W, const float* bs, float* C, int rows, int K, int Nn,
                  long cb, int crd, long cos, long cis){
    dim3 g(Nn / 64, rows / 64);
    if (act) gemm_k<1><<<g, 256, 0, stream>>>(A, lda, atab, anblk, W, bs, C, K, Nn, cb, crd, cos, cis);
    else     gemm_k<0><<<g, 256, 0, stream>>>(A, lda, atab, anblk, W, bs, C, K, Nn, cb, crd, cos, cis);
  };

  // ---- init ----
  init_k<<<2048, 256, 0, stream>>>(out + LBL_OFF, logits, sl, ent, active, zb,
                                   W1cat, pol_w1, pol_b3, tab_init, scat_init, tab_tok16,
                                   tab_mgd, scat_clf, CLF_OFF);

  // ---- lift + noise ----
  gemm(0, x, 1024, nullptr, 0, lift_w, lift_b, u, 2048, 1024, 512, 0, 16, 15872, 512);
  noise_u_k<<<4096, 256, 0, stream>>>(u, k7a, k7b);

  // ---- Y init for tokens 0..15 ----
  gemm(0, u, 0, tab_tok16, 1, W1cat, zb, Y, 2048, 512, 1024, 0, 16, 31744, 1024);

  // ---- initial policy logits (256x128 tiles, 512 threads) ----
  { dim3 g(4, 120);
    gemm128f_k<<<g, 512, 0, stream>>>(Y, tab_init, pol_b1, pol_w2, pol_b2, pol_w3,
                                      scat_init, logits); }

  // ---- forward merge loop: gemm64f -> sample -> fused enc/yrow step ----
  for (int it = 0; it < 15; it++){
    int A = 16 - it;
    if (it > 0){
      int rows = 256 * (15 - it);
      dim3 g(8, rows / 64);
      gemm64f_k<<<g, 256, 0, stream>>>(Y, tab_loop, pol_b1, pol_w2, pol_b2, pol_w3,
                                       scat_loop, logits);
    }
    float log_opt = (float)log((double)(A * (A - 1)));
    sample_k<<<128, 256, 0, stream>>>(logits, active, actions, lp, ent, it, A,
                                      ck0[it], ck1[it], log_opt,
                                      tab_loop, scat_loop, tab_pair, pol_b3);
    fwdstep_k<<<64, 512, 0, stream>>>(u, tab_pair, enc_w1, enc_b1, enc_w2, enc_b2,
                                      enc_w3, enc_b3, W1cat, z_all, Y, it, mk0[it], mk1[it]);
  }

  // ---- deferred batched dec over all 15 steps (1920 rows), then osl ----
  gemm(1, z_all, 512, nullptr, 0, dec_w1, dec_b1, h1, 1920, 512, 512, 0, 1, 512, 0);
  gemm(1, h1, 512, nullptr, 0, dec_w2, dec_b2, h2, 1920, 512, 512, 0, 1, 512, 0);
  gemm(0, h2, 512, nullptr, 0, dec_w3, dec_b3, pbuf, 1920, 512, 1024, 0, 1, 1024, 0);
  oslb_k<<<1920, 256, 0, stream>>>(pbuf, u, actions, sl, rew);

  // ---- d init (only token 30 active) ----
  build_d_k<<<256, 256, 0, stream>>>(dmat, u);

  // ---- reverse unmerge loop: one fused kernel per step ----
  for (int it = 0; it < 15; it++){
    revstep_k<<<64, 512, 0, stream>>>(dmat, dec_w1, dec_b1, dec_w2, dec_b2,
                                      dec_w3, dec_b3, actions, it);
  }

  // ---- combined clf over mgd rows (1920) + final d[:, :16] rows (2048) ----
  gemm(1, dmat, 0, tab_clf, 1, clf_w1, clf_b1, h1clf, 3968, 512, 512, 0, 1, 512, 0);
  gemm(1, h1clf, 512, nullptr, 0, clf_w2, clf_b2, h2clf, 3968, 512, 512, 0, 1, 512, 0);
  rowdot2_k<<<992, 256, 0, stream>>>(h2clf, 512, clf_w3, clf_b3, 512, out, scat_clf);

  // ---- recon = d[:, :16] @ unlift_w + unlift_b ----
  gemm(0, dmat, 0, tab_tok16, 1, unlift_w, unlift_b, recon, 2048, 512, 1024,
       0, 16, 16384, 1024);

  // ---- reward normalization, reinf, per-batch losses ----
  finalize_k<<<1, 256, 0, stream>>>(rew, lp, sl, ent,
                                    out + SL_OFF, out + ENT_OFF, out + REINF_OFF);
}

// Round 5
// 2868.766 us; speedup vs baseline: 1.7866x; 1.4767x over previous
//
#include <hip/hip_runtime.h>
#include <cstdint>
#include <cmath>

#define MASKV -9.0e20f

// ---------------- Threefry-2x32 (JAX-compatible) ----------------
__host__ __device__ inline void tf2x32(uint32_t k0, uint32_t k1, uint32_t& x0, uint32_t& x1){
  uint32_t ks2 = k0 ^ k1 ^ 0x1BD11BDAu;
  x0 += k0; x1 += k1;
#define TFR(r) { x0 += x1; x1 = (x1<<(r))|(x1>>(32-(r))); x1 ^= x0; }
  TFR(13) TFR(15) TFR(26) TFR(6)
  x0 += k1;  x1 += ks2 + 1u;
  TFR(17) TFR(29) TFR(16) TFR(24)
  x0 += ks2; x1 += k0 + 2u;
  TFR(13) TFR(15) TFR(26) TFR(6)
  x0 += k0;  x1 += k1 + 3u;
  TFR(17) TFR(29) TFR(16) TFR(24)
  x0 += k1;  x1 += ks2 + 4u;
  TFR(13) TFR(15) TFR(26) TFR(6)
  x0 += ks2; x1 += k0 + 5u;
#undef TFR
}

__device__ inline uint32_t rbits32(uint32_t k0, uint32_t k1, uint32_t idx){
  uint32_t x0 = 0u, x1 = idx;
  tf2x32(k0, k1, x0, x1);
  return x0 ^ x1;
}

__device__ inline float u01_from_bits(uint32_t bits){
  union { uint32_t u; float f; } c;
  c.u = (bits >> 9) | 0x3f800000u;
  return c.f - 1.0f;
}

__device__ inline float erfinv_f(float x){
  float w = -log1pf(-x*x);
  float p;
  if (w < 5.0f){
    w -= 2.5f;
    p = 2.81022636e-08f;
    p = fmaf(p, w, 3.43273939e-07f);
    p = fmaf(p, w, -3.5233877e-06f);
    p = fmaf(p, w, -4.39150654e-06f);
    p = fmaf(p, w, 0.00021858087f);
    p = fmaf(p, w, -0.00125372503f);
    p = fmaf(p, w, -0.00417768164f);
    p = fmaf(p, w, 0.246640727f);
    p = fmaf(p, w, 1.50140941f);
  } else {
    w = sqrtf(w) - 3.0f;
    p = -0.000200214257f;
    p = fmaf(p, w, 0.000100950558f);
    p = fmaf(p, w, 0.00134934322f);
    p = fmaf(p, w, -0.00367342844f);
    p = fmaf(p, w, 0.00573950773f);
    p = fmaf(p, w, -0.0076224613f);
    p = fmaf(p, w, 0.00943887047f);
    p = fmaf(p, w, 1.00167406f);
    p = fmaf(p, w, 2.83297682f);
  }
  return p * x;
}

__device__ inline float jax_normal(uint32_t k0, uint32_t k1, uint32_t idx){
  float f = u01_from_bits(rbits32(k0, k1, idx));
  float v = fmaf(f, 2.0f, -0.99999994f);
  v = fmaxf(v, -0.99999994f);
  return 1.41421356f * erfinv_f(v);
}

__device__ inline float jax_gumbel(uint32_t k0, uint32_t k1, uint32_t idx){
  float f = u01_from_bits(rbits32(k0, k1, idx));
  f = f + 1.17549435e-38f;
  f = fmaxf(f, 1.17549435e-38f);
  return -logf(-logf(f));
}

// ---------------- small tiled SGEMM (64x64 tile, 4x4 microtile) ----------------
template<int ACT>
__global__ __launch_bounds__(256) void gemm_k(
    const float* __restrict__ A, int lda,
    const long* __restrict__ atab, int anblk,
    const float* __restrict__ W, const float* __restrict__ bias,
    float* __restrict__ C, int K, int N,
    long c_base, int c_rdiv, long c_ostride, long c_istride)
{
  __shared__ float As[16][64];
  __shared__ float Ws[16][64];
  int tid = threadIdx.x;
  int c0 = blockIdx.x * 64;
  int r0 = blockIdx.y * 64;
  int lr = tid >> 2;
  int lk = (tid & 3) << 2;
  int wk = tid >> 4;
  int wc = (tid & 15) << 2;
  int tx = tid & 15;
  int ty = tid >> 4;
  long aoff0 = 0, aoff1 = 0;
  if (atab){
    const long* t = atab + (long)(r0 + lr) * anblk;
    aoff0 = t[0];
    if (anblk == 2) aoff1 = t[1];
  } else {
    aoff0 = (long)(r0 + lr) * lda;
  }
  float acc[4][4];
#pragma unroll
  for (int i = 0; i < 4; i++)
#pragma unroll
    for (int j = 0; j < 4; j++) acc[i][j] = 0.f;

  for (int k0 = 0; k0 < K; k0 += 16){
    int ka = k0 + lk;
    long ab = (atab && anblk == 2 && ka >= 512) ? (aoff1 + (ka - 512)) : (aoff0 + ka);
    float4 av = *(const float4*)(A + ab);
    As[lk + 0][lr] = av.x;
    As[lk + 1][lr] = av.y;
    As[lk + 2][lr] = av.z;
    As[lk + 3][lr] = av.w;
    float4 wv = *(const float4*)(W + (long)(k0 + wk) * N + (c0 + wc));
    *(float4*)&Ws[wk][wc] = wv;
    __syncthreads();
#pragma unroll
    for (int kk = 0; kk < 16; kk++){
      float4 a4 = *(const float4*)&As[kk][ty << 2];
      float4 w4 = *(const float4*)&Ws[kk][tx << 2];
      float aa[4] = {a4.x, a4.y, a4.z, a4.w};
      float ww[4] = {w4.x, w4.y, w4.z, w4.w};
#pragma unroll
      for (int i = 0; i < 4; i++)
#pragma unroll
        for (int j = 0; j < 4; j++)
          acc[i][j] = fmaf(aa[i], ww[j], acc[i][j]);
    }
    __syncthreads();
  }
  float4 bv = *(const float4*)(bias + c0 + (tx << 2));
  float bb[4] = {bv.x, bv.y, bv.z, bv.w};
#pragma unroll
  for (int i = 0; i < 4; i++){
    int r = r0 + (ty << 2) + i;
    long off = c_base + (long)(r / c_rdiv) * c_ostride + (long)(r % c_rdiv) * c_istride
               + c0 + (tx << 2);
    float4 v;
    float o0 = acc[i][0] + bb[0], o1 = acc[i][1] + bb[1];
    float o2 = acc[i][2] + bb[2], o3 = acc[i][3] + bb[3];
    if (ACT){ o0 = fmaxf(o0, 0.f); o1 = fmaxf(o1, 0.f); o2 = fmaxf(o2, 0.f); o3 = fmaxf(o3, 0.f); }
    v.x = o0; v.y = o1; v.z = o2; v.w = o3;
    *(float4*)(C + off) = v;
  }
}

// ---------------- 256x128-tile fused policy GEMM, 16x8 microtile ----------------
// 256 threads; LDS floats/FMA = 24/128 = 0.1875 -> ds_read cap ~88% (vs 66% at 8x8).
// Per-output k-chains, column grouping, shuffle tree identical to prior -> bitwise-same logits.
__global__ __launch_bounds__(256) void gemm128f_k(
    const float* __restrict__ Y,
    const long* __restrict__ atab,
    const float* __restrict__ b1,
    const float* __restrict__ W2, const float* __restrict__ b2,
    const float* __restrict__ w3,
    const int* __restrict__ scat, float* __restrict__ logits)
{
  __shared__ float As[16][260];
  __shared__ float Ws[16][132];
  int tid = threadIdx.x;
  int c0 = blockIdx.x * 128;
  int r0 = blockIdx.y * 256;
  int tx = tid & 15, ty = tid >> 4;   // ty in [0,16): 16 rows each (4 quarters of 4)
  int rA = tid;                        // one staged A-row per thread
  long a0r = atab[(long)(r0 + rA) * 2];
  long a1r = atab[(long)(r0 + rA) * 2 + 1];
  int wk = tid >> 5;                  // [0,8)
  int wc = (tid & 31) << 2;           // [0,128)
  float acc[16][8];
#pragma unroll
  for (int i = 0; i < 16; i++)
#pragma unroll
    for (int j = 0; j < 8; j++) acc[i][j] = 0.f;

  for (int k0 = 0; k0 < 512; k0 += 16){
    {
      float4 p = *(const float4*)(Y + a0r + k0);
      float4 q = *(const float4*)(Y + a1r + k0);
      float4 bv = *(const float4*)(b1 + k0);
      As[0][rA] = fmaxf(p.x + q.x + bv.x, 0.f);
      As[1][rA] = fmaxf(p.y + q.y + bv.y, 0.f);
      As[2][rA] = fmaxf(p.z + q.z + bv.z, 0.f);
      As[3][rA] = fmaxf(p.w + q.w + bv.w, 0.f);
    }
    {
      float4 p = *(const float4*)(Y + a0r + k0 + 4);
      float4 q = *(const float4*)(Y + a1r + k0 + 4);
      float4 bv = *(const float4*)(b1 + k0 + 4);
      As[4][rA] = fmaxf(p.x + q.x + bv.x, 0.f);
      As[5][rA] = fmaxf(p.y + q.y + bv.y, 0.f);
      As[6][rA] = fmaxf(p.z + q.z + bv.z, 0.f);
      As[7][rA] = fmaxf(p.w + q.w + bv.w, 0.f);
    }
    {
      float4 p = *(const float4*)(Y + a0r + k0 + 8);
      float4 q = *(const float4*)(Y + a1r + k0 + 8);
      float4 bv = *(const float4*)(b1 + k0 + 8);
      As[8][rA]  = fmaxf(p.x + q.x + bv.x, 0.f);
      As[9][rA]  = fmaxf(p.y + q.y + bv.y, 0.f);
      As[10][rA] = fmaxf(p.z + q.z + bv.z, 0.f);
      As[11][rA] = fmaxf(p.w + q.w + bv.w, 0.f);
    }
    {
      float4 p = *(const float4*)(Y + a0r + k0 + 12);
      float4 q = *(const float4*)(Y + a1r + k0 + 12);
      float4 bv = *(const float4*)(b1 + k0 + 12);
      As[12][rA] = fmaxf(p.x + q.x + bv.x, 0.f);
      As[13][rA] = fmaxf(p.y + q.y + bv.y, 0.f);
      As[14][rA] = fmaxf(p.z + q.z + bv.z, 0.f);
      As[15][rA] = fmaxf(p.w + q.w + bv.w, 0.f);
    }
    *(float4*)&Ws[wk][wc]     = *(const float4*)(W2 + (long)(k0 + wk) * 512 + (c0 + wc));
    *(float4*)&Ws[wk + 8][wc] = *(const float4*)(W2 + (long)(k0 + wk + 8) * 512 + (c0 + wc));
    __syncthreads();
#pragma unroll
    for (int kk = 0; kk < 16; kk++){
      float a16[16], w8[8];
      *(float4*)&a16[0]  = *(const float4*)&As[kk][(ty << 2)];
      *(float4*)&a16[4]  = *(const float4*)&As[kk][(ty << 2) + 64];
      *(float4*)&a16[8]  = *(const float4*)&As[kk][(ty << 2) + 128];
      *(float4*)&a16[12] = *(const float4*)&As[kk][(ty << 2) + 192];
      *(float4*)&w8[0] = *(const float4*)&Ws[kk][tx << 2];
      *(float4*)&w8[4] = *(const float4*)&Ws[kk][(tx << 2) + 64];
#pragma unroll
      for (int i = 0; i < 16; i++)
#pragma unroll
        for (int j = 0; j < 8; j++)
          acc[i][j] = fmaf(a16[i], w8[j], acc[i][j]);
    }
    __syncthreads();
  }
  float bb[8], w3v[8];
  *(float4*)&bb[0]  = *(const float4*)(b2 + c0 + (tx << 2));
  *(float4*)&bb[4]  = *(const float4*)(b2 + c0 + (tx << 2) + 64);
  *(float4*)&w3v[0] = *(const float4*)(w3 + c0 + (tx << 2));
  *(float4*)&w3v[4] = *(const float4*)(w3 + c0 + (tx << 2) + 64);
#pragma unroll
  for (int i = 0; i < 16; i++){
    float p = 0.f;
#pragma unroll
    for (int j = 0; j < 8; j++)
      p = fmaf(fmaxf(acc[i][j] + bb[j], 0.f), w3v[j], p);
    for (int m = 1; m < 16; m <<= 1) p += __shfl_xor(p, m);
    if (tx == 0){
      int rr = ((i >> 2) << 6) + (ty << 2) + (i & 3);
      atomicAdd(logits + scat[r0 + rr], p);
    }
  }
}

// ---------------- 64x128-tile fused policy GEMM (in-loop), 4x8 microtile ----------------
// ratio 12/32 = 0.375 -> cap ~50% (vs 33% at 4x4). grid (4, rows/64).
__global__ __launch_bounds__(256) void gemm64f_k(
    const float* __restrict__ Y,
    const long* __restrict__ atab,
    const float* __restrict__ b1,
    const float* __restrict__ W2, const float* __restrict__ b2,
    const float* __restrict__ w3,
    const int* __restrict__ scat, float* __restrict__ logits)
{
  __shared__ float As[16][68];
  __shared__ float Ws[16][132];
  int tid = threadIdx.x;
  int c0 = blockIdx.x * 128;
  int r0 = blockIdx.y * 64;
  int lr = tid >> 2;
  int lk = (tid & 3) << 2;
  int wk = tid >> 5;          // [0,8)
  int wc = (tid & 31) << 2;   // [0,128)
  int tx = tid & 15;
  int ty = tid >> 4;          // [0,16): 4 rows each
  long a0 = atab[(long)(r0 + lr) * 2];
  long a1 = atab[(long)(r0 + lr) * 2 + 1];
  float acc[4][8];
#pragma unroll
  for (int i = 0; i < 4; i++)
#pragma unroll
    for (int j = 0; j < 8; j++) acc[i][j] = 0.f;

  for (int k0 = 0; k0 < 512; k0 += 16){
    int ka = k0 + lk;
    float4 p = *(const float4*)(Y + a0 + ka);
    float4 q = *(const float4*)(Y + a1 + ka);
    float4 bb = *(const float4*)(b1 + ka);
    As[lk + 0][lr] = fmaxf(p.x + q.x + bb.x, 0.f);
    As[lk + 1][lr] = fmaxf(p.y + q.y + bb.y, 0.f);
    As[lk + 2][lr] = fmaxf(p.z + q.z + bb.z, 0.f);
    As[lk + 3][lr] = fmaxf(p.w + q.w + bb.w, 0.f);
    *(float4*)&Ws[wk][wc]     = *(const float4*)(W2 + (long)(k0 + wk) * 512 + (c0 + wc));
    *(float4*)&Ws[wk + 8][wc] = *(const float4*)(W2 + (long)(k0 + wk + 8) * 512 + (c0 + wc));
    __syncthreads();
#pragma unroll
    for (int kk = 0; kk < 16; kk++){
      float a4[4], w8[8];
      *(float4*)&a4[0] = *(const float4*)&As[kk][ty << 2];
      *(float4*)&w8[0] = *(const float4*)&Ws[kk][tx << 2];
      *(float4*)&w8[4] = *(const float4*)&Ws[kk][(tx << 2) + 64];
#pragma unroll
      for (int i = 0; i < 4; i++)
#pragma unroll
        for (int j = 0; j < 8; j++)
          acc[i][j] = fmaf(a4[i], w8[j], acc[i][j]);
    }
    __syncthreads();
  }
  float bb8[8], w38[8];
  *(float4*)&bb8[0] = *(const float4*)(b2 + c0 + (tx << 2));
  *(float4*)&bb8[4] = *(const float4*)(b2 + c0 + (tx << 2) + 64);
  *(float4*)&w38[0] = *(const float4*)(w3 + c0 + (tx << 2));
  *(float4*)&w38[4] = *(const float4*)(w3 + c0 + (tx << 2) + 64);
#pragma unroll
  for (int i = 0; i < 4; i++){
    float p = 0.f;
#pragma unroll
    for (int j = 0; j < 8; j++)
      p = fmaf(fmaxf(acc[i][j] + bb8[j], 0.f), w38[j], p);
    for (int m = 1; m < 16; m <<= 1) p += __shfl_xor(p, m);
    if (tx == 0){
      int r = r0 + (ty << 2) + i;
      atomicAdd(logits + scat[r], p);
    }
  }
}

// N=2 final layer with scatter table: one wave per row
__global__ __launch_bounds__(256) void rowdot2_k(
    const float* __restrict__ A, int lda,
    const float* __restrict__ W, const float* __restrict__ bias,
    int K, float* __restrict__ out, const int* __restrict__ scat)
{
  int wid = threadIdx.x >> 6, lane = threadIdx.x & 63;
  int r = blockIdx.x * 4 + wid;
  const float* a = A + (long)r * lda;
  float s0 = 0.f, s1 = 0.f;
  for (int k = lane; k < K; k += 64){
    float x = a[k];
    s0 = fmaf(x, W[k * 2], s0);
    s1 = fmaf(x, W[k * 2 + 1], s1);
  }
  for (int off = 32; off > 0; off >>= 1){
    s0 += __shfl_down(s0, off);
    s1 += __shfl_down(s1, off);
  }
  if (lane == 0){
    long o = scat[r];
    out[o] = s0 + bias[0];
    out[o + 1] = s1 + bias[1];
  }
}

// ---------------- wide per-layer matvec kernels (row/block, col/thread) ----------------
// enc layer1: src = pair gather (K=1024), C=512, relu. grid (2, 128)
__global__ __launch_bounds__(256) void pairmv_k(
    const float* __restrict__ u, const long* __restrict__ tab_pair,
    const float* __restrict__ W, const float* __restrict__ bias,
    float* __restrict__ dst)
{
  __shared__ float s[1024];
  int b = blockIdx.y, tid = threadIdx.x;
  int c = blockIdx.x * 256 + tid;
  long t0 = tab_pair[b * 2], t1 = tab_pair[b * 2 + 1];
  s[tid]       = u[t0 + tid];
  s[tid + 256] = u[t0 + tid + 256];
  s[tid + 512] = u[t1 + tid];
  s[tid + 768] = u[t1 + tid + 256];
  __syncthreads();
  float a0 = 0.f, a1 = 0.f, a2 = 0.f, a3 = 0.f;
#pragma unroll 8
  for (int k = 0; k < 1024; k += 4){
    a0 = fmaf(s[k],     W[(long)k * 512 + c],       a0);
    a1 = fmaf(s[k + 1], W[(long)(k + 1) * 512 + c], a1);
    a2 = fmaf(s[k + 2], W[(long)(k + 2) * 512 + c], a2);
    a3 = fmaf(s[k + 3], W[(long)(k + 3) * 512 + c], a3);
  }
  float v = ((a0 + a1) + (a2 + a3)) + bias[c];
  dst[(long)b * 512 + c] = fmaxf(v, 0.f);
}

// generic K=512 -> C=512 relu layer. grid (2, 128)
__global__ __launch_bounds__(256) void mvrelu_k(
    const float* __restrict__ src, long sstride,
    const float* __restrict__ W, const float* __restrict__ bias,
    float* __restrict__ dst)
{
  __shared__ float s[512];
  int b = blockIdx.y, tid = threadIdx.x;
  int c = blockIdx.x * 256 + tid;
  const float* sr = src + (long)b * sstride;
  s[tid] = sr[tid];
  s[tid + 256] = sr[tid + 256];
  __syncthreads();
  float a0 = 0.f, a1 = 0.f, a2 = 0.f, a3 = 0.f;
#pragma unroll 8
  for (int k = 0; k < 512; k += 4){
    a0 = fmaf(s[k],     W[(long)k * 512 + c],       a0);
    a1 = fmaf(s[k + 1], W[(long)(k + 1) * 512 + c], a1);
    a2 = fmaf(s[k + 2], W[(long)(k + 2) * 512 + c], a2);
    a3 = fmaf(s[k + 3], W[(long)(k + 3) * 512 + c], a3);
  }
  float v = ((a0 + a1) + (a2 + a3)) + bias[c];
  dst[(long)b * 512 + c] = fmaxf(v, 0.f);
}

// enc layer3: z = h2@W + b (no relu); store z, and u token row = z + noise. grid (2, 128)
__global__ __launch_bounds__(256) void lay3z_k(
    const float* __restrict__ src,
    const float* __restrict__ W, const float* __restrict__ bias,
    float* __restrict__ z_all, float* __restrict__ u,
    int it, uint32_t k0, uint32_t k1)
{
  __shared__ float s[512];
  int b = blockIdx.y, tid = threadIdx.x;
  int c = blockIdx.x * 256 + tid;
  const float* sr = src + (long)b * 512;
  s[tid] = sr[tid];
  s[tid + 256] = sr[tid + 256];
  __syncthreads();
  float a0 = 0.f, a1 = 0.f, a2 = 0.f, a3 = 0.f;
#pragma unroll 8
  for (int k = 0; k < 512; k += 4){
    a0 = fmaf(s[k],     W[(long)k * 512 + c],       a0);
    a1 = fmaf(s[k + 1], W[(long)(k + 1) * 512 + c], a1);
    a2 = fmaf(s[k + 2], W[(long)(k + 2) * 512 + c], a2);
    a3 = fmaf(s[k + 3], W[(long)(k + 3) * 512 + c], a3);
  }
  float v = ((a0 + a1) + (a2 + a3)) + bias[c];
  z_all[(long)it * 65536 + (long)b * 512 + c] = v;
  float nv = jax_normal(k0, k1, (uint32_t)(b * 512 + c));
  u[((long)(b * 31 + 16 + it)) * 512 + c] = v + 0.01f * nv;
}

// Y row for new token: Y[tok] = u[tok] @ W1cat (no bias). grid (4, 128)
__global__ __launch_bounds__(256) void yrow_k(
    const float* __restrict__ u, const float* __restrict__ W1cat,
    float* __restrict__ Y, int it)
{
  __shared__ float s[512];
  int b = blockIdx.y, tid = threadIdx.x;
  int c = blockIdx.x * 256 + tid;
  const float* sr = u + ((long)(b * 31 + 16 + it)) * 512;
  s[tid] = sr[tid];
  s[tid + 256] = sr[tid + 256];
  __syncthreads();
  float a0 = 0.f, a1 = 0.f, a2 = 0.f, a3 = 0.f;
#pragma unroll 8
  for (int k = 0; k < 512; k += 4){
    a0 = fmaf(s[k],     W1cat[(long)k * 1024 + c],       a0);
    a1 = fmaf(s[k + 1], W1cat[(long)(k + 1) * 1024 + c], a1);
    a2 = fmaf(s[k + 2], W1cat[(long)(k + 2) * 1024 + c], a2);
    a3 = fmaf(s[k + 3], W1cat[(long)(k + 3) * 1024 + c], a3);
  }
  Y[((long)(b * 31 + 16 + it)) * 1024 + c] = (a0 + a1) + (a2 + a3);
}

// reverse layer3 + scatter into dmat. grid (4, 128)
__global__ __launch_bounds__(256) void rev3_k(
    const float* __restrict__ src,
    const float* __restrict__ W, const float* __restrict__ bias,
    float* __restrict__ dmat, const int* __restrict__ actions, int it)
{
  __shared__ float s[512];
  int b = blockIdx.y, tid = threadIdx.x;
  int p = blockIdx.x * 256 + tid;
  const float* sr = src + (long)b * 512;
  s[tid] = sr[tid];
  s[tid + 256] = sr[tid + 256];
  __syncthreads();
  float a0 = 0.f, a1 = 0.f, a2 = 0.f, a3 = 0.f;
#pragma unroll 8
  for (int k = 0; k < 512; k += 4){
    a0 = fmaf(s[k],     W[(long)k * 1024 + p],       a0);
    a1 = fmaf(s[k + 1], W[(long)(k + 1) * 1024 + p], a1);
    a2 = fmaf(s[k + 2], W[(long)(k + 2) * 1024 + p], a2);
    a3 = fmaf(s[k + 3], W[(long)(k + 3) * 1024 + p], a3);
  }
  float v = ((a0 + a1) + (a2 + a3)) + bias[p];
  int fit = 14 - it;
  int s0 = actions[(b * 15 + fit) * 2];
  int s1 = actions[(b * 15 + fit) * 2 + 1];
  int node = (p < 512) ? s0 : s1;
  int ee = p & 511;
  dmat[((long)(b * 31 + node)) * 512 + ee] = v;
}

// batched osl over all steps: grid 1920 (r = it*128 + b)
__global__ __launch_bounds__(256) void oslb_k(
    const float* __restrict__ pred, const float* __restrict__ u,
    const int* __restrict__ actions, float* __restrict__ sl, float* __restrict__ rew)
{
  int r = blockIdx.x, tid = threadIdx.x;
  int it = r >> 7, b = r & 127;
  int s0 = actions[(b * 15 + it) * 2];
  int s1 = actions[(b * 15 + it) * 2 + 1];
  const float* t0 = u + ((long)(b * 31 + s0)) * 512;
  const float* t1 = u + ((long)(b * 31 + s1)) * 512;
  const float* p = pred + (long)r * 1024;
  float s = 0.f;
  for (int k = tid; k < 512; k += 256){
    float d0 = p[k] - t0[k];       s = fmaf(d0, d0, s);
    float d1 = p[k + 512] - t1[k]; s = fmaf(d1, d1, s);
  }
  __shared__ float red[256];
  red[tid] = s; __syncthreads();
  for (int st = 128; st > 0; st >>= 1){ if (tid < st) red[tid] += red[tid + st]; __syncthreads(); }
  if (tid == 0){
    float osl = red[0] / 1024.0f;
    atomicAdd(sl + b, osl);
    rew[b * 15 + it] = -osl;
  }
}

// ---------------- init (no dmat zeroing: every cell of d is provably overwritten) ----------------
__global__ __launch_bounds__(256) void init_k(float* __restrict__ lbl,
    float* __restrict__ logits, float* __restrict__ sl, float* __restrict__ ent,
    int* __restrict__ active, float* __restrict__ zb,
    float* __restrict__ W1cat, const float* __restrict__ pol_w1, const float* __restrict__ pol_b3,
    long* __restrict__ tab_init, int* __restrict__ scat_init, long* __restrict__ tab_tok16,
    long* __restrict__ tab_mgd, int* __restrict__ scat_clf, long clf_off)
{
  long i = (long)blockIdx.x * 256 + threadIdx.x;
  if (i < 524288L){
    int k = (int)(i >> 10), n = (int)(i & 1023);
    W1cat[i] = (n < 512) ? pol_w1[(long)k * 512 + n] : pol_w1[(long)(k + 512) * 512 + (n - 512)];
  }
  if (i < 115200L){
    int rem = (int)(i % 900);
    int rr = rem / 30, cc = rem % 30;
    logits[i] = (rr < 16 && cc < 16 && rr != cc) ? pol_b3[0] : MASKV;
  }
  if (i < 30720L){
    int r = (int)i;
    int pk = r >> 7, b = r & 127;
    int ii2 = pk / 15, jr = pk % 15;
    int jj2 = jr + (jr >= ii2 ? 1 : 0);
    tab_init[r * 2]     = ((long)(b * 31 + ii2)) * 1024;
    tab_init[r * 2 + 1] = ((long)(b * 31 + jj2)) * 1024 + 512;
    scat_init[r] = b * 900 + ii2 * 30 + jj2;
  }
  if (i < 3968L){
    lbl[i] = ((i % 31) < 15) ? 1.0f : 0.0f;
    int r = (int)i;
    if (r < 1920){
      scat_clf[r] = (int)(clf_off + (long)(r & 127) * 62 + (r >> 7) * 2);
    } else {
      int rr = r - 1920;
      scat_clf[r] = (int)(clf_off + (long)(rr >> 4) * 62 + 60 - ((rr & 15) << 1));
    }
  }
  if (i < 2048L){
    active[i] = (int)(i & 15);
    tab_tok16[i] = ((long)((i >> 4) * 31 + (i & 15))) * 512;
  }
  if (i < 1920L){
    int it = (int)(i >> 7), b = (int)(i & 127);
    tab_mgd[i] = ((long)(b * 31 + 30 - it)) * 512;
  }
  if (i < 1024L)  zb[i] = 0.f;
  if (i < 128L){ sl[i] = 0.f; ent[i] = 0.f; }
}

__global__ __launch_bounds__(256) void noise_u_k(float* __restrict__ u, uint32_t k0, uint32_t k1){
  uint32_t e = blockIdx.x * 256u + threadIdx.x; // < 1048576
  uint32_t b = e >> 13, rem = e & 8191u, n = rem >> 9, ee = rem & 511u;
  float nr = jax_normal(k0, k1, e);
  long off = ((long)(b * 31u + n)) * 512 + ee;
  u[off] += 0.01f * nr;
}

__global__ __launch_bounds__(256) void build_d_k(float* __restrict__ dmat, const float* __restrict__ u){
  int e = blockIdx.x * 256 + threadIdx.x; // 65536
  int b = e >> 9, ee = e & 511;
  long off = ((long)(b * 31 + 30)) * 512 + ee;
  dmat[off] = u[off];
}

// softmax stats + entropy + gumbel-argmax + mask + active update + next tables + b3 preset
__global__ __launch_bounds__(256) void sample_k(float* __restrict__ logits, int* __restrict__ active,
    int* __restrict__ actions, float* __restrict__ lp, float* __restrict__ ent,
    int it, int A, uint32_t k0, uint32_t k1, float log_opt,
    long* __restrict__ tab_loop, int* __restrict__ scat_loop, long* __restrict__ tab_pair,
    const float* __restrict__ pol_b3)
{
  int b = blockIdx.x, tid = threadIdx.x;
  int lane = tid & 63, wid = tid >> 6;
  float* Lg = logits + (long)b * 900;
  __shared__ float rmax[4], rS[4], rT[4], rG[4];
  __shared__ int rGi[4];
  __shared__ int ss0, ss1;

  // pass 1: max
  float v = -3.4e38f;
  for (int j = tid; j < 900; j += 256) v = fmaxf(v, Lg[j]);
#pragma unroll
  for (int m = 32; m; m >>= 1) v = fmaxf(v, __shfl_xor(v, m));
  if (lane == 0) rmax[wid] = v;
  __syncthreads();
  float mx = fmaxf(fmaxf(rmax[0], rmax[1]), fmaxf(rmax[2], rmax[3]));

  // pass 2: S = sum exp(l-m); T = sum e*(l-m) over unmasked
  float s = 0.f, t = 0.f;
  for (int j = tid; j < 900; j += 256){
    float l = Lg[j];
    float d = l - mx;
    float e = expf(d);
    s += e;
    if (l > MASKV) t = fmaf(e, d, t);
  }
#pragma unroll
  for (int m = 32; m; m >>= 1){ s += __shfl_xor(s, m); t += __shfl_xor(t, m); }
  if (lane == 0){ rS[wid] = s; rT[wid] = t; }

  // pass 3: gumbel argmax (earliest index wins on ties)
  float bv = -3.4e38f; int bi = 0;
  for (int j = tid; j < 900; j += 256){
    float g = jax_gumbel(k0, k1, (uint32_t)(b * 900 + j));
    float val = Lg[j] + g;
    if (val > bv){ bv = val; bi = j; }
  }
#pragma unroll
  for (int m = 32; m; m >>= 1){
    float ov = __shfl_xor(bv, m); int oi = __shfl_xor(bi, m);
    if (ov > bv || (ov == bv && oi < bi)){ bv = ov; bi = oi; }
  }
  if (lane == 0){ rG[wid] = bv; rGi[wid] = bi; }
  __syncthreads();

  if (tid == 0){
    float S = (rS[0] + rS[1]) + (rS[2] + rS[3]);
    float T = (rT[0] + rT[1]) + (rT[2] + rT[3]);
    ent[b] += -(T / S - logf(S)) / log_opt;
    float gb = rG[0]; int gi = rGi[0];
    for (int w = 1; w < 4; w++){
      if (rG[w] > gb || (rG[w] == gb && rGi[w] < gi)){ gb = rG[w]; gi = rGi[w]; }
    }
    int sf = gi;
    int s0 = sf / 30, s1 = sf % 30;
    ss0 = s0; ss1 = s1;
    actions[(b * 15 + it) * 2] = s0;
    actions[(b * 15 + it) * 2 + 1] = s1;
    lp[b * 15 + it] = Lg[sf] - mx - logf(S);
    tab_pair[b * 2]     = ((long)(b * 31 + s0)) * 512;
    tab_pair[b * 2 + 1] = ((long)(b * 31 + s1)) * 512;
  }
  __syncthreads();
  int s0 = ss0, s1 = ss1;
  if (tid < 30){
    Lg[s0 * 30 + tid] = MASKV;
    Lg[s1 * 30 + tid] = MASKV;
    Lg[tid * 30 + s0] = MASKV;
    Lg[tid * 30 + s1] = MASKV;
  }
  if (tid == 0){
    float b3v = pol_b3[0];
    int buf[16]; int c = 0;
    for (int k = 0; k < A; k++){
      int a = active[b * 16 + k];
      if (a != s0 && a != s1) buf[c++] = a;
    }
    int nt2 = 16 + it;
    buf[c++] = nt2;
    for (int k = 0; k < c; k++) active[b * 16 + k] = buf[k];
    int na2 = c - 1;
    for (int j = 0; j < na2; j++){
      int q = buf[j];
      int r1 = j * 128 + b;
      tab_loop[r1 * 2]     = ((long)(b * 31 + nt2)) * 1024;
      tab_loop[r1 * 2 + 1] = ((long)(b * 31 + q)) * 1024 + 512;
      int sc1 = b * 900 + nt2 * 30 + q;
      scat_loop[r1] = sc1;
      logits[sc1] = b3v;
      int r2 = (na2 + j) * 128 + b;
      tab_loop[r2 * 2]     = ((long)(b * 31 + q)) * 1024;
      tab_loop[r2 * 2 + 1] = ((long)(b * 31 + nt2)) * 1024 + 512;
      int sc2 = b * 900 + q * 30 + nt2;
      scat_loop[r2] = sc2;
      logits[sc2] = b3v;
    }
  }
}

__global__ __launch_bounds__(256) void finalize_k(const float* __restrict__ rew,
    const float* __restrict__ lp, const float* __restrict__ sl, const float* __restrict__ ent,
    float* __restrict__ out_sl, float* __restrict__ out_ent, float* __restrict__ out_reinf)
{
  __shared__ float red[256];
  int tid = threadIdx.x;
  float s = 0.f;
  for (int i = tid; i < 1920; i += 256) s += rew[i];
  red[tid] = s; __syncthreads();
  for (int st = 128; st > 0; st >>= 1){ if (tid < st) red[tid] += red[tid + st]; __syncthreads(); }
  float mean = red[0] / 1920.0f; __syncthreads();
  float v = 0.f;
  for (int i = tid; i < 1920; i += 256){ float x = rew[i] - mean; v = fmaf(x, x, v); }
  red[tid] = v; __syncthreads();
  for (int st = 128; st > 0; st >>= 1){ if (tid < st) red[tid] += red[tid + st]; __syncthreads(); }
  float denom = sqrtf(red[0] / 1919.0f) + 1e-20f;
  if (tid < 128){
    out_sl[tid] = sl[tid] / 15.0f;
    out_ent[tid] = ent[tid] / 15.0f;
    float r = 0.f;
    for (int k = 0; k < 15; k++){
      float rn = (rew[tid * 15 + k] - mean) / denom;
      r = fmaf(lp[tid * 15 + k], rn, r);
    }
    out_reinf[tid] = r;
  }
}

// ---------------- host ----------------
extern "C" void kernel_launch(void* const* d_in, const int* in_sizes, int n_in,
                              void* d_out, int out_size, void* d_ws, size_t ws_size,
                              hipStream_t stream)
{
  const float* x        = (const float*)d_in[0];
  const float* lift_w   = (const float*)d_in[1];
  const float* lift_b   = (const float*)d_in[2];
  const float* unlift_w = (const float*)d_in[3];
  const float* unlift_b = (const float*)d_in[4];
  const float* enc_w1   = (const float*)d_in[5];
  const float* enc_b1   = (const float*)d_in[6];
  const float* enc_w2   = (const float*)d_in[7];
  const float* enc_b2   = (const float*)d_in[8];
  const float* enc_w3   = (const float*)d_in[9];
  const float* enc_b3   = (const float*)d_in[10];
  const float* dec_w1   = (const float*)d_in[11];
  const float* dec_b1   = (const float*)d_in[12];
  const float* dec_w2   = (const float*)d_in[13];
  const float* dec_b2   = (const float*)d_in[14];
  const float* dec_w3   = (const float*)d_in[15];
  const float* dec_b3   = (const float*)d_in[16];
  const float* clf_w1   = (const float*)d_in[17];
  const float* clf_b1   = (const float*)d_in[18];
  const float* clf_w2   = (const float*)d_in[19];
  const float* clf_b2   = (const float*)d_in[20];
  const float* clf_w3   = (const float*)d_in[21];
  const float* clf_b3   = (const float*)d_in[22];
  const float* pol_w1   = (const float*)d_in[23];
  const float* pol_b1   = (const float*)d_in[24];
  const float* pol_w2   = (const float*)d_in[25];
  const float* pol_b2   = (const float*)d_in[26];
  const float* pol_w3   = (const float*)d_in[27];
  const float* pol_b3   = (const float*)d_in[28];

  float* out = (float*)d_out;
  const long U_OFF     = 2097152;
  const long D_OFF     = 4128768;
  const long SL_OFF    = 6160384;
  const long ENT_OFF   = 6160512;
  const long CLF_OFF   = 6160640;
  const long LBL_OFF   = 6168576;
  const long REINF_OFF = 6172544;
  float* recon = out;
  float* u     = out + U_OFF;
  float* dmat  = out + D_OFF;

  char* wsb = (char*)d_ws;
  size_t wo = 0;
  auto alloc = [&](size_t bytes) -> void* {
    void* p = (void*)(wsb + wo);
    wo = (wo + bytes + 255) & ~(size_t)255;
    return p;
  };
  float* logits    = (float*)alloc(115200 * 4);
  float* Y         = (float*)alloc((size_t)3968 * 1024 * 4); // dead after fwd -> overlays:
  float* h1clf     = Y;                  // tail clf hidden1 (3968x512)
  float* pbuf      = Y + 2031616;        // dec output 1920x1024, then clf h2
  float* h2clf     = Y + 2031616;
  float* W1cat     = (float*)alloc((size_t)524288 * 4);
  float* zb        = (float*)alloc(1024 * 4);
  float* h1        = (float*)alloc((size_t)2048 * 512 * 4);
  float* h2        = (float*)alloc((size_t)2048 * 512 * 4);
  float* z_all     = (float*)alloc((size_t)15 * 65536 * 4);
  float* sl        = (float*)alloc(128 * 4);
  float* ent       = (float*)alloc(128 * 4);
  float* lp        = (float*)alloc(1920 * 4);
  float* rew       = (float*)alloc(1920 * 4);
  int*   active    = (int*)alloc(2048 * 4);
  int*   actions   = (int*)alloc(3840 * 4);
  long*  tab_init  = (long*)alloc((size_t)30720 * 2 * 8);
  int*   scat_init = (int*)alloc(30720 * 4);
  long*  tab_loop  = (long*)alloc((size_t)3584 * 2 * 8);
  int*   scat_loop = (int*)alloc(3584 * 4);
  long*  tab_pair  = (long*)alloc(256 * 8);
  long*  tab_mgd   = (long*)alloc(1920 * 8);   // contiguous with tab_tok16 -> 3968-row clf table
  long*  tab_tok16 = (long*)alloc(2048 * 8);
  int*   scat_clf  = (int*)alloc(3968 * 4);
  long*  tab_clf   = tab_mgd;
  (void)ws_size; (void)in_sizes; (void)n_in; (void)out_size;

  uint32_t k7a, k7b, ck0[15], ck1[15], mk0[15], mk1[15];
  { uint32_t a = 0, b = 7; tf2x32(0u, 42u, a, b); k7a = a; k7b = b; }
  for (int it = 0; it < 15; it++){
    { uint32_t a = 0, b = (uint32_t)(100 + it); tf2x32(0u, 42u, a, b); ck0[it] = a; ck1[it] = b; }
    { uint32_t a = 0, b = (uint32_t)(1000 + it); tf2x32(0u, 42u, a, b); mk0[it] = a; mk1[it] = b; }
  }

  auto gemm = [&](int act, const float* A, int lda, const long* atab, int anblk,
                  const float* W, const float* bs, float* C, int rows, int K, int Nn,
                  long cb, int crd, long cos, long cis){
    dim3 g(Nn / 64, rows / 64);
    if (act) gemm_k<1><<<g, 256, 0, stream>>>(A, lda, atab, anblk, W, bs, C, K, Nn, cb, crd, cos, cis);
    else     gemm_k<0><<<g, 256, 0, stream>>>(A, lda, atab, anblk, W, bs, C, K, Nn, cb, crd, cos, cis);
  };

  // ---- init ----
  init_k<<<2048, 256, 0, stream>>>(out + LBL_OFF, logits, sl, ent, active, zb,
                                   W1cat, pol_w1, pol_b3, tab_init, scat_init, tab_tok16,
                                   tab_mgd, scat_clf, CLF_OFF);

  // ---- lift + noise ----
  gemm(0, x, 1024, nullptr, 0, lift_w, lift_b, u, 2048, 1024, 512, 0, 16, 15872, 512);
  noise_u_k<<<4096, 256, 0, stream>>>(u, k7a, k7b);

  // ---- Y init for tokens 0..15 ----
  gemm(0, u, 0, tab_tok16, 1, W1cat, zb, Y, 2048, 512, 1024, 0, 16, 31744, 1024);

  // ---- initial policy logits (256x128 tiles, 16x8 microtile, 256 threads) ----
  { dim3 g(4, 120);
    gemm128f_k<<<g, 256, 0, stream>>>(Y, tab_init, pol_b1, pol_w2, pol_b2, pol_w3,
                                      scat_init, logits); }

  // ---- forward merge loop (round-2 structure: per-layer matvecs, max fill) ----
  for (int it = 0; it < 15; it++){
    int A = 16 - it;
    if (it > 0){
      int rows = 256 * (15 - it);
      dim3 g(4, rows / 64);
      gemm64f_k<<<g, 256, 0, stream>>>(Y, tab_loop, pol_b1, pol_w2, pol_b2, pol_w3,
                                       scat_loop, logits);
    }
    float log_opt = (float)log((double)(A * (A - 1)));
    sample_k<<<128, 256, 0, stream>>>(logits, active, actions, lp, ent, it, A,
                                      ck0[it], ck1[it], log_opt,
                                      tab_loop, scat_loop, tab_pair, pol_b3);
    { dim3 g(2, 128);
      pairmv_k<<<g, 256, 0, stream>>>(u, tab_pair, enc_w1, enc_b1, h1); }
    { dim3 g(2, 128);
      mvrelu_k<<<g, 256, 0, stream>>>(h1, 512, enc_w2, enc_b2, h2); }
    { dim3 g(2, 128);
      lay3z_k<<<g, 256, 0, stream>>>(h2, enc_w3, enc_b3, z_all, u, it, mk0[it], mk1[it]); }
    if (it < 14){
      dim3 g(4, 128);
      yrow_k<<<g, 256, 0, stream>>>(u, W1cat, Y, it);
    }
  }

  // ---- deferred batched dec over all 15 steps (1920 rows), then osl ----
  gemm(1, z_all, 512, nullptr, 0, dec_w1, dec_b1, h1, 1920, 512, 512, 0, 1, 512, 0);
  gemm(1, h1, 512, nullptr, 0, dec_w2, dec_b2, h2, 1920, 512, 512, 0, 1, 512, 0);
  gemm(0, h2, 512, nullptr, 0, dec_w3, dec_b3, pbuf, 1920, 512, 1024, 0, 1, 1024, 0);
  oslb_k<<<1920, 256, 0, stream>>>(pbuf, u, actions, sl, rew);

  // ---- d init (only token 30 active) ----
  build_d_k<<<256, 256, 0, stream>>>(dmat, u);

  // ---- reverse unmerge loop (round-2 structure): 3 wide layers per step ----
  for (int it = 0; it < 15; it++){
    int tok = 30 - it;
    { dim3 g(2, 128);
      mvrelu_k<<<g, 256, 0, stream>>>(dmat + (long)tok * 512, 15872, dec_w1, dec_b1, h1); }
    { dim3 g(2, 128);
      mvrelu_k<<<g, 256, 0, stream>>>(h1, 512, dec_w2, dec_b2, h2); }
    { dim3 g(4, 128);
      rev3_k<<<g, 256, 0, stream>>>(h2, dec_w3, dec_b3, dmat, actions, it); }
  }

  // ---- combined clf over mgd rows (1920) + final d[:, :16] rows (2048) ----
  gemm(1, dmat, 0, tab_clf, 1, clf_w1, clf_b1, h1clf, 3968, 512, 512, 0, 1, 512, 0);
  gemm(1, h1clf, 512, nullptr, 0, clf_w2, clf_b2, h2clf, 3968, 512, 512, 0, 1, 512, 0);
  rowdot2_k<<<992, 256, 0, stream>>>(h2clf, 512, clf_w3, clf_b3, 512, out, scat_clf);

  // ---- recon = d[:, :16] @ unlift_w + unlift_b ----
  gemm(0, dmat, 0, tab_tok16, 1, unlift_w, unlift_b, recon, 2048, 512, 1024,
       0, 16, 16384, 1024);

  // ---- reward normalization, reinf, per-batch losses ----
  finalize_k<<<1, 256, 0, stream>>>(rew, lp, sl, ent,
                                    out + SL_OFF, out + ENT_OFF, out + REINF_OFF);
}

// Round 6
// 2553.281 us; speedup vs baseline: 2.0074x; 1.1236x over previous
//
#include <hip/hip_runtime.h>
#include <cstdint>
#include <cmath>

#define MASKV -9.0e20f

// ---------------- Threefry-2x32 (JAX-compatible) ----------------
__host__ __device__ inline void tf2x32(uint32_t k0, uint32_t k1, uint32_t& x0, uint32_t& x1){
  uint32_t ks2 = k0 ^ k1 ^ 0x1BD11BDAu;
  x0 += k0; x1 += k1;
#define TFR(r) { x0 += x1; x1 = (x1<<(r))|(x1>>(32-(r))); x1 ^= x0; }
  TFR(13) TFR(15) TFR(26) TFR(6)
  x0 += k1;  x1 += ks2 + 1u;
  TFR(17) TFR(29) TFR(16) TFR(24)
  x0 += ks2; x1 += k0 + 2u;
  TFR(13) TFR(15) TFR(26) TFR(6)
  x0 += k0;  x1 += k1 + 3u;
  TFR(17) TFR(29) TFR(16) TFR(24)
  x0 += k1;  x1 += ks2 + 4u;
  TFR(13) TFR(15) TFR(26) TFR(6)
  x0 += ks2; x1 += k0 + 5u;
#undef TFR
}

__device__ inline uint32_t rbits32(uint32_t k0, uint32_t k1, uint32_t idx){
  uint32_t x0 = 0u, x1 = idx;
  tf2x32(k0, k1, x0, x1);
  return x0 ^ x1;
}

__device__ inline float u01_from_bits(uint32_t bits){
  union { uint32_t u; float f; } c;
  c.u = (bits >> 9) | 0x3f800000u;
  return c.f - 1.0f;
}

__device__ inline float erfinv_f(float x){
  float w = -log1pf(-x*x);
  float p;
  if (w < 5.0f){
    w -= 2.5f;
    p = 2.81022636e-08f;
    p = fmaf(p, w, 3.43273939e-07f);
    p = fmaf(p, w, -3.5233877e-06f);
    p = fmaf(p, w, -4.39150654e-06f);
    p = fmaf(p, w, 0.00021858087f);
    p = fmaf(p, w, -0.00125372503f);
    p = fmaf(p, w, -0.00417768164f);
    p = fmaf(p, w, 0.246640727f);
    p = fmaf(p, w, 1.50140941f);
  } else {
    w = sqrtf(w) - 3.0f;
    p = -0.000200214257f;
    p = fmaf(p, w, 0.000100950558f);
    p = fmaf(p, w, 0.00134934322f);
    p = fmaf(p, w, -0.00367342844f);
    p = fmaf(p, w, 0.00573950773f);
    p = fmaf(p, w, -0.0076224613f);
    p = fmaf(p, w, 0.00943887047f);
    p = fmaf(p, w, 1.00167406f);
    p = fmaf(p, w, 2.83297682f);
  }
  return p * x;
}

__device__ inline float jax_normal(uint32_t k0, uint32_t k1, uint32_t idx){
  float f = u01_from_bits(rbits32(k0, k1, idx));
  float v = fmaf(f, 2.0f, -0.99999994f);
  v = fmaxf(v, -0.99999994f);
  return 1.41421356f * erfinv_f(v);
}

__device__ inline float jax_gumbel(uint32_t k0, uint32_t k1, uint32_t idx){
  float f = u01_from_bits(rbits32(k0, k1, idx));
  f = f + 1.17549435e-38f;
  f = fmaxf(f, 1.17549435e-38f);
  return -logf(-logf(f));
}

// ---------------- small tiled SGEMM (64x64 tile, 4x4 microtile) ----------------
template<int ACT>
__global__ __launch_bounds__(256) void gemm_k(
    const float* __restrict__ A, int lda,
    const long* __restrict__ atab, int anblk,
    const float* __restrict__ W, const float* __restrict__ bias,
    float* __restrict__ C, int K, int N,
    long c_base, int c_rdiv, long c_ostride, long c_istride)
{
  __shared__ float As[16][64];
  __shared__ float Ws[16][64];
  int tid = threadIdx.x;
  int c0 = blockIdx.x * 64;
  int r0 = blockIdx.y * 64;
  int lr = tid >> 2;
  int lk = (tid & 3) << 2;
  int wk = tid >> 4;
  int wc = (tid & 15) << 2;
  int tx = tid & 15;
  int ty = tid >> 4;
  long aoff0 = 0, aoff1 = 0;
  if (atab){
    const long* t = atab + (long)(r0 + lr) * anblk;
    aoff0 = t[0];
    if (anblk == 2) aoff1 = t[1];
  } else {
    aoff0 = (long)(r0 + lr) * lda;
  }
  float acc[4][4];
#pragma unroll
  for (int i = 0; i < 4; i++)
#pragma unroll
    for (int j = 0; j < 4; j++) acc[i][j] = 0.f;

  for (int k0 = 0; k0 < K; k0 += 16){
    int ka = k0 + lk;
    long ab = (atab && anblk == 2 && ka >= 512) ? (aoff1 + (ka - 512)) : (aoff0 + ka);
    float4 av = *(const float4*)(A + ab);
    As[lk + 0][lr] = av.x;
    As[lk + 1][lr] = av.y;
    As[lk + 2][lr] = av.z;
    As[lk + 3][lr] = av.w;
    float4 wv = *(const float4*)(W + (long)(k0 + wk) * N + (c0 + wc));
    *(float4*)&Ws[wk][wc] = wv;
    __syncthreads();
#pragma unroll
    for (int kk = 0; kk < 16; kk++){
      float4 a4 = *(const float4*)&As[kk][ty << 2];
      float4 w4 = *(const float4*)&Ws[kk][tx << 2];
      float aa[4] = {a4.x, a4.y, a4.z, a4.w};
      float ww[4] = {w4.x, w4.y, w4.z, w4.w};
#pragma unroll
      for (int i = 0; i < 4; i++)
#pragma unroll
        for (int j = 0; j < 4; j++)
          acc[i][j] = fmaf(aa[i], ww[j], acc[i][j]);
    }
    __syncthreads();
  }
  float4 bv = *(const float4*)(bias + c0 + (tx << 2));
  float bb[4] = {bv.x, bv.y, bv.z, bv.w};
#pragma unroll
  for (int i = 0; i < 4; i++){
    int r = r0 + (ty << 2) + i;
    long off = c_base + (long)(r / c_rdiv) * c_ostride + (long)(r % c_rdiv) * c_istride
               + c0 + (tx << 2);
    float4 v;
    float o0 = acc[i][0] + bb[0], o1 = acc[i][1] + bb[1];
    float o2 = acc[i][2] + bb[2], o3 = acc[i][3] + bb[3];
    if (ACT){ o0 = fmaxf(o0, 0.f); o1 = fmaxf(o1, 0.f); o2 = fmaxf(o2, 0.f); o3 = fmaxf(o3, 0.f); }
    v.x = o0; v.y = o1; v.z = o2; v.w = o3;
    *(float4*)(C + off) = v;
  }
}

// ---------------- 256x128-tile fused policy GEMM, 16x8 microtile ----------------
// 256 threads, __launch_bounds__(256,1): full 512-VGPR budget so acc[16][8] stays
// in registers (round-5 spilled at default occupancy heuristic -> VGPR_Count=92).
// LDS floats/FMA = 24/128 = 0.1875. Inner loop: 128 FMA per 6 LDS b128 reads -> ILP
// covers latency at ~2 waves/SIMD. Numerics identical to round-5 body (which passed).
__global__ __launch_bounds__(256, 1) void gemm128f_k(
    const float* __restrict__ Y,
    const long* __restrict__ atab,
    const float* __restrict__ b1,
    const float* __restrict__ W2, const float* __restrict__ b2,
    const float* __restrict__ w3,
    const int* __restrict__ scat, float* __restrict__ logits)
{
  __shared__ float As[16][260];
  __shared__ float Ws[16][132];
  int tid = threadIdx.x;
  int c0 = blockIdx.x * 128;
  int r0 = blockIdx.y * 256;
  int tx = tid & 15, ty = tid >> 4;   // ty in [0,16): 16 rows each (4 quarters of 4)
  int rA = tid;                        // one staged A-row per thread
  long a0r = atab[(long)(r0 + rA) * 2];
  long a1r = atab[(long)(r0 + rA) * 2 + 1];
  int wk = tid >> 5;                  // [0,8)
  int wc = (tid & 31) << 2;           // [0,128)
  float acc[16][8];
#pragma unroll
  for (int i = 0; i < 16; i++)
#pragma unroll
    for (int j = 0; j < 8; j++) acc[i][j] = 0.f;

  for (int k0 = 0; k0 < 512; k0 += 16){
    {
      float4 p = *(const float4*)(Y + a0r + k0);
      float4 q = *(const float4*)(Y + a1r + k0);
      float4 bv = *(const float4*)(b1 + k0);
      As[0][rA] = fmaxf(p.x + q.x + bv.x, 0.f);
      As[1][rA] = fmaxf(p.y + q.y + bv.y, 0.f);
      As[2][rA] = fmaxf(p.z + q.z + bv.z, 0.f);
      As[3][rA] = fmaxf(p.w + q.w + bv.w, 0.f);
    }
    {
      float4 p = *(const float4*)(Y + a0r + k0 + 4);
      float4 q = *(const float4*)(Y + a1r + k0 + 4);
      float4 bv = *(const float4*)(b1 + k0 + 4);
      As[4][rA] = fmaxf(p.x + q.x + bv.x, 0.f);
      As[5][rA] = fmaxf(p.y + q.y + bv.y, 0.f);
      As[6][rA] = fmaxf(p.z + q.z + bv.z, 0.f);
      As[7][rA] = fmaxf(p.w + q.w + bv.w, 0.f);
    }
    {
      float4 p = *(const float4*)(Y + a0r + k0 + 8);
      float4 q = *(const float4*)(Y + a1r + k0 + 8);
      float4 bv = *(const float4*)(b1 + k0 + 8);
      As[8][rA]  = fmaxf(p.x + q.x + bv.x, 0.f);
      As[9][rA]  = fmaxf(p.y + q.y + bv.y, 0.f);
      As[10][rA] = fmaxf(p.z + q.z + bv.z, 0.f);
      As[11][rA] = fmaxf(p.w + q.w + bv.w, 0.f);
    }
    {
      float4 p = *(const float4*)(Y + a0r + k0 + 12);
      float4 q = *(const float4*)(Y + a1r + k0 + 12);
      float4 bv = *(const float4*)(b1 + k0 + 12);
      As[12][rA] = fmaxf(p.x + q.x + bv.x, 0.f);
      As[13][rA] = fmaxf(p.y + q.y + bv.y, 0.f);
      As[14][rA] = fmaxf(p.z + q.z + bv.z, 0.f);
      As[15][rA] = fmaxf(p.w + q.w + bv.w, 0.f);
    }
    *(float4*)&Ws[wk][wc]     = *(const float4*)(W2 + (long)(k0 + wk) * 512 + (c0 + wc));
    *(float4*)&Ws[wk + 8][wc] = *(const float4*)(W2 + (long)(k0 + wk + 8) * 512 + (c0 + wc));
    __syncthreads();
#pragma unroll
    for (int kk = 0; kk < 16; kk++){
      float a16[16], w8[8];
      *(float4*)&a16[0]  = *(const float4*)&As[kk][(ty << 2)];
      *(float4*)&a16[4]  = *(const float4*)&As[kk][(ty << 2) + 64];
      *(float4*)&a16[8]  = *(const float4*)&As[kk][(ty << 2) + 128];
      *(float4*)&a16[12] = *(const float4*)&As[kk][(ty << 2) + 192];
      *(float4*)&w8[0] = *(const float4*)&Ws[kk][tx << 2];
      *(float4*)&w8[4] = *(const float4*)&Ws[kk][(tx << 2) + 64];
#pragma unroll
      for (int i = 0; i < 16; i++)
#pragma unroll
        for (int j = 0; j < 8; j++)
          acc[i][j] = fmaf(a16[i], w8[j], acc[i][j]);
    }
    __syncthreads();
  }
  float bb[8], w3v[8];
  *(float4*)&bb[0]  = *(const float4*)(b2 + c0 + (tx << 2));
  *(float4*)&bb[4]  = *(const float4*)(b2 + c0 + (tx << 2) + 64);
  *(float4*)&w3v[0] = *(const float4*)(w3 + c0 + (tx << 2));
  *(float4*)&w3v[4] = *(const float4*)(w3 + c0 + (tx << 2) + 64);
#pragma unroll
  for (int i = 0; i < 16; i++){
    float p = 0.f;
#pragma unroll
    for (int j = 0; j < 8; j++)
      p = fmaf(fmaxf(acc[i][j] + bb[j], 0.f), w3v[j], p);
    for (int m = 1; m < 16; m <<= 1) p += __shfl_xor(p, m);
    if (tx == 0){
      int rr = ((i >> 2) << 6) + (ty << 2) + (i & 3);
      atomicAdd(logits + scat[r0 + rr], p);
    }
  }
}

// ---------------- 64-tile fused policy GEMM (in-loop, rows <= 3584) ----------------
// Original 64x64 4x4: small tiles maximize block count for the underfilled late
// iterations (round-5 lesson: 64x128 halved parallelism there, -270us).
__global__ __launch_bounds__(256) void gemm64f_k(
    const float* __restrict__ Y,
    const long* __restrict__ atab,
    const float* __restrict__ b1,
    const float* __restrict__ W2, const float* __restrict__ b2,
    const float* __restrict__ w3,
    const int* __restrict__ scat, float* __restrict__ logits)
{
  __shared__ float As[16][64];
  __shared__ float Ws[16][64];
  int tid = threadIdx.x;
  int c0 = blockIdx.x * 64;
  int r0 = blockIdx.y * 64;
  int lr = tid >> 2;
  int lk = (tid & 3) << 2;
  int wk = tid >> 4;
  int wc = (tid & 15) << 2;
  int tx = tid & 15;
  int ty = tid >> 4;
  long a0 = atab[(long)(r0 + lr) * 2];
  long a1 = atab[(long)(r0 + lr) * 2 + 1];
  float acc[4][4];
#pragma unroll
  for (int i = 0; i < 4; i++)
#pragma unroll
    for (int j = 0; j < 4; j++) acc[i][j] = 0.f;

  for (int k0 = 0; k0 < 512; k0 += 16){
    int ka = k0 + lk;
    float4 p = *(const float4*)(Y + a0 + ka);
    float4 q = *(const float4*)(Y + a1 + ka);
    float4 bb = *(const float4*)(b1 + ka);
    As[lk + 0][lr] = fmaxf(p.x + q.x + bb.x, 0.f);
    As[lk + 1][lr] = fmaxf(p.y + q.y + bb.y, 0.f);
    As[lk + 2][lr] = fmaxf(p.z + q.z + bb.z, 0.f);
    As[lk + 3][lr] = fmaxf(p.w + q.w + bb.w, 0.f);
    *(float4*)&Ws[wk][wc] = *(const float4*)(W2 + (long)(k0 + wk) * 512 + (c0 + wc));
    __syncthreads();
#pragma unroll
    for (int kk = 0; kk < 16; kk++){
      float4 a4 = *(const float4*)&As[kk][ty << 2];
      float4 w4 = *(const float4*)&Ws[kk][tx << 2];
      float aa[4] = {a4.x, a4.y, a4.z, a4.w};
      float ww[4] = {w4.x, w4.y, w4.z, w4.w};
#pragma unroll
      for (int i = 0; i < 4; i++)
#pragma unroll
        for (int j = 0; j < 4; j++)
          acc[i][j] = fmaf(aa[i], ww[j], acc[i][j]);
    }
    __syncthreads();
  }
  float bb4[4], w34[4];
  *(float4*)&bb4[0] = *(const float4*)(b2 + c0 + (tx << 2));
  *(float4*)&w34[0] = *(const float4*)(w3 + c0 + (tx << 2));
#pragma unroll
  for (int i = 0; i < 4; i++){
    float p = 0.f;
#pragma unroll
    for (int j = 0; j < 4; j++)
      p = fmaf(fmaxf(acc[i][j] + bb4[j], 0.f), w34[j], p);
    for (int m = 1; m < 16; m <<= 1) p += __shfl_xor(p, m);
    if (tx == 0){
      int r = r0 + (ty << 2) + i;
      atomicAdd(logits + scat[r], p);
    }
  }
}

// N=2 final layer with scatter table: one wave per row
__global__ __launch_bounds__(256) void rowdot2_k(
    const float* __restrict__ A, int lda,
    const float* __restrict__ W, const float* __restrict__ bias,
    int K, float* __restrict__ out, const int* __restrict__ scat)
{
  int wid = threadIdx.x >> 6, lane = threadIdx.x & 63;
  int r = blockIdx.x * 4 + wid;
  const float* a = A + (long)r * lda;
  float s0 = 0.f, s1 = 0.f;
  for (int k = lane; k < K; k += 64){
    float x = a[k];
    s0 = fmaf(x, W[k * 2], s0);
    s1 = fmaf(x, W[k * 2 + 1], s1);
  }
  for (int off = 32; off > 0; off >>= 1){
    s0 += __shfl_down(s0, off);
    s1 += __shfl_down(s1, off);
  }
  if (lane == 0){
    long o = scat[r];
    out[o] = s0 + bias[0];
    out[o + 1] = s1 + bias[1];
  }
}

// ---------------- wide per-layer matvec kernels (row/block, col/thread) ----------------
// enc layer1: src = pair gather (K=1024), C=512, relu. grid (2, 128)
__global__ __launch_bounds__(256) void pairmv_k(
    const float* __restrict__ u, const long* __restrict__ tab_pair,
    const float* __restrict__ W, const float* __restrict__ bias,
    float* __restrict__ dst)
{
  __shared__ float s[1024];
  int b = blockIdx.y, tid = threadIdx.x;
  int c = blockIdx.x * 256 + tid;
  long t0 = tab_pair[b * 2], t1 = tab_pair[b * 2 + 1];
  s[tid]       = u[t0 + tid];
  s[tid + 256] = u[t0 + tid + 256];
  s[tid + 512] = u[t1 + tid];
  s[tid + 768] = u[t1 + tid + 256];
  __syncthreads();
  float a0 = 0.f, a1 = 0.f, a2 = 0.f, a3 = 0.f;
#pragma unroll 8
  for (int k = 0; k < 1024; k += 4){
    a0 = fmaf(s[k],     W[(long)k * 512 + c],       a0);
    a1 = fmaf(s[k + 1], W[(long)(k + 1) * 512 + c], a1);
    a2 = fmaf(s[k + 2], W[(long)(k + 2) * 512 + c], a2);
    a3 = fmaf(s[k + 3], W[(long)(k + 3) * 512 + c], a3);
  }
  float v = ((a0 + a1) + (a2 + a3)) + bias[c];
  dst[(long)b * 512 + c] = fmaxf(v, 0.f);
}

// generic K=512 -> C=512 relu layer. grid (2, 128)
__global__ __launch_bounds__(256) void mvrelu_k(
    const float* __restrict__ src, long sstride,
    const float* __restrict__ W, const float* __restrict__ bias,
    float* __restrict__ dst)
{
  __shared__ float s[512];
  int b = blockIdx.y, tid = threadIdx.x;
  int c = blockIdx.x * 256 + tid;
  const float* sr = src + (long)b * sstride;
  s[tid] = sr[tid];
  s[tid + 256] = sr[tid + 256];
  __syncthreads();
  float a0 = 0.f, a1 = 0.f, a2 = 0.f, a3 = 0.f;
#pragma unroll 8
  for (int k = 0; k < 512; k += 4){
    a0 = fmaf(s[k],     W[(long)k * 512 + c],       a0);
    a1 = fmaf(s[k + 1], W[(long)(k + 1) * 512 + c], a1);
    a2 = fmaf(s[k + 2], W[(long)(k + 2) * 512 + c], a2);
    a3 = fmaf(s[k + 3], W[(long)(k + 3) * 512 + c], a3);
  }
  float v = ((a0 + a1) + (a2 + a3)) + bias[c];
  dst[(long)b * 512 + c] = fmaxf(v, 0.f);
}

// enc layer3: z = h2@W + b (no relu); store z, and u token row = z + noise. grid (2, 128)
__global__ __launch_bounds__(256) void lay3z_k(
    const float* __restrict__ src,
    const float* __restrict__ W, const float* __restrict__ bias,
    float* __restrict__ z_all, float* __restrict__ u,
    int it, uint32_t k0, uint32_t k1)
{
  __shared__ float s[512];
  int b = blockIdx.y, tid = threadIdx.x;
  int c = blockIdx.x * 256 + tid;
  const float* sr = src + (long)b * 512;
  s[tid] = sr[tid];
  s[tid + 256] = sr[tid + 256];
  __syncthreads();
  float a0 = 0.f, a1 = 0.f, a2 = 0.f, a3 = 0.f;
#pragma unroll 8
  for (int k = 0; k < 512; k += 4){
    a0 = fmaf(s[k],     W[(long)k * 512 + c],       a0);
    a1 = fmaf(s[k + 1], W[(long)(k + 1) * 512 + c], a1);
    a2 = fmaf(s[k + 2], W[(long)(k + 2) * 512 + c], a2);
    a3 = fmaf(s[k + 3], W[(long)(k + 3) * 512 + c], a3);
  }
  float v = ((a0 + a1) + (a2 + a3)) + bias[c];
  z_all[(long)it * 65536 + (long)b * 512 + c] = v;
  float nv = jax_normal(k0, k1, (uint32_t)(b * 512 + c));
  u[((long)(b * 31 + 16 + it)) * 512 + c] = v + 0.01f * nv;
}

// Y row for new token: Y[tok] = u[tok] @ W1cat (no bias). grid (4, 128)
__global__ __launch_bounds__(256) void yrow_k(
    const float* __restrict__ u, const float* __restrict__ W1cat,
    float* __restrict__ Y, int it)
{
  __shared__ float s[512];
  int b = blockIdx.y, tid = threadIdx.x;
  int c = blockIdx.x * 256 + tid;
  const float* sr = u + ((long)(b * 31 + 16 + it)) * 512;
  s[tid] = sr[tid];
  s[tid + 256] = sr[tid + 256];
  __syncthreads();
  float a0 = 0.f, a1 = 0.f, a2 = 0.f, a3 = 0.f;
#pragma unroll 8
  for (int k = 0; k < 512; k += 4){
    a0 = fmaf(s[k],     W1cat[(long)k * 1024 + c],       a0);
    a1 = fmaf(s[k + 1], W1cat[(long)(k + 1) * 1024 + c], a1);
    a2 = fmaf(s[k + 2], W1cat[(long)(k + 2) * 1024 + c], a2);
    a3 = fmaf(s[k + 3], W1cat[(long)(k + 3) * 1024 + c], a3);
  }
  Y[((long)(b * 31 + 16 + it)) * 1024 + c] = (a0 + a1) + (a2 + a3);
}

// reverse layer3 + scatter into dmat. grid (4, 128)
__global__ __launch_bounds__(256) void rev3_k(
    const float* __restrict__ src,
    const float* __restrict__ W, const float* __restrict__ bias,
    float* __restrict__ dmat, const int* __restrict__ actions, int it)
{
  __shared__ float s[512];
  int b = blockIdx.y, tid = threadIdx.x;
  int p = blockIdx.x * 256 + tid;
  const float* sr = src + (long)b * 512;
  s[tid] = sr[tid];
  s[tid + 256] = sr[tid + 256];
  __syncthreads();
  float a0 = 0.f, a1 = 0.f, a2 = 0.f, a3 = 0.f;
#pragma unroll 8
  for (int k = 0; k < 512; k += 4){
    a0 = fmaf(s[k],     W[(long)k * 1024 + p],       a0);
    a1 = fmaf(s[k + 1], W[(long)(k + 1) * 1024 + p], a1);
    a2 = fmaf(s[k + 2], W[(long)(k + 2) * 1024 + p], a2);
    a3 = fmaf(s[k + 3], W[(long)(k + 3) * 1024 + p], a3);
  }
  float v = ((a0 + a1) + (a2 + a3)) + bias[p];
  int fit = 14 - it;
  int s0 = actions[(b * 15 + fit) * 2];
  int s1 = actions[(b * 15 + fit) * 2 + 1];
  int node = (p < 512) ? s0 : s1;
  int ee = p & 511;
  dmat[((long)(b * 31 + node)) * 512 + ee] = v;
}

// batched osl over all steps: grid 1920 (r = it*128 + b)
__global__ __launch_bounds__(256) void oslb_k(
    const float* __restrict__ pred, const float* __restrict__ u,
    const int* __restrict__ actions, float* __restrict__ sl, float* __restrict__ rew)
{
  int r = blockIdx.x, tid = threadIdx.x;
  int it = r >> 7, b = r & 127;
  int s0 = actions[(b * 15 + it) * 2];
  int s1 = actions[(b * 15 + it) * 2 + 1];
  const float* t0 = u + ((long)(b * 31 + s0)) * 512;
  const float* t1 = u + ((long)(b * 31 + s1)) * 512;
  const float* p = pred + (long)r * 1024;
  float s = 0.f;
  for (int k = tid; k < 512; k += 256){
    float d0 = p[k] - t0[k];       s = fmaf(d0, d0, s);
    float d1 = p[k + 512] - t1[k]; s = fmaf(d1, d1, s);
  }
  __shared__ float red[256];
  red[tid] = s; __syncthreads();
  for (int st = 128; st > 0; st >>= 1){ if (tid < st) red[tid] += red[tid + st]; __syncthreads(); }
  if (tid == 0){
    float osl = red[0] / 1024.0f;
    atomicAdd(sl + b, osl);
    rew[b * 15 + it] = -osl;
  }
}

// ---------------- init (no dmat zeroing: every cell of d is provably overwritten) ----------------
__global__ __launch_bounds__(256) void init_k(float* __restrict__ lbl,
    float* __restrict__ logits, float* __restrict__ sl, float* __restrict__ ent,
    int* __restrict__ active, float* __restrict__ zb,
    float* __restrict__ W1cat, const float* __restrict__ pol_w1, const float* __restrict__ pol_b3,
    long* __restrict__ tab_init, int* __restrict__ scat_init, long* __restrict__ tab_tok16,
    long* __restrict__ tab_mgd, int* __restrict__ scat_clf, long clf_off)
{
  long i = (long)blockIdx.x * 256 + threadIdx.x;
  if (i < 524288L){
    int k = (int)(i >> 10), n = (int)(i & 1023);
    W1cat[i] = (n < 512) ? pol_w1[(long)k * 512 + n] : pol_w1[(long)(k + 512) * 512 + (n - 512)];
  }
  if (i < 115200L){
    int rem = (int)(i % 900);
    int rr = rem / 30, cc = rem % 30;
    logits[i] = (rr < 16 && cc < 16 && rr != cc) ? pol_b3[0] : MASKV;
  }
  if (i < 30720L){
    int r = (int)i;
    int pk = r >> 7, b = r & 127;
    int ii2 = pk / 15, jr = pk % 15;
    int jj2 = jr + (jr >= ii2 ? 1 : 0);
    tab_init[r * 2]     = ((long)(b * 31 + ii2)) * 1024;
    tab_init[r * 2 + 1] = ((long)(b * 31 + jj2)) * 1024 + 512;
    scat_init[r] = b * 900 + ii2 * 30 + jj2;
  }
  if (i < 3968L){
    lbl[i] = ((i % 31) < 15) ? 1.0f : 0.0f;
    int r = (int)i;
    if (r < 1920){
      scat_clf[r] = (int)(clf_off + (long)(r & 127) * 62 + (r >> 7) * 2);
    } else {
      int rr = r - 1920;
      scat_clf[r] = (int)(clf_off + (long)(rr >> 4) * 62 + 60 - ((rr & 15) << 1));
    }
  }
  if (i < 2048L){
    active[i] = (int)(i & 15);
    tab_tok16[i] = ((long)((i >> 4) * 31 + (i & 15))) * 512;
  }
  if (i < 1920L){
    int it = (int)(i >> 7), b = (int)(i & 127);
    tab_mgd[i] = ((long)(b * 31 + 30 - it)) * 512;
  }
  if (i < 1024L)  zb[i] = 0.f;
  if (i < 128L){ sl[i] = 0.f; ent[i] = 0.f; }
}

__global__ __launch_bounds__(256) void noise_u_k(float* __restrict__ u, uint32_t k0, uint32_t k1){
  uint32_t e = blockIdx.x * 256u + threadIdx.x; // < 1048576
  uint32_t b = e >> 13, rem = e & 8191u, n = rem >> 9, ee = rem & 511u;
  float nr = jax_normal(k0, k1, e);
  long off = ((long)(b * 31u + n)) * 512 + ee;
  u[off] += 0.01f * nr;
}

__global__ __launch_bounds__(256) void build_d_k(float* __restrict__ dmat, const float* __restrict__ u){
  int e = blockIdx.x * 256 + threadIdx.x; // 65536
  int b = e >> 9, ee = e & 511;
  long off = ((long)(b * 31 + 30)) * 512 + ee;
  dmat[off] = u[off];
}

// softmax stats + entropy + gumbel-argmax + mask + active update + next tables + b3 preset
__global__ __launch_bounds__(256) void sample_k(float* __restrict__ logits, int* __restrict__ active,
    int* __restrict__ actions, float* __restrict__ lp, float* __restrict__ ent,
    int it, int A, uint32_t k0, uint32_t k1, float log_opt,
    long* __restrict__ tab_loop, int* __restrict__ scat_loop, long* __restrict__ tab_pair,
    const float* __restrict__ pol_b3)
{
  int b = blockIdx.x, tid = threadIdx.x;
  int lane = tid & 63, wid = tid >> 6;
  float* Lg = logits + (long)b * 900;
  __shared__ float rmax[4], rS[4], rT[4], rG[4];
  __shared__ int rGi[4];
  __shared__ int ss0, ss1;

  // pass 1: max
  float v = -3.4e38f;
  for (int j = tid; j < 900; j += 256) v = fmaxf(v, Lg[j]);
#pragma unroll
  for (int m = 32; m; m >>= 1) v = fmaxf(v, __shfl_xor(v, m));
  if (lane == 0) rmax[wid] = v;
  __syncthreads();
  float mx = fmaxf(fmaxf(rmax[0], rmax[1]), fmaxf(rmax[2], rmax[3]));

  // pass 2: S = sum exp(l-m); T = sum e*(l-m) over unmasked
  float s = 0.f, t = 0.f;
  for (int j = tid; j < 900; j += 256){
    float l = Lg[j];
    float d = l - mx;
    float e = expf(d);
    s += e;
    if (l > MASKV) t = fmaf(e, d, t);
  }
#pragma unroll
  for (int m = 32; m; m >>= 1){ s += __shfl_xor(s, m); t += __shfl_xor(t, m); }
  if (lane == 0){ rS[wid] = s; rT[wid] = t; }

  // pass 3: gumbel argmax (earliest index wins on ties)
  float bv = -3.4e38f; int bi = 0;
  for (int j = tid; j < 900; j += 256){
    float g = jax_gumbel(k0, k1, (uint32_t)(b * 900 + j));
    float val = Lg[j] + g;
    if (val > bv){ bv = val; bi = j; }
  }
#pragma unroll
  for (int m = 32; m; m >>= 1){
    float ov = __shfl_xor(bv, m); int oi = __shfl_xor(bi, m);
    if (ov > bv || (ov == bv && oi < bi)){ bv = ov; bi = oi; }
  }
  if (lane == 0){ rG[wid] = bv; rGi[wid] = bi; }
  __syncthreads();

  if (tid == 0){
    float S = (rS[0] + rS[1]) + (rS[2] + rS[3]);
    float T = (rT[0] + rT[1]) + (rT[2] + rT[3]);
    ent[b] += -(T / S - logf(S)) / log_opt;
    float gb = rG[0]; int gi = rGi[0];
    for (int w = 1; w < 4; w++){
      if (rG[w] > gb || (rG[w] == gb && rGi[w] < gi)){ gb = rG[w]; gi = rGi[w]; }
    }
    int sf = gi;
    int s0 = sf / 30, s1 = sf % 30;
    ss0 = s0; ss1 = s1;
    actions[(b * 15 + it) * 2] = s0;
    actions[(b * 15 + it) * 2 + 1] = s1;
    lp[b * 15 + it] = Lg[sf] - mx - logf(S);
    tab_pair[b * 2]     = ((long)(b * 31 + s0)) * 512;
    tab_pair[b * 2 + 1] = ((long)(b * 31 + s1)) * 512;
  }
  __syncthreads();
  int s0 = ss0, s1 = ss1;
  if (tid < 30){
    Lg[s0 * 30 + tid] = MASKV;
    Lg[s1 * 30 + tid] = MASKV;
    Lg[tid * 30 + s0] = MASKV;
    Lg[tid * 30 + s1] = MASKV;
  }
  if (tid == 0){
    float b3v = pol_b3[0];
    int buf[16]; int c = 0;
    for (int k = 0; k < A; k++){
      int a = active[b * 16 + k];
      if (a != s0 && a != s1) buf[c++] = a;
    }
    int nt2 = 16 + it;
    buf[c++] = nt2;
    for (int k = 0; k < c; k++) active[b * 16 + k] = buf[k];
    int na2 = c - 1;
    for (int j = 0; j < na2; j++){
      int q = buf[j];
      int r1 = j * 128 + b;
      tab_loop[r1 * 2]     = ((long)(b * 31 + nt2)) * 1024;
      tab_loop[r1 * 2 + 1] = ((long)(b * 31 + q)) * 1024 + 512;
      int sc1 = b * 900 + nt2 * 30 + q;
      scat_loop[r1] = sc1;
      logits[sc1] = b3v;
      int r2 = (na2 + j) * 128 + b;
      tab_loop[r2 * 2]     = ((long)(b * 31 + q)) * 1024;
      tab_loop[r2 * 2 + 1] = ((long)(b * 31 + nt2)) * 1024 + 512;
      int sc2 = b * 900 + q * 30 + nt2;
      scat_loop[r2] = sc2;
      logits[sc2] = b3v;
    }
  }
}

__global__ __launch_bounds__(256) void finalize_k(const float* __restrict__ rew,
    const float* __restrict__ lp, const float* __restrict__ sl, const float* __restrict__ ent,
    float* __restrict__ out_sl, float* __restrict__ out_ent, float* __restrict__ out_reinf)
{
  __shared__ float red[256];
  int tid = threadIdx.x;
  float s = 0.f;
  for (int i = tid; i < 1920; i += 256) s += rew[i];
  red[tid] = s; __syncthreads();
  for (int st = 128; st > 0; st >>= 1){ if (tid < st) red[tid] += red[tid + st]; __syncthreads(); }
  float mean = red[0] / 1920.0f; __syncthreads();
  float v = 0.f;
  for (int i = tid; i < 1920; i += 256){ float x = rew[i] - mean; v = fmaf(x, x, v); }
  red[tid] = v; __syncthreads();
  for (int st = 128; st > 0; st >>= 1){ if (tid < st) red[tid] += red[tid + st]; __syncthreads(); }
  float denom = sqrtf(red[0] / 1919.0f) + 1e-20f;
  if (tid < 128){
    out_sl[tid] = sl[tid] / 15.0f;
    out_ent[tid] = ent[tid] / 15.0f;
    float r = 0.f;
    for (int k = 0; k < 15; k++){
      float rn = (rew[tid * 15 + k] - mean) / denom;
      r = fmaf(lp[tid * 15 + k], rn, r);
    }
    out_reinf[tid] = r;
  }
}

// ---------------- host ----------------
extern "C" void kernel_launch(void* const* d_in, const int* in_sizes, int n_in,
                              void* d_out, int out_size, void* d_ws, size_t ws_size,
                              hipStream_t stream)
{
  const float* x        = (const float*)d_in[0];
  const float* lift_w   = (const float*)d_in[1];
  const float* lift_b   = (const float*)d_in[2];
  const float* unlift_w = (const float*)d_in[3];
  const float* unlift_b = (const float*)d_in[4];
  const float* enc_w1   = (const float*)d_in[5];
  const float* enc_b1   = (const float*)d_in[6];
  const float* enc_w2   = (const float*)d_in[7];
  const float* enc_b2   = (const float*)d_in[8];
  const float* enc_w3   = (const float*)d_in[9];
  const float* enc_b3   = (const float*)d_in[10];
  const float* dec_w1   = (const float*)d_in[11];
  const float* dec_b1   = (const float*)d_in[12];
  const float* dec_w2   = (const float*)d_in[13];
  const float* dec_b2   = (const float*)d_in[14];
  const float* dec_w3   = (const float*)d_in[15];
  const float* dec_b3   = (const float*)d_in[16];
  const float* clf_w1   = (const float*)d_in[17];
  const float* clf_b1   = (const float*)d_in[18];
  const float* clf_w2   = (const float*)d_in[19];
  const float* clf_b2   = (const float*)d_in[20];
  const float* clf_w3   = (const float*)d_in[21];
  const float* clf_b3   = (const float*)d_in[22];
  const float* pol_w1   = (const float*)d_in[23];
  const float* pol_b1   = (const float*)d_in[24];
  const float* pol_w2   = (const float*)d_in[25];
  const float* pol_b2   = (const float*)d_in[26];
  const float* pol_w3   = (const float*)d_in[27];
  const float* pol_b3   = (const float*)d_in[28];

  float* out = (float*)d_out;
  const long U_OFF     = 2097152;
  const long D_OFF     = 4128768;
  const long SL_OFF    = 6160384;
  const long ENT_OFF   = 6160512;
  const long CLF_OFF   = 6160640;
  const long LBL_OFF   = 6168576;
  const long REINF_OFF = 6172544;
  float* recon = out;
  float* u     = out + U_OFF;
  float* dmat  = out + D_OFF;

  char* wsb = (char*)d_ws;
  size_t wo = 0;
  auto alloc = [&](size_t bytes) -> void* {
    void* p = (void*)(wsb + wo);
    wo = (wo + bytes + 255) & ~(size_t)255;
    return p;
  };
  float* logits    = (float*)alloc(115200 * 4);
  float* Y         = (float*)alloc((size_t)3968 * 1024 * 4); // dead after fwd -> overlays:
  float* h1clf     = Y;                  // tail clf hidden1 (3968x512)
  float* pbuf      = Y + 2031616;        // dec output 1920x1024, then clf h2
  float* h2clf     = Y + 2031616;
  float* W1cat     = (float*)alloc((size_t)524288 * 4);
  float* zb        = (float*)alloc(1024 * 4);
  float* h1        = (float*)alloc((size_t)2048 * 512 * 4);
  float* h2        = (float*)alloc((size_t)2048 * 512 * 4);
  float* z_all     = (float*)alloc((size_t)15 * 65536 * 4);
  float* sl        = (float*)alloc(128 * 4);
  float* ent       = (float*)alloc(128 * 4);
  float* lp        = (float*)alloc(1920 * 4);
  float* rew       = (float*)alloc(1920 * 4);
  int*   active    = (int*)alloc(2048 * 4);
  int*   actions   = (int*)alloc(3840 * 4);
  long*  tab_init  = (long*)alloc((size_t)30720 * 2 * 8);
  int*   scat_init = (int*)alloc(30720 * 4);
  long*  tab_loop  = (long*)alloc((size_t)3584 * 2 * 8);
  int*   scat_loop = (int*)alloc(3584 * 4);
  long*  tab_pair  = (long*)alloc(256 * 8);
  long*  tab_mgd   = (long*)alloc(1920 * 8);   // contiguous with tab_tok16 -> 3968-row clf table
  long*  tab_tok16 = (long*)alloc(2048 * 8);
  int*   scat_clf  = (int*)alloc(3968 * 4);
  long*  tab_clf   = tab_mgd;
  (void)ws_size; (void)in_sizes; (void)n_in; (void)out_size;

  uint32_t k7a, k7b, ck0[15], ck1[15], mk0[15], mk1[15];
  { uint32_t a = 0, b = 7; tf2x32(0u, 42u, a, b); k7a = a; k7b = b; }
  for (int it = 0; it < 15; it++){
    { uint32_t a = 0, b = (uint32_t)(100 + it); tf2x32(0u, 42u, a, b); ck0[it] = a; ck1[it] = b; }
    { uint32_t a = 0, b = (uint32_t)(1000 + it); tf2x32(0u, 42u, a, b); mk0[it] = a; mk1[it] = b; }
  }

  auto gemm = [&](int act, const float* A, int lda, const long* atab, int anblk,
                  const float* W, const float* bs, float* C, int rows, int K, int Nn,
                  long cb, int crd, long cos, long cis){
    dim3 g(Nn / 64, rows / 64);
    if (act) gemm_k<1><<<g, 256, 0, stream>>>(A, lda, atab, anblk, W, bs, C, K, Nn, cb, crd, cos, cis);
    else     gemm_k<0><<<g, 256, 0, stream>>>(A, lda, atab, anblk, W, bs, C, K, Nn, cb, crd, cos, cis);
  };

  // ---- init ----
  init_k<<<2048, 256, 0, stream>>>(out + LBL_OFF, logits, sl, ent, active, zb,
                                   W1cat, pol_w1, pol_b3, tab_init, scat_init, tab_tok16,
                                   tab_mgd, scat_clf, CLF_OFF);

  // ---- lift + noise ----
  gemm(0, x, 1024, nullptr, 0, lift_w, lift_b, u, 2048, 1024, 512, 0, 16, 15872, 512);
  noise_u_k<<<4096, 256, 0, stream>>>(u, k7a, k7b);

  // ---- Y init for tokens 0..15 ----
  gemm(0, u, 0, tab_tok16, 1, W1cat, zb, Y, 2048, 512, 1024, 0, 16, 31744, 1024);

  // ---- initial policy logits (256x128 tiles, 16x8 microtile, 256 threads, LB(256,1)) ----
  { dim3 g(4, 120);
    gemm128f_k<<<g, 256, 0, stream>>>(Y, tab_init, pol_b1, pol_w2, pol_b2, pol_w3,
                                      scat_init, logits); }

  // ---- forward merge loop (round-2 structure: per-layer matvecs, max fill) ----
  for (int it = 0; it < 15; it++){
    int A = 16 - it;
    if (it > 0){
      int rows = 256 * (15 - it);
      dim3 g(8, rows / 64);
      gemm64f_k<<<g, 256, 0, stream>>>(Y, tab_loop, pol_b1, pol_w2, pol_b2, pol_w3,
                                       scat_loop, logits);
    }
    float log_opt = (float)log((double)(A * (A - 1)));
    sample_k<<<128, 256, 0, stream>>>(logits, active, actions, lp, ent, it, A,
                                      ck0[it], ck1[it], log_opt,
                                      tab_loop, scat_loop, tab_pair, pol_b3);
    { dim3 g(2, 128);
      pairmv_k<<<g, 256, 0, stream>>>(u, tab_pair, enc_w1, enc_b1, h1); }
    { dim3 g(2, 128);
      mvrelu_k<<<g, 256, 0, stream>>>(h1, 512, enc_w2, enc_b2, h2); }
    { dim3 g(2, 128);
      lay3z_k<<<g, 256, 0, stream>>>(h2, enc_w3, enc_b3, z_all, u, it, mk0[it], mk1[it]); }
    if (it < 14){
      dim3 g(4, 128);
      yrow_k<<<g, 256, 0, stream>>>(u, W1cat, Y, it);
    }
  }

  // ---- deferred batched dec over all 15 steps (1920 rows), then osl ----
  gemm(1, z_all, 512, nullptr, 0, dec_w1, dec_b1, h1, 1920, 512, 512, 0, 1, 512, 0);
  gemm(1, h1, 512, nullptr, 0, dec_w2, dec_b2, h2, 1920, 512, 512, 0, 1, 512, 0);
  gemm(0, h2, 512, nullptr, 0, dec_w3, dec_b3, pbuf, 1920, 512, 1024, 0, 1, 1024, 0);
  oslb_k<<<1920, 256, 0, stream>>>(pbuf, u, actions, sl, rew);

  // ---- d init (only token 30 active) ----
  build_d_k<<<256, 256, 0, stream>>>(dmat, u);

  // ---- reverse unmerge loop (round-2 structure): 3 wide layers per step ----
  for (int it = 0; it < 15; it++){
    int tok = 30 - it;
    { dim3 g(2, 128);
      mvrelu_k<<<g, 256, 0, stream>>>(dmat + (long)tok * 512, 15872, dec_w1, dec_b1, h1); }
    { dim3 g(2, 128);
      mvrelu_k<<<g, 256, 0, stream>>>(h1, 512, dec_w2, dec_b2, h2); }
    { dim3 g(4, 128);
      rev3_k<<<g, 256, 0, stream>>>(h2, dec_w3, dec_b3, dmat, actions, it); }
  }

  // ---- combined clf over mgd rows (1920) + final d[:, :16] rows (2048) ----
  gemm(1, dmat, 0, tab_clf, 1, clf_w1, clf_b1, h1clf, 3968, 512, 512, 0, 1, 512, 0);
  gemm(1, h1clf, 512, nullptr, 0, clf_w2, clf_b2, h2clf, 3968, 512, 512, 0, 1, 512, 0);
  rowdot2_k<<<992, 256, 0, stream>>>(h2clf, 512, clf_w3, clf_b3, 512, out, scat_clf);

  // ---- recon = d[:, :16] @ unlift_w + unlift_b ----
  gemm(0, dmat, 0, tab_tok16, 1, unlift_w, unlift_b, recon, 2048, 512, 1024,
       0, 16, 16384, 1024);

  // ---- reward normalization, reinf, per-batch losses ----
  finalize_k<<<1, 256, 0, stream>>>(rew, lp, sl, ent,
                                    out + SL_OFF, out + ENT_OFF, out + REINF_OFF);
}

// Round 7
// 2539.833 us; speedup vs baseline: 2.0180x; 1.0053x over previous
//
#include <hip/hip_runtime.h>
#include <cstdint>
#include <cmath>

#define MASKV -9.0e20f

// ---------------- Threefry-2x32 (JAX-compatible) ----------------
__host__ __device__ inline void tf2x32(uint32_t k0, uint32_t k1, uint32_t& x0, uint32_t& x1){
  uint32_t ks2 = k0 ^ k1 ^ 0x1BD11BDAu;
  x0 += k0; x1 += k1;
#define TFR(r) { x0 += x1; x1 = (x1<<(r))|(x1>>(32-(r))); x1 ^= x0; }
  TFR(13) TFR(15) TFR(26) TFR(6)
  x0 += k1;  x1 += ks2 + 1u;
  TFR(17) TFR(29) TFR(16) TFR(24)
  x0 += ks2; x1 += k0 + 2u;
  TFR(13) TFR(15) TFR(26) TFR(6)
  x0 += k0;  x1 += k1 + 3u;
  TFR(17) TFR(29) TFR(16) TFR(24)
  x0 += k1;  x1 += ks2 + 4u;
  TFR(13) TFR(15) TFR(26) TFR(6)
  x0 += ks2; x1 += k0 + 5u;
#undef TFR
}

__device__ inline uint32_t rbits32(uint32_t k0, uint32_t k1, uint32_t idx){
  uint32_t x0 = 0u, x1 = idx;
  tf2x32(k0, k1, x0, x1);
  return x0 ^ x1;
}

__device__ inline float u01_from_bits(uint32_t bits){
  union { uint32_t u; float f; } c;
  c.u = (bits >> 9) | 0x3f800000u;
  return c.f - 1.0f;
}

__device__ inline float erfinv_f(float x){
  float w = -log1pf(-x*x);
  float p;
  if (w < 5.0f){
    w -= 2.5f;
    p = 2.81022636e-08f;
    p = fmaf(p, w, 3.43273939e-07f);
    p = fmaf(p, w, -3.5233877e-06f);
    p = fmaf(p, w, -4.39150654e-06f);
    p = fmaf(p, w, 0.00021858087f);
    p = fmaf(p, w, -0.00125372503f);
    p = fmaf(p, w, -0.00417768164f);
    p = fmaf(p, w, 0.246640727f);
    p = fmaf(p, w, 1.50140941f);
  } else {
    w = sqrtf(w) - 3.0f;
    p = -0.000200214257f;
    p = fmaf(p, w, 0.000100950558f);
    p = fmaf(p, w, 0.00134934322f);
    p = fmaf(p, w, -0.00367342844f);
    p = fmaf(p, w, 0.00573950773f);
    p = fmaf(p, w, -0.0076224613f);
    p = fmaf(p, w, 0.00943887047f);
    p = fmaf(p, w, 1.00167406f);
    p = fmaf(p, w, 2.83297682f);
  }
  return p * x;
}

__device__ inline float jax_normal(uint32_t k0, uint32_t k1, uint32_t idx){
  float f = u01_from_bits(rbits32(k0, k1, idx));
  float v = fmaf(f, 2.0f, -0.99999994f);
  v = fmaxf(v, -0.99999994f);
  return 1.41421356f * erfinv_f(v);
}

__device__ inline float jax_gumbel(uint32_t k0, uint32_t k1, uint32_t idx){
  float f = u01_from_bits(rbits32(k0, k1, idx));
  f = f + 1.17549435e-38f;
  f = fmaxf(f, 1.17549435e-38f);
  return -logf(-logf(f));
}

// ---------------- small tiled SGEMM (64x64 tile, 4x4 microtile) ----------------
template<int ACT>
__global__ __launch_bounds__(256) void gemm_k(
    const float* __restrict__ A, int lda,
    const long* __restrict__ atab, int anblk,
    const float* __restrict__ W, const float* __restrict__ bias,
    float* __restrict__ C, int K, int N,
    long c_base, int c_rdiv, long c_ostride, long c_istride)
{
  __shared__ float As[16][64];
  __shared__ float Ws[16][64];
  int tid = threadIdx.x;
  int c0 = blockIdx.x * 64;
  int r0 = blockIdx.y * 64;
  int lr = tid >> 2;
  int lk = (tid & 3) << 2;
  int wk = tid >> 4;
  int wc = (tid & 15) << 2;
  int tx = tid & 15;
  int ty = tid >> 4;
  long aoff0 = 0, aoff1 = 0;
  if (atab){
    const long* t = atab + (long)(r0 + lr) * anblk;
    aoff0 = t[0];
    if (anblk == 2) aoff1 = t[1];
  } else {
    aoff0 = (long)(r0 + lr) * lda;
  }
  float acc[4][4];
#pragma unroll
  for (int i = 0; i < 4; i++)
#pragma unroll
    for (int j = 0; j < 4; j++) acc[i][j] = 0.f;

  for (int k0 = 0; k0 < K; k0 += 16){
    int ka = k0 + lk;
    long ab = (atab && anblk == 2 && ka >= 512) ? (aoff1 + (ka - 512)) : (aoff0 + ka);
    float4 av = *(const float4*)(A + ab);
    As[lk + 0][lr] = av.x;
    As[lk + 1][lr] = av.y;
    As[lk + 2][lr] = av.z;
    As[lk + 3][lr] = av.w;
    float4 wv = *(const float4*)(W + (long)(k0 + wk) * N + (c0 + wc));
    *(float4*)&Ws[wk][wc] = wv;
    __syncthreads();
#pragma unroll
    for (int kk = 0; kk < 16; kk++){
      float4 a4 = *(const float4*)&As[kk][ty << 2];
      float4 w4 = *(const float4*)&Ws[kk][tx << 2];
      float aa[4] = {a4.x, a4.y, a4.z, a4.w};
      float ww[4] = {w4.x, w4.y, w4.z, w4.w};
#pragma unroll
      for (int i = 0; i < 4; i++)
#pragma unroll
        for (int j = 0; j < 4; j++)
          acc[i][j] = fmaf(aa[i], ww[j], acc[i][j]);
    }
    __syncthreads();
  }
  float4 bv = *(const float4*)(bias + c0 + (tx << 2));
  float bb[4] = {bv.x, bv.y, bv.z, bv.w};
#pragma unroll
  for (int i = 0; i < 4; i++){
    int r = r0 + (ty << 2) + i;
    long off = c_base + (long)(r / c_rdiv) * c_ostride + (long)(r % c_rdiv) * c_istride
               + c0 + (tx << 2);
    float4 v;
    float o0 = acc[i][0] + bb[0], o1 = acc[i][1] + bb[1];
    float o2 = acc[i][2] + bb[2], o3 = acc[i][3] + bb[3];
    if (ACT){ o0 = fmaxf(o0, 0.f); o1 = fmaxf(o1, 0.f); o2 = fmaxf(o2, 0.f); o3 = fmaxf(o3, 0.f); }
    v.x = o0; v.y = o1; v.z = o2; v.w = o3;
    *(float4*)(C + off) = v;
  }
}

// ---------------- 256x128-tile fused policy GEMM (round-4 measured-best) ----------------
// 512 threads / 8 waves, 8x8 microtile. Measured: 215.8us, VGPR 52, no spill,
// VALUBusy ~62% (= ds_read_b128 throughput cap for ratio-0.25 structures).
// 16x8 alternative spills (VGPR 92, 240-258us) regardless of launch_bounds.
__global__ __launch_bounds__(512, 4) void gemm128f_k(
    const float* __restrict__ Y,
    const long* __restrict__ atab,
    const float* __restrict__ b1,
    const float* __restrict__ W2, const float* __restrict__ b2,
    const float* __restrict__ w3,
    const int* __restrict__ scat, float* __restrict__ logits)
{
  __shared__ float As[16][260];
  __shared__ float Ws[16][132];
  int tid = threadIdx.x;
  int c0 = blockIdx.x * 128;
  int r0 = blockIdx.y * 256;
  int tx = tid & 15, ty = tid >> 4;   // ty in [0,32): 8 rows each
  int rA = tid >> 1;                  // [0,256): staged A-row
  int kh = (tid & 1) << 3;            // 0 or 8
  long a0r = atab[(long)(r0 + rA) * 2];
  long a1r = atab[(long)(r0 + rA) * 2 + 1];
  int wk = tid >> 5;                  // [0,16)
  int wc = (tid & 31) << 2;           // [0,128)
  float acc[8][8];
#pragma unroll
  for (int i = 0; i < 8; i++)
#pragma unroll
    for (int j = 0; j < 8; j++) acc[i][j] = 0.f;

  for (int k0 = 0; k0 < 512; k0 += 16){
    float4 p0 = *(const float4*)(Y + a0r + k0 + kh);
    float4 p1 = *(const float4*)(Y + a0r + k0 + kh + 4);
    float4 q0 = *(const float4*)(Y + a1r + k0 + kh);
    float4 q1 = *(const float4*)(Y + a1r + k0 + kh + 4);
    float4 bv0 = *(const float4*)(b1 + k0 + kh);
    float4 bv1 = *(const float4*)(b1 + k0 + kh + 4);
    As[kh + 0][rA] = fmaxf(p0.x + q0.x + bv0.x, 0.f);
    As[kh + 1][rA] = fmaxf(p0.y + q0.y + bv0.y, 0.f);
    As[kh + 2][rA] = fmaxf(p0.z + q0.z + bv0.z, 0.f);
    As[kh + 3][rA] = fmaxf(p0.w + q0.w + bv0.w, 0.f);
    As[kh + 4][rA] = fmaxf(p1.x + q1.x + bv1.x, 0.f);
    As[kh + 5][rA] = fmaxf(p1.y + q1.y + bv1.y, 0.f);
    As[kh + 6][rA] = fmaxf(p1.z + q1.z + bv1.z, 0.f);
    As[kh + 7][rA] = fmaxf(p1.w + q1.w + bv1.w, 0.f);
    *(float4*)&Ws[wk][wc] = *(const float4*)(W2 + (long)(k0 + wk) * 512 + (c0 + wc));
    __syncthreads();
#pragma unroll
    for (int kk = 0; kk < 16; kk++){
      float a8[8], w8[8];
      *(float4*)&a8[0] = *(const float4*)&As[kk][ty << 3];
      *(float4*)&a8[4] = *(const float4*)&As[kk][(ty << 3) + 4];
      *(float4*)&w8[0] = *(const float4*)&Ws[kk][tx << 2];
      *(float4*)&w8[4] = *(const float4*)&Ws[kk][(tx << 2) + 64];
#pragma unroll
      for (int i = 0; i < 8; i++)
#pragma unroll
        for (int j = 0; j < 8; j++)
          acc[i][j] = fmaf(a8[i], w8[j], acc[i][j]);
    }
    __syncthreads();
  }
  float bb[8], w3v[8];
  *(float4*)&bb[0]  = *(const float4*)(b2 + c0 + (tx << 2));
  *(float4*)&bb[4]  = *(const float4*)(b2 + c0 + (tx << 2) + 64);
  *(float4*)&w3v[0] = *(const float4*)(w3 + c0 + (tx << 2));
  *(float4*)&w3v[4] = *(const float4*)(w3 + c0 + (tx << 2) + 64);
#pragma unroll
  for (int i = 0; i < 8; i++){
    float p = 0.f;
#pragma unroll
    for (int j = 0; j < 8; j++)
      p = fmaf(fmaxf(acc[i][j] + bb[j], 0.f), w3v[j], p);
    for (int m = 1; m < 16; m <<= 1) p += __shfl_xor(p, m);
    if (tx == 0){
      int rr = (ty << 3) + i;
      atomicAdd(logits + scat[r0 + rr], p);
    }
  }
}

// ---------------- 64-tile fused policy GEMM (in-loop, rows <= 3584) ----------------
// 64x64 4x4: small tiles maximize block count for underfilled late iterations.
__global__ __launch_bounds__(256) void gemm64f_k(
    const float* __restrict__ Y,
    const long* __restrict__ atab,
    const float* __restrict__ b1,
    const float* __restrict__ W2, const float* __restrict__ b2,
    const float* __restrict__ w3,
    const int* __restrict__ scat, float* __restrict__ logits)
{
  __shared__ float As[16][64];
  __shared__ float Ws[16][64];
  int tid = threadIdx.x;
  int c0 = blockIdx.x * 64;
  int r0 = blockIdx.y * 64;
  int lr = tid >> 2;
  int lk = (tid & 3) << 2;
  int wk = tid >> 4;
  int wc = (tid & 15) << 2;
  int tx = tid & 15;
  int ty = tid >> 4;
  long a0 = atab[(long)(r0 + lr) * 2];
  long a1 = atab[(long)(r0 + lr) * 2 + 1];
  float acc[4][4];
#pragma unroll
  for (int i = 0; i < 4; i++)
#pragma unroll
    for (int j = 0; j < 4; j++) acc[i][j] = 0.f;

  for (int k0 = 0; k0 < 512; k0 += 16){
    int ka = k0 + lk;
    float4 p = *(const float4*)(Y + a0 + ka);
    float4 q = *(const float4*)(Y + a1 + ka);
    float4 bb = *(const float4*)(b1 + ka);
    As[lk + 0][lr] = fmaxf(p.x + q.x + bb.x, 0.f);
    As[lk + 1][lr] = fmaxf(p.y + q.y + bb.y, 0.f);
    As[lk + 2][lr] = fmaxf(p.z + q.z + bb.z, 0.f);
    As[lk + 3][lr] = fmaxf(p.w + q.w + bb.w, 0.f);
    *(float4*)&Ws[wk][wc] = *(const float4*)(W2 + (long)(k0 + wk) * 512 + (c0 + wc));
    __syncthreads();
#pragma unroll
    for (int kk = 0; kk < 16; kk++){
      float4 a4 = *(const float4*)&As[kk][ty << 2];
      float4 w4 = *(const float4*)&Ws[kk][tx << 2];
      float aa[4] = {a4.x, a4.y, a4.z, a4.w};
      float ww[4] = {w4.x, w4.y, w4.z, w4.w};
#pragma unroll
      for (int i = 0; i < 4; i++)
#pragma unroll
        for (int j = 0; j < 4; j++)
          acc[i][j] = fmaf(aa[i], ww[j], acc[i][j]);
    }
    __syncthreads();
  }
  float bb4[4], w34[4];
  *(float4*)&bb4[0] = *(const float4*)(b2 + c0 + (tx << 2));
  *(float4*)&w34[0] = *(const float4*)(w3 + c0 + (tx << 2));
#pragma unroll
  for (int i = 0; i < 4; i++){
    float p = 0.f;
#pragma unroll
    for (int j = 0; j < 4; j++)
      p = fmaf(fmaxf(acc[i][j] + bb4[j], 0.f), w34[j], p);
    for (int m = 1; m < 16; m <<= 1) p += __shfl_xor(p, m);
    if (tx == 0){
      int r = r0 + (ty << 2) + i;
      atomicAdd(logits + scat[r], p);
    }
  }
}

// N=2 final layer with scatter table: one wave per row
__global__ __launch_bounds__(256) void rowdot2_k(
    const float* __restrict__ A, int lda,
    const float* __restrict__ W, const float* __restrict__ bias,
    int K, float* __restrict__ out, const int* __restrict__ scat)
{
  int wid = threadIdx.x >> 6, lane = threadIdx.x & 63;
  int r = blockIdx.x * 4 + wid;
  const float* a = A + (long)r * lda;
  float s0 = 0.f, s1 = 0.f;
  for (int k = lane; k < K; k += 64){
    float x = a[k];
    s0 = fmaf(x, W[k * 2], s0);
    s1 = fmaf(x, W[k * 2 + 1], s1);
  }
  for (int off = 32; off > 0; off >>= 1){
    s0 += __shfl_down(s0, off);
    s1 += __shfl_down(s1, off);
  }
  if (lane == 0){
    long o = scat[r];
    out[o] = s0 + bias[0];
    out[o + 1] = s1 + bias[1];
  }
}

// ---------------- wide per-layer matvec kernels (row/block, col/thread) ----------------
// enc layer1: src = pair gather (K=1024), C=512, relu. grid (2, 128)
__global__ __launch_bounds__(256) void pairmv_k(
    const float* __restrict__ u, const long* __restrict__ tab_pair,
    const float* __restrict__ W, const float* __restrict__ bias,
    float* __restrict__ dst)
{
  __shared__ float s[1024];
  int b = blockIdx.y, tid = threadIdx.x;
  int c = blockIdx.x * 256 + tid;
  long t0 = tab_pair[b * 2], t1 = tab_pair[b * 2 + 1];
  s[tid]       = u[t0 + tid];
  s[tid + 256] = u[t0 + tid + 256];
  s[tid + 512] = u[t1 + tid];
  s[tid + 768] = u[t1 + tid + 256];
  __syncthreads();
  float a0 = 0.f, a1 = 0.f, a2 = 0.f, a3 = 0.f;
#pragma unroll 8
  for (int k = 0; k < 1024; k += 4){
    a0 = fmaf(s[k],     W[(long)k * 512 + c],       a0);
    a1 = fmaf(s[k + 1], W[(long)(k + 1) * 512 + c], a1);
    a2 = fmaf(s[k + 2], W[(long)(k + 2) * 512 + c], a2);
    a3 = fmaf(s[k + 3], W[(long)(k + 3) * 512 + c], a3);
  }
  float v = ((a0 + a1) + (a2 + a3)) + bias[c];
  dst[(long)b * 512 + c] = fmaxf(v, 0.f);
}

// generic K=512 -> C=512 relu layer. grid (2, 128)
__global__ __launch_bounds__(256) void mvrelu_k(
    const float* __restrict__ src, long sstride,
    const float* __restrict__ W, const float* __restrict__ bias,
    float* __restrict__ dst)
{
  __shared__ float s[512];
  int b = blockIdx.y, tid = threadIdx.x;
  int c = blockIdx.x * 256 + tid;
  const float* sr = src + (long)b * sstride;
  s[tid] = sr[tid];
  s[tid + 256] = sr[tid + 256];
  __syncthreads();
  float a0 = 0.f, a1 = 0.f, a2 = 0.f, a3 = 0.f;
#pragma unroll 8
  for (int k = 0; k < 512; k += 4){
    a0 = fmaf(s[k],     W[(long)k * 512 + c],       a0);
    a1 = fmaf(s[k + 1], W[(long)(k + 1) * 512 + c], a1);
    a2 = fmaf(s[k + 2], W[(long)(k + 2) * 512 + c], a2);
    a3 = fmaf(s[k + 3], W[(long)(k + 3) * 512 + c], a3);
  }
  float v = ((a0 + a1) + (a2 + a3)) + bias[c];
  dst[(long)b * 512 + c] = fmaxf(v, 0.f);
}

// enc layer3: z = h2@W + b (no relu); store z, and u token row = z + noise. grid (2, 128)
__global__ __launch_bounds__(256) void lay3z_k(
    const float* __restrict__ src,
    const float* __restrict__ W, const float* __restrict__ bias,
    float* __restrict__ z_all, float* __restrict__ u,
    int it, uint32_t k0, uint32_t k1)
{
  __shared__ float s[512];
  int b = blockIdx.y, tid = threadIdx.x;
  int c = blockIdx.x * 256 + tid;
  const float* sr = src + (long)b * 512;
  s[tid] = sr[tid];
  s[tid + 256] = sr[tid + 256];
  __syncthreads();
  float a0 = 0.f, a1 = 0.f, a2 = 0.f, a3 = 0.f;
#pragma unroll 8
  for (int k = 0; k < 512; k += 4){
    a0 = fmaf(s[k],     W[(long)k * 512 + c],       a0);
    a1 = fmaf(s[k + 1], W[(long)(k + 1) * 512 + c], a1);
    a2 = fmaf(s[k + 2], W[(long)(k + 2) * 512 + c], a2);
    a3 = fmaf(s[k + 3], W[(long)(k + 3) * 512 + c], a3);
  }
  float v = ((a0 + a1) + (a2 + a3)) + bias[c];
  z_all[(long)it * 65536 + (long)b * 512 + c] = v;
  float nv = jax_normal(k0, k1, (uint32_t)(b * 512 + c));
  u[((long)(b * 31 + 16 + it)) * 512 + c] = v + 0.01f * nv;
}

// Y row for new token: Y[tok] = u[tok] @ W1cat (no bias). grid (4, 128)
__global__ __launch_bounds__(256) void yrow_k(
    const float* __restrict__ u, const float* __restrict__ W1cat,
    float* __restrict__ Y, int it)
{
  __shared__ float s[512];
  int b = blockIdx.y, tid = threadIdx.x;
  int c = blockIdx.x * 256 + tid;
  const float* sr = u + ((long)(b * 31 + 16 + it)) * 512;
  s[tid] = sr[tid];
  s[tid + 256] = sr[tid + 256];
  __syncthreads();
  float a0 = 0.f, a1 = 0.f, a2 = 0.f, a3 = 0.f;
#pragma unroll 8
  for (int k = 0; k < 512; k += 4){
    a0 = fmaf(s[k],     W1cat[(long)k * 1024 + c],       a0);
    a1 = fmaf(s[k + 1], W1cat[(long)(k + 1) * 1024 + c], a1);
    a2 = fmaf(s[k + 2], W1cat[(long)(k + 2) * 1024 + c], a2);
    a3 = fmaf(s[k + 3], W1cat[(long)(k + 3) * 1024 + c], a3);
  }
  Y[((long)(b * 31 + 16 + it)) * 1024 + c] = (a0 + a1) + (a2 + a3);
}

// reverse layer3 + scatter into dmat. grid (4, 128)
__global__ __launch_bounds__(256) void rev3_k(
    const float* __restrict__ src,
    const float* __restrict__ W, const float* __restrict__ bias,
    float* __restrict__ dmat, const int* __restrict__ actions, int it)
{
  __shared__ float s[512];
  int b = blockIdx.y, tid = threadIdx.x;
  int p = blockIdx.x * 256 + tid;
  const float* sr = src + (long)b * 512;
  s[tid] = sr[tid];
  s[tid + 256] = sr[tid + 256];
  __syncthreads();
  float a0 = 0.f, a1 = 0.f, a2 = 0.f, a3 = 0.f;
#pragma unroll 8
  for (int k = 0; k < 512; k += 4){
    a0 = fmaf(s[k],     W[(long)k * 1024 + p],       a0);
    a1 = fmaf(s[k + 1], W[(long)(k + 1) * 1024 + p], a1);
    a2 = fmaf(s[k + 2], W[(long)(k + 2) * 1024 + p], a2);
    a3 = fmaf(s[k + 3], W[(long)(k + 3) * 1024 + p], a3);
  }
  float v = ((a0 + a1) + (a2 + a3)) + bias[p];
  int fit = 14 - it;
  int s0 = actions[(b * 15 + fit) * 2];
  int s1 = actions[(b * 15 + fit) * 2 + 1];
  int node = (p < 512) ? s0 : s1;
  int ee = p & 511;
  dmat[((long)(b * 31 + node)) * 512 + ee] = v;
}

// batched osl over all steps: grid 1920 (r = it*128 + b)
__global__ __launch_bounds__(256) void oslb_k(
    const float* __restrict__ pred, const float* __restrict__ u,
    const int* __restrict__ actions, float* __restrict__ sl, float* __restrict__ rew)
{
  int r = blockIdx.x, tid = threadIdx.x;
  int it = r >> 7, b = r & 127;
  int s0 = actions[(b * 15 + it) * 2];
  int s1 = actions[(b * 15 + it) * 2 + 1];
  const float* t0 = u + ((long)(b * 31 + s0)) * 512;
  const float* t1 = u + ((long)(b * 31 + s1)) * 512;
  const float* p = pred + (long)r * 1024;
  float s = 0.f;
  for (int k = tid; k < 512; k += 256){
    float d0 = p[k] - t0[k];       s = fmaf(d0, d0, s);
    float d1 = p[k + 512] - t1[k]; s = fmaf(d1, d1, s);
  }
  __shared__ float red[256];
  red[tid] = s; __syncthreads();
  for (int st = 128; st > 0; st >>= 1){ if (tid < st) red[tid] += red[tid + st]; __syncthreads(); }
  if (tid == 0){
    float osl = red[0] / 1024.0f;
    atomicAdd(sl + b, osl);
    rew[b * 15 + it] = -osl;
  }
}

// ---------------- init (no dmat zeroing: every cell of d is provably overwritten) ----------------
__global__ __launch_bounds__(256) void init_k(float* __restrict__ lbl,
    float* __restrict__ logits, float* __restrict__ sl, float* __restrict__ ent,
    int* __restrict__ active, float* __restrict__ zb,
    float* __restrict__ W1cat, const float* __restrict__ pol_w1, const float* __restrict__ pol_b3,
    long* __restrict__ tab_init, int* __restrict__ scat_init, long* __restrict__ tab_tok16,
    long* __restrict__ tab_mgd, int* __restrict__ scat_clf, long clf_off)
{
  long i = (long)blockIdx.x * 256 + threadIdx.x;
  if (i < 524288L){
    int k = (int)(i >> 10), n = (int)(i & 1023);
    W1cat[i] = (n < 512) ? pol_w1[(long)k * 512 + n] : pol_w1[(long)(k + 512) * 512 + (n - 512)];
  }
  if (i < 115200L){
    int rem = (int)(i % 900);
    int rr = rem / 30, cc = rem % 30;
    logits[i] = (rr < 16 && cc < 16 && rr != cc) ? pol_b3[0] : MASKV;
  }
  if (i < 30720L){
    int r = (int)i;
    int pk = r >> 7, b = r & 127;
    int ii2 = pk / 15, jr = pk % 15;
    int jj2 = jr + (jr >= ii2 ? 1 : 0);
    tab_init[r * 2]     = ((long)(b * 31 + ii2)) * 1024;
    tab_init[r * 2 + 1] = ((long)(b * 31 + jj2)) * 1024 + 512;
    scat_init[r] = b * 900 + ii2 * 30 + jj2;
  }
  if (i < 3968L){
    lbl[i] = ((i % 31) < 15) ? 1.0f : 0.0f;
    int r = (int)i;
    if (r < 1920){
      scat_clf[r] = (int)(clf_off + (long)(r & 127) * 62 + (r >> 7) * 2);
    } else {
      int rr = r - 1920;
      scat_clf[r] = (int)(clf_off + (long)(rr >> 4) * 62 + 60 - ((rr & 15) << 1));
    }
  }
  if (i < 2048L){
    active[i] = (int)(i & 15);
    tab_tok16[i] = ((long)((i >> 4) * 31 + (i & 15))) * 512;
  }
  if (i < 1920L){
    int it = (int)(i >> 7), b = (int)(i & 127);
    tab_mgd[i] = ((long)(b * 31 + 30 - it)) * 512;
  }
  if (i < 1024L)  zb[i] = 0.f;
  if (i < 128L){ sl[i] = 0.f; ent[i] = 0.f; }
}

__global__ __launch_bounds__(256) void noise_u_k(float* __restrict__ u, uint32_t k0, uint32_t k1){
  uint32_t e = blockIdx.x * 256u + threadIdx.x; // < 1048576
  uint32_t b = e >> 13, rem = e & 8191u, n = rem >> 9, ee = rem & 511u;
  float nr = jax_normal(k0, k1, e);
  long off = ((long)(b * 31u + n)) * 512 + ee;
  u[off] += 0.01f * nr;
}

__global__ __launch_bounds__(256) void build_d_k(float* __restrict__ dmat, const float* __restrict__ u){
  int e = blockIdx.x * 256 + threadIdx.x; // 65536
  int b = e >> 9, ee = e & 511;
  long off = ((long)(b * 31 + 30)) * 512 + ee;
  dmat[off] = u[off];
}

// softmax stats + entropy + gumbel-argmax + mask + active update + next tables + b3 preset
__global__ __launch_bounds__(256) void sample_k(float* __restrict__ logits, int* __restrict__ active,
    int* __restrict__ actions, float* __restrict__ lp, float* __restrict__ ent,
    int it, int A, uint32_t k0, uint32_t k1, float log_opt,
    long* __restrict__ tab_loop, int* __restrict__ scat_loop, long* __restrict__ tab_pair,
    const float* __restrict__ pol_b3)
{
  int b = blockIdx.x, tid = threadIdx.x;
  int lane = tid & 63, wid = tid >> 6;
  float* Lg = logits + (long)b * 900;
  __shared__ float rmax[4], rS[4], rT[4], rG[4];
  __shared__ int rGi[4];
  __shared__ int ss0, ss1;

  // pass 1: max
  float v = -3.4e38f;
  for (int j = tid; j < 900; j += 256) v = fmaxf(v, Lg[j]);
#pragma unroll
  for (int m = 32; m; m >>= 1) v = fmaxf(v, __shfl_xor(v, m));
  if (lane == 0) rmax[wid] = v;
  __syncthreads();
  float mx = fmaxf(fmaxf(rmax[0], rmax[1]), fmaxf(rmax[2], rmax[3]));

  // pass 2: S = sum exp(l-m); T = sum e*(l-m) over unmasked
  float s = 0.f, t = 0.f;
  for (int j = tid; j < 900; j += 256){
    float l = Lg[j];
    float d = l - mx;
    float e = expf(d);
    s += e;
    if (l > MASKV) t = fmaf(e, d, t);
  }
#pragma unroll
  for (int m = 32; m; m >>= 1){ s += __shfl_xor(s, m); t += __shfl_xor(t, m); }
  if (lane == 0){ rS[wid] = s; rT[wid] = t; }

  // pass 3: gumbel argmax (earliest index wins on ties)
  float bv = -3.4e38f; int bi = 0;
  for (int j = tid; j < 900; j += 256){
    float g = jax_gumbel(k0, k1, (uint32_t)(b * 900 + j));
    float val = Lg[j] + g;
    if (val > bv){ bv = val; bi = j; }
  }
#pragma unroll
  for (int m = 32; m; m >>= 1){
    float ov = __shfl_xor(bv, m); int oi = __shfl_xor(bi, m);
    if (ov > bv || (ov == bv && oi < bi)){ bv = ov; bi = oi; }
  }
  if (lane == 0){ rG[wid] = bv; rGi[wid] = bi; }
  __syncthreads();

  if (tid == 0){
    float S = (rS[0] + rS[1]) + (rS[2] + rS[3]);
    float T = (rT[0] + rT[1]) + (rT[2] + rT[3]);
    ent[b] += -(T / S - logf(S)) / log_opt;
    float gb = rG[0]; int gi = rGi[0];
    for (int w = 1; w < 4; w++){
      if (rG[w] > gb || (rG[w] == gb && rGi[w] < gi)){ gb = rG[w]; gi = rGi[w]; }
    }
    int sf = gi;
    int s0 = sf / 30, s1 = sf % 30;
    ss0 = s0; ss1 = s1;
    actions[(b * 15 + it) * 2] = s0;
    actions[(b * 15 + it) * 2 + 1] = s1;
    lp[b * 15 + it] = Lg[sf] - mx - logf(S);
    tab_pair[b * 2]     = ((long)(b * 31 + s0)) * 512;
    tab_pair[b * 2 + 1] = ((long)(b * 31 + s1)) * 512;
  }
  __syncthreads();
  int s0 = ss0, s1 = ss1;
  if (tid < 30){
    Lg[s0 * 30 + tid] = MASKV;
    Lg[s1 * 30 + tid] = MASKV;
    Lg[tid * 30 + s0] = MASKV;
    Lg[tid * 30 + s1] = MASKV;
  }
  if (tid == 0){
    float b3v = pol_b3[0];
    int buf[16]; int c = 0;
    for (int k = 0; k < A; k++){
      int a = active[b * 16 + k];
      if (a != s0 && a != s1) buf[c++] = a;
    }
    int nt2 = 16 + it;
    buf[c++] = nt2;
    for (int k = 0; k < c; k++) active[b * 16 + k] = buf[k];
    int na2 = c - 1;
    for (int j = 0; j < na2; j++){
      int q = buf[j];
      int r1 = j * 128 + b;
      tab_loop[r1 * 2]     = ((long)(b * 31 + nt2)) * 1024;
      tab_loop[r1 * 2 + 1] = ((long)(b * 31 + q)) * 1024 + 512;
      int sc1 = b * 900 + nt2 * 30 + q;
      scat_loop[r1] = sc1;
      logits[sc1] = b3v;
      int r2 = (na2 + j) * 128 + b;
      tab_loop[r2 * 2]     = ((long)(b * 31 + q)) * 1024;
      tab_loop[r2 * 2 + 1] = ((long)(b * 31 + nt2)) * 1024 + 512;
      int sc2 = b * 900 + q * 30 + nt2;
      scat_loop[r2] = sc2;
      logits[sc2] = b3v;
    }
  }
}

__global__ __launch_bounds__(256) void finalize_k(const float* __restrict__ rew,
    const float* __restrict__ lp, const float* __restrict__ sl, const float* __restrict__ ent,
    float* __restrict__ out_sl, float* __restrict__ out_ent, float* __restrict__ out_reinf)
{
  __shared__ float red[256];
  int tid = threadIdx.x;
  float s = 0.f;
  for (int i = tid; i < 1920; i += 256) s += rew[i];
  red[tid] = s; __syncthreads();
  for (int st = 128; st > 0; st >>= 1){ if (tid < st) red[tid] += red[tid + st]; __syncthreads(); }
  float mean = red[0] / 1920.0f; __syncthreads();
  float v = 0.f;
  for (int i = tid; i < 1920; i += 256){ float x = rew[i] - mean; v = fmaf(x, x, v); }
  red[tid] = v; __syncthreads();
  for (int st = 128; st > 0; st >>= 1){ if (tid < st) red[tid] += red[tid + st]; __syncthreads(); }
  float denom = sqrtf(red[0] / 1919.0f) + 1e-20f;
  if (tid < 128){
    out_sl[tid] = sl[tid] / 15.0f;
    out_ent[tid] = ent[tid] / 15.0f;
    float r = 0.f;
    for (int k = 0; k < 15; k++){
      float rn = (rew[tid * 15 + k] - mean) / denom;
      r = fmaf(lp[tid * 15 + k], rn, r);
    }
    out_reinf[tid] = r;
  }
}

// ---------------- host ----------------
extern "C" void kernel_launch(void* const* d_in, const int* in_sizes, int n_in,
                              void* d_out, int out_size, void* d_ws, size_t ws_size,
                              hipStream_t stream)
{
  const float* x        = (const float*)d_in[0];
  const float* lift_w   = (const float*)d_in[1];
  const float* lift_b   = (const float*)d_in[2];
  const float* unlift_w = (const float*)d_in[3];
  const float* unlift_b = (const float*)d_in[4];
  const float* enc_w1   = (const float*)d_in[5];
  const float* enc_b1   = (const float*)d_in[6];
  const float* enc_w2   = (const float*)d_in[7];
  const float* enc_b2   = (const float*)d_in[8];
  const float* enc_w3   = (const float*)d_in[9];
  const float* enc_b3   = (const float*)d_in[10];
  const float* dec_w1   = (const float*)d_in[11];
  const float* dec_b1   = (const float*)d_in[12];
  const float* dec_w2   = (const float*)d_in[13];
  const float* dec_b2   = (const float*)d_in[14];
  const float* dec_w3   = (const float*)d_in[15];
  const float* dec_b3   = (const float*)d_in[16];
  const float* clf_w1   = (const float*)d_in[17];
  const float* clf_b1   = (const float*)d_in[18];
  const float* clf_w2   = (const float*)d_in[19];
  const float* clf_b2   = (const float*)d_in[20];
  const float* clf_w3   = (const float*)d_in[21];
  const float* clf_b3   = (const float*)d_in[22];
  const float* pol_w1   = (const float*)d_in[23];
  const float* pol_b1   = (const float*)d_in[24];
  const float* pol_w2   = (const float*)d_in[25];
  const float* pol_b2   = (const float*)d_in[26];
  const float* pol_w3   = (const float*)d_in[27];
  const float* pol_b3   = (const float*)d_in[28];

  float* out = (float*)d_out;
  const long U_OFF     = 2097152;
  const long D_OFF     = 4128768;
  const long SL_OFF    = 6160384;
  const long ENT_OFF   = 6160512;
  const long CLF_OFF   = 6160640;
  const long LBL_OFF   = 6168576;
  const long REINF_OFF = 6172544;
  float* recon = out;
  float* u     = out + U_OFF;
  float* dmat  = out + D_OFF;

  char* wsb = (char*)d_ws;
  size_t wo = 0;
  auto alloc = [&](size_t bytes) -> void* {
    void* p = (void*)(wsb + wo);
    wo = (wo + bytes + 255) & ~(size_t)255;
    return p;
  };
  float* logits    = (float*)alloc(115200 * 4);
  float* Y         = (float*)alloc((size_t)3968 * 1024 * 4); // dead after fwd -> overlays:
  float* h1clf     = Y;                  // tail clf hidden1 (3968x512)
  float* pbuf      = Y + 2031616;        // dec output 1920x1024, then clf h2
  float* h2clf     = Y + 2031616;
  float* W1cat     = (float*)alloc((size_t)524288 * 4);
  float* zb        = (float*)alloc(1024 * 4);
  float* h1        = (float*)alloc((size_t)2048 * 512 * 4);
  float* h2        = (float*)alloc((size_t)2048 * 512 * 4);
  float* z_all     = (float*)alloc((size_t)15 * 65536 * 4);
  float* sl        = (float*)alloc(128 * 4);
  float* ent       = (float*)alloc(128 * 4);
  float* lp        = (float*)alloc(1920 * 4);
  float* rew       = (float*)alloc(1920 * 4);
  int*   active    = (int*)alloc(2048 * 4);
  int*   actions   = (int*)alloc(3840 * 4);
  long*  tab_init  = (long*)alloc((size_t)30720 * 2 * 8);
  int*   scat_init = (int*)alloc(30720 * 4);
  long*  tab_loop  = (long*)alloc((size_t)3584 * 2 * 8);
  int*   scat_loop = (int*)alloc(3584 * 4);
  long*  tab_pair  = (long*)alloc(256 * 8);
  long*  tab_mgd   = (long*)alloc(1920 * 8);   // contiguous with tab_tok16 -> 3968-row clf table
  long*  tab_tok16 = (long*)alloc(2048 * 8);
  int*   scat_clf  = (int*)alloc(3968 * 4);
  long*  tab_clf   = tab_mgd;
  (void)ws_size; (void)in_sizes; (void)n_in; (void)out_size;

  uint32_t k7a, k7b, ck0[15], ck1[15], mk0[15], mk1[15];
  { uint32_t a = 0, b = 7; tf2x32(0u, 42u, a, b); k7a = a; k7b = b; }
  for (int it = 0; it < 15; it++){
    { uint32_t a = 0, b = (uint32_t)(100 + it); tf2x32(0u, 42u, a, b); ck0[it] = a; ck1[it] = b; }
    { uint32_t a = 0, b = (uint32_t)(1000 + it); tf2x32(0u, 42u, a, b); mk0[it] = a; mk1[it] = b; }
  }

  auto gemm = [&](int act, const float* A, int lda, const long* atab, int anblk,
                  const float* W, const float* bs, float* C, int rows, int K, int Nn,
                  long cb, int crd, long cos, long cis){
    dim3 g(Nn / 64, rows / 64);
    if (act) gemm_k<1><<<g, 256, 0, stream>>>(A, lda, atab, anblk, W, bs, C, K, Nn, cb, crd, cos, cis);
    else     gemm_k<0><<<g, 256, 0, stream>>>(A, lda, atab, anblk, W, bs, C, K, Nn, cb, crd, cos, cis);
  };

  // ---- init ----
  init_k<<<2048, 256, 0, stream>>>(out + LBL_OFF, logits, sl, ent, active, zb,
                                   W1cat, pol_w1, pol_b3, tab_init, scat_init, tab_tok16,
                                   tab_mgd, scat_clf, CLF_OFF);

  // ---- lift + noise ----
  gemm(0, x, 1024, nullptr, 0, lift_w, lift_b, u, 2048, 1024, 512, 0, 16, 15872, 512);
  noise_u_k<<<4096, 256, 0, stream>>>(u, k7a, k7b);

  // ---- Y init for tokens 0..15 ----
  gemm(0, u, 0, tab_tok16, 1, W1cat, zb, Y, 2048, 512, 1024, 0, 16, 31744, 1024);

  // ---- initial policy logits (round-4 best: 256x128 tile, 8x8, 512 threads) ----
  { dim3 g(4, 120);
    gemm128f_k<<<g, 512, 0, stream>>>(Y, tab_init, pol_b1, pol_w2, pol_b2, pol_w3,
                                      scat_init, logits); }

  // ---- forward merge loop (per-layer matvecs, max fill) ----
  for (int it = 0; it < 15; it++){
    int A = 16 - it;
    if (it > 0){
      int rows = 256 * (15 - it);
      dim3 g(8, rows / 64);
      gemm64f_k<<<g, 256, 0, stream>>>(Y, tab_loop, pol_b1, pol_w2, pol_b2, pol_w3,
                                       scat_loop, logits);
    }
    float log_opt = (float)log((double)(A * (A - 1)));
    sample_k<<<128, 256, 0, stream>>>(logits, active, actions, lp, ent, it, A,
                                      ck0[it], ck1[it], log_opt,
                                      tab_loop, scat_loop, tab_pair, pol_b3);
    { dim3 g(2, 128);
      pairmv_k<<<g, 256, 0, stream>>>(u, tab_pair, enc_w1, enc_b1, h1); }
    { dim3 g(2, 128);
      mvrelu_k<<<g, 256, 0, stream>>>(h1, 512, enc_w2, enc_b2, h2); }
    { dim3 g(2, 128);
      lay3z_k<<<g, 256, 0, stream>>>(h2, enc_w3, enc_b3, z_all, u, it, mk0[it], mk1[it]); }
    if (it < 14){
      dim3 g(4, 128);
      yrow_k<<<g, 256, 0, stream>>>(u, W1cat, Y, it);
    }
  }

  // ---- deferred batched dec over all 15 steps (1920 rows), then osl ----
  gemm(1, z_all, 512, nullptr, 0, dec_w1, dec_b1, h1, 1920, 512, 512, 0, 1, 512, 0);
  gemm(1, h1, 512, nullptr, 0, dec_w2, dec_b2, h2, 1920, 512, 512, 0, 1, 512, 0);
  gemm(0, h2, 512, nullptr, 0, dec_w3, dec_b3, pbuf, 1920, 512, 1024, 0, 1, 1024, 0);
  oslb_k<<<1920, 256, 0, stream>>>(pbuf, u, actions, sl, rew);

  // ---- d init (only token 30 active) ----
  build_d_k<<<256, 256, 0, stream>>>(dmat, u);

  // ---- reverse unmerge loop: 3 wide layers per step ----
  for (int it = 0; it < 15; it++){
    int tok = 30 - it;
    { dim3 g(2, 128);
      mvrelu_k<<<g, 256, 0, stream>>>(dmat + (long)tok * 512, 15872, dec_w1, dec_b1, h1); }
    { dim3 g(2, 128);
      mvrelu_k<<<g, 256, 0, stream>>>(h1, 512, dec_w2, dec_b2, h2); }
    { dim3 g(4, 128);
      rev3_k<<<g, 256, 0, stream>>>(h2, dec_w3, dec_b3, dmat, actions, it); }
  }

  // ---- combined clf over mgd rows (1920) + final d[:, :16] rows (2048) ----
  gemm(1, dmat, 0, tab_clf, 1, clf_w1, clf_b1, h1clf, 3968, 512, 512, 0, 1, 512, 0);
  gemm(1, h1clf, 512, nullptr, 0, clf_w2, clf_b2, h2clf, 3968, 512, 512, 0, 1, 512, 0);
  rowdot2_k<<<992, 256, 0, stream>>>(h2clf, 512, clf_w3, clf_b3, 512, out, scat_clf);

  // ---- recon = d[:, :16] @ unlift_w + unlift_b ----
  gemm(0, dmat, 0, tab_tok16, 1, unlift_w, unlift_b, recon, 2048, 512, 1024,
       0, 16, 16384, 1024);

  // ---- reward normalization, reinf, per-batch losses ----
  finalize_k<<<1, 256, 0, stream>>>(rew, lp, sl, ent,
                                    out + SL_OFF, out + ENT_OFF, out + REINF_OFF);
}